// Round 11
// baseline (573.594 us; speedup 1.0000x reference)
//
#include <hip/hip_runtime.h>
#include <hip/hip_fp16.h>
#include <hip/hip_bf16.h>

#define NR 32

typedef __attribute__((ext_vector_type(8))) short bf8_t;   // 8 x bf16 (4 VGPR)
typedef __attribute__((ext_vector_type(4))) float f4_t;

__device__ __forceinline__ float silu_f(float x) {
    return x * __builtin_amdgcn_rcpf(1.0f + __expf(-x));
}

__device__ __forceinline__ unsigned pkbf(float lo, float hi) {
    __hip_bfloat162 h = __float22bfloat162_rn(make_float2(lo, hi));
    union { __hip_bfloat162 h2; unsigned u; } cv; cv.h2 = h; return cv.u;
}
__device__ __forceinline__ float bf_lo(unsigned u) { return __uint_as_float(u << 16); }
__device__ __forceinline__ float bf_hi(unsigned u) { return __uint_as_float(u & 0xffff0000u); }

__device__ __forceinline__ float rdl(float v, int l) {
    return __int_as_float(__builtin_amdgcn_readlane(__float_as_int(v), l));
}

// ---------------- CSR build ----------------
__global__ __launch_bounds__(256) void k_hist(
    const int* __restrict__ eidx, int* __restrict__ cnt, int nedges)
{
    int e = blockIdx.x * 256 + threadIdx.x;
    if (e < nedges) atomicAdd(&cnt[eidx[e]], 1);
}

__global__ __launch_bounds__(1024) void k_scan2(
    int* __restrict__ cnt, int* __restrict__ off, int n)
{
    __shared__ int wsum[16];
    __shared__ int wbase[16];
    const int tid = threadIdx.x;
    const int lane = tid & 63, wid = tid >> 6;
    const int per = (n + 1023) >> 10;
    const int base = tid * per;
    int s = 0;
    for (int i = 0; i < per; i++) {
        int idx = base + i;
        if (idx < n) s += cnt[idx];
    }
    int incl = s;
    for (int d = 1; d < 64; d <<= 1) {
        int t = __shfl_up(incl, d);
        if (lane >= d) incl += t;
    }
    if (lane == 63) wsum[wid] = incl;
    __syncthreads();
    if (wid == 0) {
        int v = (lane < 16) ? wsum[lane] : 0;
        int inc2 = v;
        for (int d = 1; d < 16; d <<= 1) {
            int t = __shfl_up(inc2, d);
            if (lane >= d) inc2 += t;
        }
        if (lane < 16) wbase[lane] = inc2 - v;
        if (lane == 15) off[n] = inc2;
    }
    __syncthreads();
    int run = wbase[wid] + incl - s;
    for (int i = 0; i < per; i++) {
        int idx = base + i;
        if (idx < n) {
            int v = cnt[idx];
            off[idx] = run;
            cnt[idx] = run;
            run += v;
        }
    }
}

__global__ __launch_bounds__(256) void k_scatter(
    const int* __restrict__ eidx, int* __restrict__ cur,
    int* __restrict__ perm, int* __restrict__ col_s, int nedges)
{
    int e = blockIdx.x * 256 + threadIdx.x;
    if (e < nedges) {
        int r = eidx[e];
        int pos = atomicAdd(&cur[r], 1);
        perm[pos] = e;
        col_s[pos] = eidx[nedges + e];
    }
}

// ---------------- K_prep: bake bf16 frag-linear remapped weight blob ----------------
// blob dwords: [0,12288) w3p | [12288,12672) biases f32 | [12672,13696) w1p | [13696,17792) w2p
// frag slot order: slot = r*4+g, dword dd; k-remap c0 = 32*kt + 16*(dd>>1) + 4*g + 2*(dd&1)
__global__ __launch_bounds__(256) void k_prep(
    const float* __restrict__ w1, const float* __restrict__ b1,
    const float* __restrict__ w2, const float* __restrict__ b2,
    const float* __restrict__ w3, const float* __restrict__ b3,
    unsigned* __restrict__ wpre)
{
    int i = blockIdx.x * 256 + threadIdx.x;
    if (i < 12288) {                       // w3p: 48 (m*4+kt) x 256 dw
        int mk = i >> 8, m = mk >> 2, kt = mk & 3;
        int rr = (i >> 4) & 15, gg = (i >> 2) & 3, dd = i & 3;
        int row = 16 * m + rr;
        int c0 = 32 * kt + 16 * (dd >> 1) + 4 * gg + 2 * (dd & 1);
        const float* s = w3 + (size_t)row * 128 + c0;
        wpre[i] = pkbf(s[0], s[1]);
    } else if (i < 12672) {                // biases: b1[64] b2[128] b3[192]
        int j = i - 12288;
        float v = (j < 64) ? b1[j] : (j < 192) ? b2[j - 64] : b3[j - 192];
        wpre[i] = __float_as_uint(v);
    } else if (i < 13696) {                // w1p: 4 m x 256 dw, natural k
        int j = i - 12672;
        int m = j >> 8, rr = (j >> 4) & 15, gg = (j >> 2) & 3, dd = j & 3;
        const float* s = w1 + (size_t)(16 * m + rr) * 32 + 8 * gg + 2 * dd;
        wpre[i] = pkbf(s[0], s[1]);
    } else if (i < 17792) {                // w2p: 16 (m*2+kt) x 256 dw, remapped
        int j = i - 13696;
        int mk = j >> 8, m = mk >> 1, kt = mk & 1;
        int rr = (j >> 4) & 15, gg = (j >> 2) & 3, dd = j & 3;
        int row = 16 * m + rr;
        int c0 = 32 * kt + 16 * (dd >> 1) + 4 * gg + 2 * (dd & 1);
        const float* s = w2 + (size_t)row * 64 + c0;
        wpre[i] = pkbf(s[0], s[1]);
    }
}

// ---------------- K1: node decompose + mix (lin_w[0..2]) -> Tmh[N][5][64] packed bf16 ----------------
__global__ __launch_bounds__(512) void k1_node_mix(
    const float* __restrict__ X, const float* __restrict__ lw,
    unsigned* __restrict__ Tmh, int nnodes)
{
    __shared__ float Wl[3 * 64 * 68];      // padded rows (68 dwords, 16B-aligned)
    const int tid = threadIdx.x;
#pragma unroll
    for (int k = 0; k < 6; k++) {          // stage lw[0..2]: 12288 floats coalesced
        int l = (tid + k * 512) * 4;
        int row = l >> 6, col = l & 63;
        *(float4*)&Wl[row * 68 + col] = *(const float4*)(lw + l);
    }

    const int wid = tid >> 6, lane = tid & 63;
    const int n = blockIdx.x * 8 + wid;
    const bool valid = (n < nnodes);

    float i0 = 0, i1 = 0, i2 = 0, i3 = 0, i4 = 0, i5 = 0, i6 = 0, i7 = 0, i8 = 0;
    if (valid) {
        const float* xp = X + ((size_t)n * 64 + lane) * 9;
        float v[9];
#pragma unroll
        for (int i = 0; i < 9; i++) v[i] = xp[i];
        float tn = 0.f;
#pragma unroll
        for (int i = 0; i < 9; i++) tn = fmaf(v[i], v[i], tn);
        float inv = 1.0f / (tn + 1.0f);
#pragma unroll
        for (int i = 0; i < 9; i++) v[i] *= inv;
        float lam = (v[0] + v[4] + v[8]) * (1.0f / 3.0f);
        i0 = lam;
        i1 = (v[1] - v[3]) * 0.5f;
        i2 = (v[2] - v[6]) * 0.5f;
        i3 = (v[5] - v[7]) * 0.5f;
        i4 = v[0] - lam;
        i5 = (v[1] + v[3]) * 0.5f;
        i6 = (v[2] + v[6]) * 0.5f;
        i7 = v[4] - lam;
        i8 = (v[5] + v[7]) * 0.5f;
    }
    __syncthreads();

    const int g = lane;
    float a0 = 0, a1 = 0, a2 = 0, a3 = 0, a4 = 0, a5 = 0, a6 = 0, a7 = 0, a8 = 0;
#pragma unroll
    for (int h4 = 0; h4 < 64; h4 += 4) {
        float4 w0 = *(const float4*)&Wl[g * 68 + h4];
        float4 w1 = *(const float4*)&Wl[(64 + g) * 68 + h4];
        float4 w2 = *(const float4*)&Wl[(128 + g) * 68 + h4];
#pragma unroll
        for (int j = 0; j < 4; j++) {
            const int h = h4 + j;
            float wa = (&w0.x)[j], wb = (&w1.x)[j], wc = (&w2.x)[j];
            a0 = fmaf(wa, rdl(i0, h), a0);
            a1 = fmaf(wb, rdl(i1, h), a1);
            a2 = fmaf(wb, rdl(i2, h), a2);
            a3 = fmaf(wb, rdl(i3, h), a3);
            a4 = fmaf(wc, rdl(i4, h), a4);
            a5 = fmaf(wc, rdl(i5, h), a5);
            a6 = fmaf(wc, rdl(i6, h), a6);
            a7 = fmaf(wc, rdl(i7, h), a7);
            a8 = fmaf(wc, rdl(i8, h), a8);
        }
    }
    if (valid) {
        unsigned* outp = Tmh + (size_t)n * 320 + g;
        outp[0 * 64] = pkbf(a0, a1);
        outp[1 * 64] = pkbf(a2, a3);
        outp[2 * 64] = pkbf(a4, a5);
        outp[3 * 64] = pkbf(a6, a7);
        outp[4 * 64] = pkbf(a8, 0.f);
    }
}

// ---------------- K2f: fused edge MLP (MFMA, transposed) + accumulate + k3 ----------------
// 16 waves/block; col_s preloaded per chunk, Tmh gathers prefetched under L3 MFMA.
// LDS: w3p frag-linear [0,49152) | biases [49152,50688) | 16 per-wave ef tiles (16 x 408 B).
#define LBI 49152
#define LEF 50688
#define EFS 408
#define NW  16

__global__ __launch_bounds__(1024, 4) void k2f_fused(
    const float* __restrict__ ea, const float* __restrict__ dist,
    const int* __restrict__ perm, const int* __restrict__ col_s,
    const int* __restrict__ off, const unsigned* __restrict__ wpre,
    const unsigned* __restrict__ Tmh, float* __restrict__ out, int nrows)
{
    __shared__ __align__(16) char smem[LEF + NW * 16 * EFS];   // 155136 B
    const int tid = threadIdx.x;

    // stage w3p + biases -> LDS, linear coalesced (12672 dw = 3168 uint4)
#pragma unroll
    for (int k = 0; k < 4; k++) {
        int idx = tid + k * 1024;
        if (idx < 3168)
            ((uint4*)smem)[idx] = ((const uint4*)wpre)[idx];
    }

    const int wid = tid >> 6, lane = tid & 63;
    const int r16 = lane & 15, g = lane >> 4;
    const int slot = r16 * 4 + g;
    char* efb = smem + LEF + wid * (16 * EFS);

    // W1/W2 A-frags from prepped blob (contiguous 1KB windows per wave)
    bf8_t aw1[4];
#pragma unroll
    for (int m = 0; m < 4; m++)
        aw1[m] = *(const bf8_t*)(wpre + 12672 + (m * 64 + slot) * 4);
    bf8_t aw2[8][2];
#pragma unroll
    for (int m = 0; m < 8; m++)
#pragma unroll
        for (int kt = 0; kt < 2; kt++)
            aw2[m][kt] = *(const bf8_t*)(wpre + 13696 + ((m * 2 + kt) * 64 + slot) * 4);
    __syncthreads();

    const int r = blockIdx.x * NW + wid;
    if (r >= nrows) return;
    const int beg = off[r];
    const int deg = off[r + 1] - beg;

    float acc[9];
#pragma unroll
    for (int i = 0; i < 9; i++) acc[i] = 0.f;

    // ---- prefetch chunk 0's edge data ----
    float4 nv0 = {0, 0, 0, 0}, nv1 = {0, 0, 0, 0};
    float nd = 1e9f;
    int nval = 0;
    if (deg > 0) {
        int cnt0 = min(16, deg);
        int e0 = perm[beg + ((r16 < cnt0) ? r16 : 0)];
        const float* ar0 = ea + (size_t)e0 * NR + 8 * g;
        nv0 = *(const float4*)(ar0);
        nv1 = *(const float4*)(ar0 + 4);
        nd = dist[e0];
        nval = (r16 < cnt0) ? 1 : 0;
    }

#pragma unroll 1
    for (int c0 = 0; c0 < deg; c0 += 16) {
        const int cnt = min(16, deg - c0);

        // cols of this chunk (lane r16 holds edge r16's col; clamped for pads)
        int colv = col_s[beg + c0 + ((r16 < cnt) ? r16 : (cnt - 1))];

        // build B-frag + cutoff from prefetched regs
        bf8_t bx;
        {
            union { bf8_t v; unsigned u[4]; } tt;
            tt.u[0] = pkbf(nv0.x, nv0.y); tt.u[1] = pkbf(nv0.z, nv0.w);
            tt.u[2] = pkbf(nv1.x, nv1.y); tt.u[3] = pkbf(nv1.z, nv1.w);
            bx = tt.v;
        }
        float cf = (nval && nd < 5.0f)
                 ? 0.5f * (__cosf(nd * 0.62831853071795864f) + 1.0f) : 0.0f;

        // ---- L1 ----
        unsigned pk1[4][2];
#pragma unroll
        for (int m = 0; m < 4; m++) {
            f4_t c = *(const f4_t*)(smem + LBI + (16 * m + 4 * g) * 4);
            c = __builtin_amdgcn_mfma_f32_16x16x32_bf16(aw1[m], bx, c, 0, 0, 0);
            pk1[m][0] = pkbf(silu_f(c[0]), silu_f(c[1]));
            pk1[m][1] = pkbf(silu_f(c[2]), silu_f(c[3]));
        }
        bf8_t B2[2];
        {
            union { bf8_t v; unsigned u[4]; } ta, tb;
            ta.u[0] = pk1[0][0]; ta.u[1] = pk1[0][1]; ta.u[2] = pk1[1][0]; ta.u[3] = pk1[1][1];
            tb.u[0] = pk1[2][0]; tb.u[1] = pk1[2][1]; tb.u[2] = pk1[3][0]; tb.u[3] = pk1[3][1];
            B2[0] = ta.v; B2[1] = tb.v;
        }

        // ---- L2 ----
        unsigned pk2[8][2];
#pragma unroll
        for (int m = 0; m < 8; m++) {
            f4_t c = *(const f4_t*)(smem + LBI + (64 + 16 * m + 4 * g) * 4);
            c = __builtin_amdgcn_mfma_f32_16x16x32_bf16(aw2[m][0], B2[0], c, 0, 0, 0);
            c = __builtin_amdgcn_mfma_f32_16x16x32_bf16(aw2[m][1], B2[1], c, 0, 0, 0);
            pk2[m][0] = pkbf(silu_f(c[0]), silu_f(c[1]));
            pk2[m][1] = pkbf(silu_f(c[2]), silu_f(c[3]));
        }
        bf8_t B3[4];
#pragma unroll
        for (int kt = 0; kt < 4; kt++) {
            union { bf8_t v; unsigned u[4]; } tt;
            tt.u[0] = pk2[2 * kt][0]; tt.u[1] = pk2[2 * kt][1];
            tt.u[2] = pk2[2 * kt + 1][0]; tt.u[3] = pk2[2 * kt + 1][1];
            B3[kt] = tt.v;
        }

        // ---- Tmh gather prefetch, edges 0..11 (hidden under L3 MFMAs) ----
        unsigned q[12][5];
#pragma unroll
        for (int s = 0; s < 12; s++) {
            int sc = __builtin_amdgcn_readlane(colv, s);
            const unsigned* t = Tmh + (size_t)(unsigned)sc * 320 + lane;
            q[s][0] = t[0]; q[s][1] = t[64]; q[s][2] = t[128];
            q[s][3] = t[192]; q[s][4] = t[256];
        }

        // ---- issue next chunk's ea prefetch ----
        {
            int c1 = c0 + 16;
            if (c1 < deg) {
                int cnt1 = min(16, deg - c1);
                int e1 = perm[beg + c1 + ((r16 < cnt1) ? r16 : 0)];
                const float* ar1 = ea + (size_t)e1 * NR + 8 * g;
                nv0 = *(const float4*)(ar1);
                nv1 = *(const float4*)(ar1 + 4);
                nd = dist[e1];
                nval = (r16 < cnt1) ? 1 : 0;
            }
        }

        // ---- drain prior chunk's LDS reads before overwriting the tile ----
        asm volatile("s_waitcnt lgkmcnt(0)" ::: "memory");
        __builtin_amdgcn_sched_barrier(0);

        // ---- L3 + cutoff -> per-wave LDS ef tile ----
#pragma unroll
        for (int m = 0; m < 12; m++) {
            f4_t c = *(const f4_t*)(smem + LBI + (192 + 16 * m + 4 * g) * 4);
#pragma unroll
            for (int kt = 0; kt < 4; kt++) {
                bf8_t aw = *(const bf8_t*)(smem + ((m * 4 + kt) * 64 + slot) * 16);
                c = __builtin_amdgcn_mfma_f32_16x16x32_bf16(aw, B3[kt], c, 0, 0, 0);
            }
            union { struct { __half2 a, b; } h; uint2 u; } pu;
            pu.h.a = __float22half2_rn(make_float2(c[0] * cf, c[1] * cf));
            pu.h.b = __float22half2_rn(make_float2(c[2] * cf, c[3] * cf));
            *(uint2*)(efb + r16 * EFS + (16 * m + 4 * g) * 2) = pu.u;
        }
        asm volatile("s_waitcnt lgkmcnt(0)" ::: "memory");
        __builtin_amdgcn_sched_barrier(0);

        // ---- accumulate (branchless over 16 slots; padded slots carry f=0) ----
#define ACC_STEP(S, Q)                                                        \
        {                                                                     \
            const __half* fp = (const __half*)(efb + (S) * EFS + 6 * lane);   \
            float f0 = __half2float(fp[0]);                                   \
            float f1 = __half2float(fp[1]);                                   \
            float f2 = __half2float(fp[2]);                                   \
            acc[0] = fmaf(f0, bf_lo(Q[0]), acc[0]);                           \
            acc[1] = fmaf(f1, bf_hi(Q[0]), acc[1]);                           \
            acc[2] = fmaf(f1, bf_lo(Q[1]), acc[2]);                           \
            acc[3] = fmaf(f1, bf_hi(Q[1]), acc[3]);                           \
            acc[4] = fmaf(f2, bf_lo(Q[2]), acc[4]);                           \
            acc[5] = fmaf(f2, bf_hi(Q[2]), acc[5]);                           \
            acc[6] = fmaf(f2, bf_lo(Q[3]), acc[6]);                           \
            acc[7] = fmaf(f2, bf_hi(Q[3]), acc[7]);                           \
            acc[8] = fmaf(f2, bf_lo(Q[4]), acc[8]);                           \
        }

        // edges 0..3 (prefetched), then reuse q[0..3] for edges 12..15
        ACC_STEP(0, q[0]) ACC_STEP(1, q[1]) ACC_STEP(2, q[2]) ACC_STEP(3, q[3])
#pragma unroll
        for (int s = 12; s < 16; s++) {
            int sc = __builtin_amdgcn_readlane(colv, s);
            const unsigned* t = Tmh + (size_t)(unsigned)sc * 320 + lane;
            q[s - 12][0] = t[0]; q[s - 12][1] = t[64]; q[s - 12][2] = t[128];
            q[s - 12][3] = t[192]; q[s - 12][4] = t[256];
        }
        ACC_STEP(4, q[4])  ACC_STEP(5, q[5])  ACC_STEP(6, q[6])  ACC_STEP(7, q[7])
        ACC_STEP(8, q[8])  ACC_STEP(9, q[9])  ACC_STEP(10, q[10]) ACC_STEP(11, q[11])
        ACC_STEP(12, q[0]) ACC_STEP(13, q[1]) ACC_STEP(14, q[2])  ACC_STEP(15, q[3])
#undef ACC_STEP
    }

    // ---- fused k3: prod = M@Y + Y@M, decompose, /norm -> out (pc comp-major) ----
    float y[9];
    {
        const unsigned* tp = Tmh + (size_t)r * 320 + lane;
        unsigned q0 = tp[0], q1 = tp[64], q2 = tp[128], q3 = tp[192], q4 = tp[256];
        y[0] = bf_lo(q0); y[1] = bf_hi(q0); y[2] = bf_lo(q1); y[3] = bf_hi(q1);
        y[4] = bf_lo(q2); y[5] = bf_hi(q2); y[6] = bf_lo(q3); y[7] = bf_hi(q3);
        y[8] = bf_lo(q4);
    }
    float Y[9], Mm[9];
    Y[0] = y[0] + y[4]; Y[1] = y[1] + y[5]; Y[2] = y[2] + y[6];
    Y[3] = -y[1] + y[5]; Y[4] = y[0] + y[7]; Y[5] = y[3] + y[8];
    Y[6] = -y[2] + y[6]; Y[7] = -y[3] + y[8]; Y[8] = y[0] - y[4] - y[7];
    Mm[0] = acc[0] + acc[4]; Mm[1] = acc[1] + acc[5]; Mm[2] = acc[2] + acc[6];
    Mm[3] = -acc[1] + acc[5]; Mm[4] = acc[0] + acc[7]; Mm[5] = acc[3] + acc[8];
    Mm[6] = -acc[2] + acc[6]; Mm[7] = -acc[3] + acc[8]; Mm[8] = acc[0] - acc[4] - acc[7];
    float P[9];
#pragma unroll
    for (int a = 0; a < 3; a++)
#pragma unroll
        for (int b = 0; b < 3; b++) {
            float s = 0.f;
#pragma unroll
            for (int c = 0; c < 3; c++) {
                s = fmaf(Mm[a * 3 + c], Y[c * 3 + b], s);
                s = fmaf(Y[a * 3 + c], Mm[c * 3 + b], s);
            }
            P[a * 3 + b] = s;
        }
    float tn = 0.f;
#pragma unroll
    for (int k = 0; k < 9; k++) tn = fmaf(P[k], P[k], tn);
    float inv = 1.0f / (tn + 1.0f);
    float lam = (P[0] + P[4] + P[8]) * (1.0f / 3.0f);

    float* mp = out + (size_t)r * 576 + lane;
    mp[0 * 64] = lam * inv;
    mp[1 * 64] = (P[1] - P[3]) * 0.5f * inv;
    mp[2 * 64] = (P[2] - P[6]) * 0.5f * inv;
    mp[3 * 64] = (P[5] - P[7]) * 0.5f * inv;
    mp[4 * 64] = (P[0] - lam) * inv;
    mp[5 * 64] = (P[1] + P[3]) * 0.5f * inv;
    mp[6 * 64] = (P[2] + P[6]) * 0.5f * inv;
    mp[7 * 64] = (P[4] - lam) * inv;
    mp[8 * 64] = (P[5] + P[7]) * 0.5f * inv;
}

// ---------------- K4: mix (lin_w[3..5]) -> dX; out = Xn + dX + dX@dX (in-place over pc) ----------------
__global__ __launch_bounds__(512) void k4_final(
    const float* __restrict__ X, const float* __restrict__ lw,
    float* __restrict__ out, int nnodes)
{
    __shared__ float Wl[3 * 64 * 68];
    const int tid = threadIdx.x;
#pragma unroll
    for (int k = 0; k < 6; k++) {          // stage lw[3..5]
        int l = (tid + k * 512) * 4;
        int row = l >> 6, col = l & 63;
        *(float4*)&Wl[row * 68 + col] = *(const float4*)(lw + 3 * 4096 + l);
    }

    const int wid = tid >> 6, lane = tid & 63;
    const int n = blockIdx.x * 8 + wid;
    const bool valid = (n < nnodes);

    float i0 = 0, i1 = 0, i2 = 0, i3 = 0, i4 = 0, i5 = 0, i6 = 0, i7 = 0, i8 = 0;
    if (valid) {
        const float* pp = out + (size_t)n * 576 + lane;   // pc comp-major [n][9][64]
        i0 = pp[0 * 64]; i1 = pp[1 * 64]; i2 = pp[2 * 64];
        i3 = pp[3 * 64]; i4 = pp[4 * 64]; i5 = pp[5 * 64];
        i6 = pp[6 * 64]; i7 = pp[7 * 64]; i8 = pp[8 * 64];
    }
    __syncthreads();

    const int g = lane;
    float a0 = 0, a1 = 0, a2 = 0, a3 = 0, a4 = 0, a5 = 0, a6 = 0, a7 = 0, a8 = 0;
#pragma unroll
    for (int h4 = 0; h4 < 64; h4 += 4) {
        float4 w0 = *(const float4*)&Wl[g * 68 + h4];
        float4 w1 = *(const float4*)&Wl[(64 + g) * 68 + h4];
        float4 w2 = *(const float4*)&Wl[(128 + g) * 68 + h4];
#pragma unroll
        for (int j = 0; j < 4; j++) {
            const int h = h4 + j;
            float wa = (&w0.x)[j], wb = (&w1.x)[j], wc = (&w2.x)[j];
            a0 = fmaf(wa, rdl(i0, h), a0);
            a1 = fmaf(wb, rdl(i1, h), a1);
            a2 = fmaf(wb, rdl(i2, h), a2);
            a3 = fmaf(wb, rdl(i3, h), a3);
            a4 = fmaf(wc, rdl(i4, h), a4);
            a5 = fmaf(wc, rdl(i5, h), a5);
            a6 = fmaf(wc, rdl(i6, h), a6);
            a7 = fmaf(wc, rdl(i7, h), a7);
            a8 = fmaf(wc, rdl(i8, h), a8);
        }
    }

    if (valid) {
        float D[9];
        D[0] = a0 + a4; D[1] = a1 + a5; D[2] = a2 + a6;
        D[3] = -a1 + a5; D[4] = a0 + a7; D[5] = a3 + a8;
        D[6] = -a2 + a6; D[7] = -a3 + a8; D[8] = a0 - a4 - a7;

        const float* xp = X + ((size_t)n * 64 + g) * 9;
        float xv[9];
#pragma unroll
        for (int i = 0; i < 9; i++) xv[i] = xp[i];
        float tn = 0.f;
#pragma unroll
        for (int i = 0; i < 9; i++) tn = fmaf(xv[i], xv[i], tn);
        float inv = 1.0f / (tn + 1.0f);

        float* op = out + ((size_t)n * 64 + g) * 9;   // final [N][64][3][3]
        float res[9];
#pragma unroll
        for (int a = 0; a < 3; a++)
#pragma unroll
            for (int b = 0; b < 3; b++) {
                float dd = 0.f;
#pragma unroll
                for (int c = 0; c < 3; c++) dd = fmaf(D[a * 3 + c], D[c * 3 + b], dd);
                res[a * 3 + b] = xv[a * 3 + b] * inv + D[a * 3 + b] + dd;
            }
#pragma unroll
        for (int i = 0; i < 9; i++) op[i] = res[i];
    }
}

extern "C" void kernel_launch(void* const* d_in, const int* in_sizes, int n_in,
                              void* d_out, int out_size, void* d_ws, size_t ws_size,
                              hipStream_t stream)
{
    const float* X    = (const float*)d_in[0];
    const int*   eidx = (const int*)d_in[1];
    const float* dist = (const float*)d_in[2];
    const float* ea   = (const float*)d_in[3];
    const float* w1   = (const float*)d_in[4];
    const float* b1   = (const float*)d_in[5];
    const float* w2   = (const float*)d_in[6];
    const float* b2   = (const float*)d_in[7];
    const float* w3   = (const float*)d_in[8];
    const float* b3   = (const float*)d_in[9];
    const float* lw   = (const float*)d_in[10];
    float* outp = (float*)d_out;

    const int nnodes = in_sizes[0] / (64 * 9);   // 20000
    const int nedges = in_sizes[2];              // 320000

    unsigned* Tmh  = (unsigned*)d_ws;                       // N*320 dwords (packed bf16 pairs)
    int* cur       = (int*)(Tmh + (size_t)nnodes * 320);
    int* off       = cur + nnodes;                          // nnodes+1
    int* perm      = off + nnodes + 1;                      // nedges
    int* col_s     = perm + nedges;                         // nedges
    unsigned* wpre = (unsigned*)(col_s + nedges);           // 17792 dwords

    // CSR build (edges sorted by destination row; col pre-gathered)
    hipMemsetAsync(cur, 0, (size_t)nnodes * sizeof(int), stream);
    k_hist<<<(nedges + 255) / 256, 256, 0, stream>>>(eidx, cur, nedges);
    k_scan2<<<1, 1024, 0, stream>>>(cur, off, nnodes);
    k_scatter<<<(nedges + 255) / 256, 256, 0, stream>>>(eidx, cur, perm, col_s, nedges);
    k_prep<<<70, 256, 0, stream>>>(w1, b1, w2, b2, w3, b3, wpre);

    k1_node_mix<<<(nnodes + 7) / 8, 512, 0, stream>>>(X, lw, Tmh, nnodes);
    k2f_fused<<<(nnodes + NW - 1) / NW, 1024, 0, stream>>>(ea, dist, perm, col_s, off, wpre, Tmh, outp, nnodes);
    k4_final<<<(nnodes + 7) / 8, 512, 0, stream>>>(X, lw, outp, nnodes);
}

// Round 14
// 560.871 us; speedup vs baseline: 1.0227x; 1.0227x over previous
//
#include <hip/hip_runtime.h>
#include <hip/hip_fp16.h>
#include <hip/hip_bf16.h>

#define NR 32

typedef __attribute__((ext_vector_type(8))) short bf8_t;   // 8 x bf16 (4 VGPR)
typedef __attribute__((ext_vector_type(4))) float f4_t;

__device__ __forceinline__ float silu_f(float x) {
    return x * __builtin_amdgcn_rcpf(1.0f + __expf(-x));
}

__device__ __forceinline__ unsigned pkbf(float lo, float hi) {
    __hip_bfloat162 h = __float22bfloat162_rn(make_float2(lo, hi));
    union { __hip_bfloat162 h2; unsigned u; } cv; cv.h2 = h; return cv.u;
}
__device__ __forceinline__ float bf_lo(unsigned u) { return __uint_as_float(u << 16); }
__device__ __forceinline__ float bf_hi(unsigned u) { return __uint_as_float(u & 0xffff0000u); }

__device__ __forceinline__ float rdl(float v, int l) {
    return __int_as_float(__builtin_amdgcn_readlane(__float_as_int(v), l));
}

// ---------------- CSR build ----------------
__global__ __launch_bounds__(256) void k_hist(
    const int* __restrict__ eidx, int* __restrict__ cnt, int nedges)
{
    int e = blockIdx.x * 256 + threadIdx.x;
    if (e < nedges) atomicAdd(&cnt[eidx[e]], 1);
}

__global__ __launch_bounds__(1024) void k_scan2(
    int* __restrict__ cnt, int* __restrict__ off, int n)
{
    __shared__ int wsum[16];
    __shared__ int wbase[16];
    const int tid = threadIdx.x;
    const int lane = tid & 63, wid = tid >> 6;
    const int per = (n + 1023) >> 10;
    const int base = tid * per;
    int s = 0;
    for (int i = 0; i < per; i++) {
        int idx = base + i;
        if (idx < n) s += cnt[idx];
    }
    int incl = s;
    for (int d = 1; d < 64; d <<= 1) {
        int t = __shfl_up(incl, d);
        if (lane >= d) incl += t;
    }
    if (lane == 63) wsum[wid] = incl;
    __syncthreads();
    if (wid == 0) {
        int v = (lane < 16) ? wsum[lane] : 0;
        int inc2 = v;
        for (int d = 1; d < 16; d <<= 1) {
            int t = __shfl_up(inc2, d);
            if (lane >= d) inc2 += t;
        }
        if (lane < 16) wbase[lane] = inc2 - v;
        if (lane == 15) off[n] = inc2;
    }
    __syncthreads();
    int run = wbase[wid] + incl - s;
    for (int i = 0; i < per; i++) {
        int idx = base + i;
        if (idx < n) {
            int v = cnt[idx];
            off[idx] = run;
            cnt[idx] = run;
            run += v;
        }
    }
}

__global__ __launch_bounds__(256) void k_scatter(
    const int* __restrict__ eidx, int* __restrict__ cur,
    int* __restrict__ perm, int* __restrict__ col_s, int nedges)
{
    int e = blockIdx.x * 256 + threadIdx.x;
    if (e < nedges) {
        int r = eidx[e];
        int pos = atomicAdd(&cur[r], 1);
        perm[pos] = e;
        col_s[pos] = eidx[nedges + e];
    }
}

// ---------------- K_prep: bake bf16 frag-linear remapped weight blob ----------------
// blob dwords: [0,12288) w3p | [12288,12672) biases f32 | [12672,13696) w1p | [13696,17792) w2p
// frag slot order: slot = r*4+g, dword dd; k-remap c0 = 32*kt + 16*(dd>>1) + 4*g + 2*(dd&1)
__global__ __launch_bounds__(256) void k_prep(
    const float* __restrict__ w1, const float* __restrict__ b1,
    const float* __restrict__ w2, const float* __restrict__ b2,
    const float* __restrict__ w3, const float* __restrict__ b3,
    unsigned* __restrict__ wpre)
{
    int i = blockIdx.x * 256 + threadIdx.x;
    if (i < 12288) {                       // w3p: 48 (m*4+kt) x 256 dw
        int mk = i >> 8, m = mk >> 2, kt = mk & 3;
        int rr = (i >> 4) & 15, gg = (i >> 2) & 3, dd = i & 3;
        int row = 16 * m + rr;
        int c0 = 32 * kt + 16 * (dd >> 1) + 4 * gg + 2 * (dd & 1);
        const float* s = w3 + (size_t)row * 128 + c0;
        wpre[i] = pkbf(s[0], s[1]);
    } else if (i < 12672) {                // biases: b1[64] b2[128] b3[192]
        int j = i - 12288;
        float v = (j < 64) ? b1[j] : (j < 192) ? b2[j - 64] : b3[j - 192];
        wpre[i] = __float_as_uint(v);
    } else if (i < 13696) {                // w1p: 4 m x 256 dw, natural k
        int j = i - 12672;
        int m = j >> 8, rr = (j >> 4) & 15, gg = (j >> 2) & 3, dd = j & 3;
        const float* s = w1 + (size_t)(16 * m + rr) * 32 + 8 * gg + 2 * dd;
        wpre[i] = pkbf(s[0], s[1]);
    } else if (i < 17792) {                // w2p: 16 (m*2+kt) x 256 dw, remapped
        int j = i - 13696;
        int mk = j >> 8, m = mk >> 1, kt = mk & 1;
        int rr = (j >> 4) & 15, gg = (j >> 2) & 3, dd = j & 3;
        int row = 16 * m + rr;
        int c0 = 32 * kt + 16 * (dd >> 1) + 4 * gg + 2 * (dd & 1);
        const float* s = w2 + (size_t)row * 64 + c0;
        wpre[i] = pkbf(s[0], s[1]);
    }
}

// ---------------- K1: node decompose + mix (lin_w[0..2]) -> Tmh[N][5][64] packed bf16 ----------------
__global__ __launch_bounds__(512) void k1_node_mix(
    const float* __restrict__ X, const float* __restrict__ lw,
    unsigned* __restrict__ Tmh, int nnodes)
{
    __shared__ float Wl[3 * 64 * 68];      // padded rows (68 dwords, 16B-aligned)
    const int tid = threadIdx.x;
#pragma unroll
    for (int k = 0; k < 6; k++) {          // stage lw[0..2]: 12288 floats coalesced
        int l = (tid + k * 512) * 4;
        int row = l >> 6, col = l & 63;
        *(float4*)&Wl[row * 68 + col] = *(const float4*)(lw + l);
    }

    const int wid = tid >> 6, lane = tid & 63;
    const int n = blockIdx.x * 8 + wid;
    const bool valid = (n < nnodes);

    float i0 = 0, i1 = 0, i2 = 0, i3 = 0, i4 = 0, i5 = 0, i6 = 0, i7 = 0, i8 = 0;
    if (valid) {
        const float* xp = X + ((size_t)n * 64 + lane) * 9;
        float v[9];
#pragma unroll
        for (int i = 0; i < 9; i++) v[i] = xp[i];
        float tn = 0.f;
#pragma unroll
        for (int i = 0; i < 9; i++) tn = fmaf(v[i], v[i], tn);
        float inv = 1.0f / (tn + 1.0f);
#pragma unroll
        for (int i = 0; i < 9; i++) v[i] *= inv;
        float lam = (v[0] + v[4] + v[8]) * (1.0f / 3.0f);
        i0 = lam;
        i1 = (v[1] - v[3]) * 0.5f;
        i2 = (v[2] - v[6]) * 0.5f;
        i3 = (v[5] - v[7]) * 0.5f;
        i4 = v[0] - lam;
        i5 = (v[1] + v[3]) * 0.5f;
        i6 = (v[2] + v[6]) * 0.5f;
        i7 = v[4] - lam;
        i8 = (v[5] + v[7]) * 0.5f;
    }
    __syncthreads();

    const int g = lane;
    float a0 = 0, a1 = 0, a2 = 0, a3 = 0, a4 = 0, a5 = 0, a6 = 0, a7 = 0, a8 = 0;
#pragma unroll
    for (int h4 = 0; h4 < 64; h4 += 4) {
        float4 w0 = *(const float4*)&Wl[g * 68 + h4];
        float4 w1 = *(const float4*)&Wl[(64 + g) * 68 + h4];
        float4 w2 = *(const float4*)&Wl[(128 + g) * 68 + h4];
#pragma unroll
        for (int j = 0; j < 4; j++) {
            const int h = h4 + j;
            float wa = (&w0.x)[j], wb = (&w1.x)[j], wc = (&w2.x)[j];
            a0 = fmaf(wa, rdl(i0, h), a0);
            a1 = fmaf(wb, rdl(i1, h), a1);
            a2 = fmaf(wb, rdl(i2, h), a2);
            a3 = fmaf(wb, rdl(i3, h), a3);
            a4 = fmaf(wc, rdl(i4, h), a4);
            a5 = fmaf(wc, rdl(i5, h), a5);
            a6 = fmaf(wc, rdl(i6, h), a6);
            a7 = fmaf(wc, rdl(i7, h), a7);
            a8 = fmaf(wc, rdl(i8, h), a8);
        }
    }
    if (valid) {
        unsigned* outp = Tmh + (size_t)n * 320 + g;
        outp[0 * 64] = pkbf(a0, a1);
        outp[1 * 64] = pkbf(a2, a3);
        outp[2 * 64] = pkbf(a4, a5);
        outp[3 * 64] = pkbf(a6, a7);
        outp[4 * 64] = pkbf(a8, 0.f);
    }
}

// ---------------- K2f: fused edge MLP (MFMA, transposed) + accumulate + k3 ----------------
// 16 waves/block (LDS-capped at 1 block/CU -> 4 waves/SIMD -> 128 VGPR budget).
// q[8][5] Tmh prefetch: edges 0-7 under L3 MFMA; 8-11 / 12-15 rotated in during accumulate.
// LDS: w3p frag-linear [0,49152) | biases [49152,50688) | 16 per-wave ef tiles (16 x 408 B).
#define LBI 49152
#define LEF 50688
#define EFS 408
#define NW  16

__global__ __launch_bounds__(1024, 1) void k2f_fused(
    const float* __restrict__ ea, const float* __restrict__ dist,
    const int* __restrict__ perm, const int* __restrict__ col_s,
    const int* __restrict__ off, const unsigned* __restrict__ wpre,
    const unsigned* __restrict__ Tmh, float* __restrict__ out, int nrows)
{
    __shared__ __align__(16) char smem[LEF + NW * 16 * EFS];   // 155136 B
    const int tid = threadIdx.x;

    // stage w3p + biases -> LDS, linear coalesced (12672 dw = 3168 uint4)
#pragma unroll
    for (int k = 0; k < 4; k++) {
        int idx = tid + k * 1024;
        if (idx < 3168)
            ((uint4*)smem)[idx] = ((const uint4*)wpre)[idx];
    }

    const int wid = tid >> 6, lane = tid & 63;
    const int r16 = lane & 15, g = lane >> 4;
    const int slot = r16 * 4 + g;
    char* efb = smem + LEF + wid * (16 * EFS);

    // W1/W2 A-frags from prepped blob (contiguous 1KB windows per wave)
    bf8_t aw1[4];
#pragma unroll
    for (int m = 0; m < 4; m++)
        aw1[m] = *(const bf8_t*)(wpre + 12672 + (m * 64 + slot) * 4);
    bf8_t aw2[8][2];
#pragma unroll
    for (int m = 0; m < 8; m++)
#pragma unroll
        for (int kt = 0; kt < 2; kt++)
            aw2[m][kt] = *(const bf8_t*)(wpre + 13696 + ((m * 2 + kt) * 64 + slot) * 4);
    __syncthreads();

    const int r = blockIdx.x * NW + wid;
    if (r >= nrows) return;
    const int beg = off[r];
    const int deg = off[r + 1] - beg;

    float acc[9];
#pragma unroll
    for (int i = 0; i < 9; i++) acc[i] = 0.f;

    // ---- prefetch chunk 0's edge data ----
    float4 nv0 = {0, 0, 0, 0}, nv1 = {0, 0, 0, 0};
    float nd = 1e9f;
    int nval = 0;
    if (deg > 0) {
        int cnt0 = min(16, deg);
        int e0 = perm[beg + ((r16 < cnt0) ? r16 : 0)];
        const float* ar0 = ea + (size_t)e0 * NR + 8 * g;
        nv0 = *(const float4*)(ar0);
        nv1 = *(const float4*)(ar0 + 4);
        nd = dist[e0];
        nval = (r16 < cnt0) ? 1 : 0;
    }

#pragma unroll 1
    for (int c0 = 0; c0 < deg; c0 += 16) {
        const int cnt = min(16, deg - c0);

        // cols of this chunk (lane r16 holds edge r16's col; clamped for pads)
        int colv = col_s[beg + c0 + ((r16 < cnt) ? r16 : (cnt - 1))];

        // build B-frag + cutoff from prefetched regs
        bf8_t bx;
        {
            union { bf8_t v; unsigned u[4]; } tt;
            tt.u[0] = pkbf(nv0.x, nv0.y); tt.u[1] = pkbf(nv0.z, nv0.w);
            tt.u[2] = pkbf(nv1.x, nv1.y); tt.u[3] = pkbf(nv1.z, nv1.w);
            bx = tt.v;
        }
        float cf = (nval && nd < 5.0f)
                 ? 0.5f * (__cosf(nd * 0.62831853071795864f) + 1.0f) : 0.0f;

        // ---- L1 ----
        unsigned pk1[4][2];
#pragma unroll
        for (int m = 0; m < 4; m++) {
            f4_t c = *(const f4_t*)(smem + LBI + (16 * m + 4 * g) * 4);
            c = __builtin_amdgcn_mfma_f32_16x16x32_bf16(aw1[m], bx, c, 0, 0, 0);
            pk1[m][0] = pkbf(silu_f(c[0]), silu_f(c[1]));
            pk1[m][1] = pkbf(silu_f(c[2]), silu_f(c[3]));
        }
        bf8_t B2[2];
        {
            union { bf8_t v; unsigned u[4]; } ta, tb;
            ta.u[0] = pk1[0][0]; ta.u[1] = pk1[0][1]; ta.u[2] = pk1[1][0]; ta.u[3] = pk1[1][1];
            tb.u[0] = pk1[2][0]; tb.u[1] = pk1[2][1]; tb.u[2] = pk1[3][0]; tb.u[3] = pk1[3][1];
            B2[0] = ta.v; B2[1] = tb.v;
        }

        // ---- L2 ----
        unsigned pk2[8][2];
#pragma unroll
        for (int m = 0; m < 8; m++) {
            f4_t c = *(const f4_t*)(smem + LBI + (64 + 16 * m + 4 * g) * 4);
            c = __builtin_amdgcn_mfma_f32_16x16x32_bf16(aw2[m][0], B2[0], c, 0, 0, 0);
            c = __builtin_amdgcn_mfma_f32_16x16x32_bf16(aw2[m][1], B2[1], c, 0, 0, 0);
            pk2[m][0] = pkbf(silu_f(c[0]), silu_f(c[1]));
            pk2[m][1] = pkbf(silu_f(c[2]), silu_f(c[3]));
        }
        bf8_t B3[4];
#pragma unroll
        for (int kt = 0; kt < 4; kt++) {
            union { bf8_t v; unsigned u[4]; } tt;
            tt.u[0] = pk2[2 * kt][0]; tt.u[1] = pk2[2 * kt][1];
            tt.u[2] = pk2[2 * kt + 1][0]; tt.u[3] = pk2[2 * kt + 1][1];
            B3[kt] = tt.v;
        }

        // ---- Tmh gather prefetch, edges 0..7 (hidden under L3 MFMAs) ----
        unsigned q[8][5];
#pragma unroll
        for (int s = 0; s < 8; s++) {
            int sc = __builtin_amdgcn_readlane(colv, s);
            const unsigned* t = Tmh + (size_t)(unsigned)sc * 320 + lane;
            q[s][0] = t[0]; q[s][1] = t[64]; q[s][2] = t[128];
            q[s][3] = t[192]; q[s][4] = t[256];
        }

        // ---- issue next chunk's ea prefetch ----
        {
            int c1 = c0 + 16;
            if (c1 < deg) {
                int cnt1 = min(16, deg - c1);
                int e1 = perm[beg + c1 + ((r16 < cnt1) ? r16 : 0)];
                const float* ar1 = ea + (size_t)e1 * NR + 8 * g;
                nv0 = *(const float4*)(ar1);
                nv1 = *(const float4*)(ar1 + 4);
                nd = dist[e1];
                nval = (r16 < cnt1) ? 1 : 0;
            }
        }

        // ---- drain prior chunk's LDS reads before overwriting the tile ----
        asm volatile("s_waitcnt lgkmcnt(0)" ::: "memory");
        __builtin_amdgcn_sched_barrier(0);

        // ---- L3 + cutoff -> per-wave LDS ef tile ----
#pragma unroll
        for (int m = 0; m < 12; m++) {
            f4_t c = *(const f4_t*)(smem + LBI + (192 + 16 * m + 4 * g) * 4);
#pragma unroll
            for (int kt = 0; kt < 4; kt++) {
                bf8_t aw = *(const bf8_t*)(smem + ((m * 4 + kt) * 64 + slot) * 16);
                c = __builtin_amdgcn_mfma_f32_16x16x32_bf16(aw, B3[kt], c, 0, 0, 0);
            }
            union { struct { __half2 a, b; } h; uint2 u; } pu;
            pu.h.a = __float22half2_rn(make_float2(c[0] * cf, c[1] * cf));
            pu.h.b = __float22half2_rn(make_float2(c[2] * cf, c[3] * cf));
            *(uint2*)(efb + r16 * EFS + (16 * m + 4 * g) * 2) = pu.u;
        }
        asm volatile("s_waitcnt lgkmcnt(0)" ::: "memory");
        __builtin_amdgcn_sched_barrier(0);

        // ---- accumulate (branchless over 16 slots; padded slots carry f=0) ----
#define ACC_STEP(S, Q)                                                        \
        {                                                                     \
            const __half* fp = (const __half*)(efb + (S) * EFS + 6 * lane);   \
            float f0 = __half2float(fp[0]);                                   \
            float f1 = __half2float(fp[1]);                                   \
            float f2 = __half2float(fp[2]);                                   \
            acc[0] = fmaf(f0, bf_lo(Q[0]), acc[0]);                           \
            acc[1] = fmaf(f1, bf_hi(Q[0]), acc[1]);                           \
            acc[2] = fmaf(f1, bf_lo(Q[1]), acc[2]);                           \
            acc[3] = fmaf(f1, bf_hi(Q[1]), acc[3]);                           \
            acc[4] = fmaf(f2, bf_lo(Q[2]), acc[4]);                           \
            acc[5] = fmaf(f2, bf_hi(Q[2]), acc[5]);                           \
            acc[6] = fmaf(f2, bf_lo(Q[3]), acc[6]);                           \
            acc[7] = fmaf(f2, bf_hi(Q[3]), acc[7]);                           \
            acc[8] = fmaf(f2, bf_lo(Q[4]), acc[8]);                           \
        }
#define LOAD_Q(DST, S)                                                        \
        {                                                                     \
            int sc = __builtin_amdgcn_readlane(colv, (S));                    \
            const unsigned* t = Tmh + (size_t)(unsigned)sc * 320 + lane;      \
            DST[0] = t[0]; DST[1] = t[64]; DST[2] = t[128];                   \
            DST[3] = t[192]; DST[4] = t[256];                                 \
        }

        ACC_STEP(0, q[0]) ACC_STEP(1, q[1]) ACC_STEP(2, q[2]) ACC_STEP(3, q[3])
        LOAD_Q(q[0], 8)  LOAD_Q(q[1], 9)  LOAD_Q(q[2], 10) LOAD_Q(q[3], 11)
        ACC_STEP(4, q[4]) ACC_STEP(5, q[5]) ACC_STEP(6, q[6]) ACC_STEP(7, q[7])
        LOAD_Q(q[4], 12) LOAD_Q(q[5], 13) LOAD_Q(q[6], 14) LOAD_Q(q[7], 15)
        ACC_STEP(8, q[0])  ACC_STEP(9, q[1])  ACC_STEP(10, q[2]) ACC_STEP(11, q[3])
        ACC_STEP(12, q[4]) ACC_STEP(13, q[5]) ACC_STEP(14, q[6]) ACC_STEP(15, q[7])
#undef ACC_STEP
#undef LOAD_Q
    }

    // ---- fused k3: prod = M@Y + Y@M, decompose, /norm -> out (pc comp-major) ----
    float y[9];
    {
        const unsigned* tp = Tmh + (size_t)r * 320 + lane;
        unsigned q0 = tp[0], q1 = tp[64], q2 = tp[128], q3 = tp[192], q4 = tp[256];
        y[0] = bf_lo(q0); y[1] = bf_hi(q0); y[2] = bf_lo(q1); y[3] = bf_hi(q1);
        y[4] = bf_lo(q2); y[5] = bf_hi(q2); y[6] = bf_lo(q3); y[7] = bf_hi(q3);
        y[8] = bf_lo(q4);
    }
    float Y[9], Mm[9];
    Y[0] = y[0] + y[4]; Y[1] = y[1] + y[5]; Y[2] = y[2] + y[6];
    Y[3] = -y[1] + y[5]; Y[4] = y[0] + y[7]; Y[5] = y[3] + y[8];
    Y[6] = -y[2] + y[6]; Y[7] = -y[3] + y[8]; Y[8] = y[0] - y[4] - y[7];
    Mm[0] = acc[0] + acc[4]; Mm[1] = acc[1] + acc[5]; Mm[2] = acc[2] + acc[6];
    Mm[3] = -acc[1] + acc[5]; Mm[4] = acc[0] + acc[7]; Mm[5] = acc[3] + acc[8];
    Mm[6] = -acc[2] + acc[6]; Mm[7] = -acc[3] + acc[8]; Mm[8] = acc[0] - acc[4] - acc[7];
    float P[9];
#pragma unroll
    for (int a = 0; a < 3; a++)
#pragma unroll
        for (int b = 0; b < 3; b++) {
            float s = 0.f;
#pragma unroll
            for (int c = 0; c < 3; c++) {
                s = fmaf(Mm[a * 3 + c], Y[c * 3 + b], s);
                s = fmaf(Y[a * 3 + c], Mm[c * 3 + b], s);
            }
            P[a * 3 + b] = s;
        }
    float tn = 0.f;
#pragma unroll
    for (int k = 0; k < 9; k++) tn = fmaf(P[k], P[k], tn);
    float inv = 1.0f / (tn + 1.0f);
    float lam = (P[0] + P[4] + P[8]) * (1.0f / 3.0f);

    float* mp = out + (size_t)r * 576 + lane;
    mp[0 * 64] = lam * inv;
    mp[1 * 64] = (P[1] - P[3]) * 0.5f * inv;
    mp[2 * 64] = (P[2] - P[6]) * 0.5f * inv;
    mp[3 * 64] = (P[5] - P[7]) * 0.5f * inv;
    mp[4 * 64] = (P[0] - lam) * inv;
    mp[5 * 64] = (P[1] + P[3]) * 0.5f * inv;
    mp[6 * 64] = (P[2] + P[6]) * 0.5f * inv;
    mp[7 * 64] = (P[4] - lam) * inv;
    mp[8 * 64] = (P[5] + P[7]) * 0.5f * inv;
}

// ---------------- K4: mix (lin_w[3..5]) -> dX; out = Xn + dX + dX@dX (in-place over pc) ----------------
__global__ __launch_bounds__(512) void k4_final(
    const float* __restrict__ X, const float* __restrict__ lw,
    float* __restrict__ out, int nnodes)
{
    __shared__ float Wl[3 * 64 * 68];
    const int tid = threadIdx.x;
#pragma unroll
    for (int k = 0; k < 6; k++) {          // stage lw[3..5]
        int l = (tid + k * 512) * 4;
        int row = l >> 6, col = l & 63;
        *(float4*)&Wl[row * 68 + col] = *(const float4*)(lw + 3 * 4096 + l);
    }

    const int wid = tid >> 6, lane = tid & 63;
    const int n = blockIdx.x * 8 + wid;
    const bool valid = (n < nnodes);

    float i0 = 0, i1 = 0, i2 = 0, i3 = 0, i4 = 0, i5 = 0, i6 = 0, i7 = 0, i8 = 0;
    if (valid) {
        const float* pp = out + (size_t)n * 576 + lane;   // pc comp-major [n][9][64]
        i0 = pp[0 * 64]; i1 = pp[1 * 64]; i2 = pp[2 * 64];
        i3 = pp[3 * 64]; i4 = pp[4 * 64]; i5 = pp[5 * 64];
        i6 = pp[6 * 64]; i7 = pp[7 * 64]; i8 = pp[8 * 64];
    }
    __syncthreads();

    const int g = lane;
    float a0 = 0, a1 = 0, a2 = 0, a3 = 0, a4 = 0, a5 = 0, a6 = 0, a7 = 0, a8 = 0;
#pragma unroll
    for (int h4 = 0; h4 < 64; h4 += 4) {
        float4 w0 = *(const float4*)&Wl[g * 68 + h4];
        float4 w1 = *(const float4*)&Wl[(64 + g) * 68 + h4];
        float4 w2 = *(const float4*)&Wl[(128 + g) * 68 + h4];
#pragma unroll
        for (int j = 0; j < 4; j++) {
            const int h = h4 + j;
            float wa = (&w0.x)[j], wb = (&w1.x)[j], wc = (&w2.x)[j];
            a0 = fmaf(wa, rdl(i0, h), a0);
            a1 = fmaf(wb, rdl(i1, h), a1);
            a2 = fmaf(wb, rdl(i2, h), a2);
            a3 = fmaf(wb, rdl(i3, h), a3);
            a4 = fmaf(wc, rdl(i4, h), a4);
            a5 = fmaf(wc, rdl(i5, h), a5);
            a6 = fmaf(wc, rdl(i6, h), a6);
            a7 = fmaf(wc, rdl(i7, h), a7);
            a8 = fmaf(wc, rdl(i8, h), a8);
        }
    }

    if (valid) {
        float D[9];
        D[0] = a0 + a4; D[1] = a1 + a5; D[2] = a2 + a6;
        D[3] = -a1 + a5; D[4] = a0 + a7; D[5] = a3 + a8;
        D[6] = -a2 + a6; D[7] = -a3 + a8; D[8] = a0 - a4 - a7;

        const float* xp = X + ((size_t)n * 64 + g) * 9;
        float xv[9];
#pragma unroll
        for (int i = 0; i < 9; i++) xv[i] = xp[i];
        float tn = 0.f;
#pragma unroll
        for (int i = 0; i < 9; i++) tn = fmaf(xv[i], xv[i], tn);
        float inv = 1.0f / (tn + 1.0f);

        float* op = out + ((size_t)n * 64 + g) * 9;   // final [N][64][3][3]
        float res[9];
#pragma unroll
        for (int a = 0; a < 3; a++)
#pragma unroll
            for (int b = 0; b < 3; b++) {
                float dd = 0.f;
#pragma unroll
                for (int c = 0; c < 3; c++) dd = fmaf(D[a * 3 + c], D[c * 3 + b], dd);
                res[a * 3 + b] = xv[a * 3 + b] * inv + D[a * 3 + b] + dd;
            }
#pragma unroll
        for (int i = 0; i < 9; i++) op[i] = res[i];
    }
}

extern "C" void kernel_launch(void* const* d_in, const int* in_sizes, int n_in,
                              void* d_out, int out_size, void* d_ws, size_t ws_size,
                              hipStream_t stream)
{
    const float* X    = (const float*)d_in[0];
    const int*   eidx = (const int*)d_in[1];
    const float* dist = (const float*)d_in[2];
    const float* ea   = (const float*)d_in[3];
    const float* w1   = (const float*)d_in[4];
    const float* b1   = (const float*)d_in[5];
    const float* w2   = (const float*)d_in[6];
    const float* b2   = (const float*)d_in[7];
    const float* w3   = (const float*)d_in[8];
    const float* b3   = (const float*)d_in[9];
    const float* lw   = (const float*)d_in[10];
    float* outp = (float*)d_out;

    const int nnodes = in_sizes[0] / (64 * 9);   // 20000
    const int nedges = in_sizes[2];              // 320000

    unsigned* Tmh  = (unsigned*)d_ws;                       // N*320 dwords (packed bf16 pairs)
    int* cur       = (int*)(Tmh + (size_t)nnodes * 320);
    int* off       = cur + nnodes;                          // nnodes+1
    int* perm      = off + nnodes + 1;                      // nedges
    int* col_s     = perm + nedges;                         // nedges
    unsigned* wpre = (unsigned*)(col_s + nedges);           // 17792 dwords

    // CSR build (edges sorted by destination row; col pre-gathered)
    hipMemsetAsync(cur, 0, (size_t)nnodes * sizeof(int), stream);
    k_hist<<<(nedges + 255) / 256, 256, 0, stream>>>(eidx, cur, nedges);
    k_scan2<<<1, 1024, 0, stream>>>(cur, off, nnodes);
    k_scatter<<<(nedges + 255) / 256, 256, 0, stream>>>(eidx, cur, perm, col_s, nedges);
    k_prep<<<70, 256, 0, stream>>>(w1, b1, w2, b2, w3, b3, wpre);

    k1_node_mix<<<(nnodes + 7) / 8, 512, 0, stream>>>(X, lw, Tmh, nnodes);
    k2f_fused<<<(nnodes + NW - 1) / NW, 1024, 0, stream>>>(ea, dist, perm, col_s, off, wpre, Tmh, outp, nnodes);
    k4_final<<<(nnodes + 7) / 8, 512, 0, stream>>>(X, lw, outp, nnodes);
}

// Round 15
// 444.113 us; speedup vs baseline: 1.2915x; 1.2629x over previous
//
#include <hip/hip_runtime.h>
#include <hip/hip_fp16.h>
#include <hip/hip_bf16.h>

#define NR 32

typedef __attribute__((ext_vector_type(8))) short bf8_t;   // 8 x bf16 (4 VGPR)
typedef __attribute__((ext_vector_type(4))) float f4_t;

__device__ __forceinline__ float silu_f(float x) {
    return x * __builtin_amdgcn_rcpf(1.0f + __expf(-x));
}

__device__ __forceinline__ unsigned pkbf(float lo, float hi) {
    __hip_bfloat162 h = __float22bfloat162_rn(make_float2(lo, hi));
    union { __hip_bfloat162 h2; unsigned u; } cv; cv.h2 = h; return cv.u;
}
__device__ __forceinline__ float bf_lo(unsigned u) { return __uint_as_float(u << 16); }
__device__ __forceinline__ float bf_hi(unsigned u) { return __uint_as_float(u & 0xffff0000u); }

__device__ __forceinline__ float rdl(float v, int l) {
    return __int_as_float(__builtin_amdgcn_readlane(__float_as_int(v), l));
}

// ---------------- CSR build ----------------
__global__ __launch_bounds__(256) void k_hist(
    const int* __restrict__ eidx, int* __restrict__ cnt, int nedges)
{
    int e = blockIdx.x * 256 + threadIdx.x;
    if (e < nedges) atomicAdd(&cnt[eidx[e]], 1);
}

__global__ __launch_bounds__(1024) void k_scan2(
    int* __restrict__ cnt, int* __restrict__ off, int n)
{
    __shared__ int wsum[16];
    __shared__ int wbase[16];
    const int tid = threadIdx.x;
    const int lane = tid & 63, wid = tid >> 6;
    const int per = (n + 1023) >> 10;
    const int base = tid * per;
    int s = 0;
    for (int i = 0; i < per; i++) {
        int idx = base + i;
        if (idx < n) s += cnt[idx];
    }
    int incl = s;
    for (int d = 1; d < 64; d <<= 1) {
        int t = __shfl_up(incl, d);
        if (lane >= d) incl += t;
    }
    if (lane == 63) wsum[wid] = incl;
    __syncthreads();
    if (wid == 0) {
        int v = (lane < 16) ? wsum[lane] : 0;
        int inc2 = v;
        for (int d = 1; d < 16; d <<= 1) {
            int t = __shfl_up(inc2, d);
            if (lane >= d) inc2 += t;
        }
        if (lane < 16) wbase[lane] = inc2 - v;
        if (lane == 15) off[n] = inc2;
    }
    __syncthreads();
    int run = wbase[wid] + incl - s;
    for (int i = 0; i < per; i++) {
        int idx = base + i;
        if (idx < n) {
            int v = cnt[idx];
            off[idx] = run;
            cnt[idx] = run;
            run += v;
        }
    }
}

__global__ __launch_bounds__(256) void k_scatter(
    const int* __restrict__ eidx, int* __restrict__ cur,
    int* __restrict__ perm, int* __restrict__ col_s, int nedges)
{
    int e = blockIdx.x * 256 + threadIdx.x;
    if (e < nedges) {
        int r = eidx[e];
        int pos = atomicAdd(&cur[r], 1);
        perm[pos] = e;
        col_s[pos] = eidx[nedges + e];
    }
}

// ---------------- K_prep: bake bf16 frag-linear remapped weight blob ----------------
// blob dwords: [0,12288) w3p | [12288,12672) biases f32 | [12672,13696) w1p | [13696,17792) w2p
// frag slot order: slot = r*4+g, dword dd; k-remap c0 = 32*kt + 16*(dd>>1) + 4*g + 2*(dd&1)
__global__ __launch_bounds__(256) void k_prep(
    const float* __restrict__ w1, const float* __restrict__ b1,
    const float* __restrict__ w2, const float* __restrict__ b2,
    const float* __restrict__ w3, const float* __restrict__ b3,
    unsigned* __restrict__ wpre)
{
    int i = blockIdx.x * 256 + threadIdx.x;
    if (i < 12288) {                       // w3p: 48 (m*4+kt) x 256 dw
        int mk = i >> 8, m = mk >> 2, kt = mk & 3;
        int rr = (i >> 4) & 15, gg = (i >> 2) & 3, dd = i & 3;
        int row = 16 * m + rr;
        int c0 = 32 * kt + 16 * (dd >> 1) + 4 * gg + 2 * (dd & 1);
        const float* s = w3 + (size_t)row * 128 + c0;
        wpre[i] = pkbf(s[0], s[1]);
    } else if (i < 12672) {                // biases: b1[64] b2[128] b3[192]
        int j = i - 12288;
        float v = (j < 64) ? b1[j] : (j < 192) ? b2[j - 64] : b3[j - 192];
        wpre[i] = __float_as_uint(v);
    } else if (i < 13696) {                // w1p: 4 m x 256 dw, natural k
        int j = i - 12672;
        int m = j >> 8, rr = (j >> 4) & 15, gg = (j >> 2) & 3, dd = j & 3;
        const float* s = w1 + (size_t)(16 * m + rr) * 32 + 8 * gg + 2 * dd;
        wpre[i] = pkbf(s[0], s[1]);
    } else if (i < 17792) {                // w2p: 16 (m*2+kt) x 256 dw, remapped
        int j = i - 13696;
        int mk = j >> 8, m = mk >> 1, kt = mk & 1;
        int rr = (j >> 4) & 15, gg = (j >> 2) & 3, dd = j & 3;
        int row = 16 * m + rr;
        int c0 = 32 * kt + 16 * (dd >> 1) + 4 * gg + 2 * (dd & 1);
        const float* s = w2 + (size_t)row * 64 + c0;
        wpre[i] = pkbf(s[0], s[1]);
    }
}

// ---------------- K1: node decompose + mix (lin_w[0..2]) -> Tmh[N][5][64] packed bf16 ----------------
__global__ __launch_bounds__(512) void k1_node_mix(
    const float* __restrict__ X, const float* __restrict__ lw,
    unsigned* __restrict__ Tmh, int nnodes)
{
    __shared__ float Wl[3 * 64 * 68];      // padded rows (68 dwords, 16B-aligned)
    const int tid = threadIdx.x;
#pragma unroll
    for (int k = 0; k < 6; k++) {          // stage lw[0..2]: 12288 floats coalesced
        int l = (tid + k * 512) * 4;
        int row = l >> 6, col = l & 63;
        *(float4*)&Wl[row * 68 + col] = *(const float4*)(lw + l);
    }

    const int wid = tid >> 6, lane = tid & 63;
    const int n = blockIdx.x * 8 + wid;
    const bool valid = (n < nnodes);

    float i0 = 0, i1 = 0, i2 = 0, i3 = 0, i4 = 0, i5 = 0, i6 = 0, i7 = 0, i8 = 0;
    if (valid) {
        const float* xp = X + ((size_t)n * 64 + lane) * 9;
        float v[9];
#pragma unroll
        for (int i = 0; i < 9; i++) v[i] = xp[i];
        float tn = 0.f;
#pragma unroll
        for (int i = 0; i < 9; i++) tn = fmaf(v[i], v[i], tn);
        float inv = 1.0f / (tn + 1.0f);
#pragma unroll
        for (int i = 0; i < 9; i++) v[i] *= inv;
        float lam = (v[0] + v[4] + v[8]) * (1.0f / 3.0f);
        i0 = lam;
        i1 = (v[1] - v[3]) * 0.5f;
        i2 = (v[2] - v[6]) * 0.5f;
        i3 = (v[5] - v[7]) * 0.5f;
        i4 = v[0] - lam;
        i5 = (v[1] + v[3]) * 0.5f;
        i6 = (v[2] + v[6]) * 0.5f;
        i7 = v[4] - lam;
        i8 = (v[5] + v[7]) * 0.5f;
    }
    __syncthreads();

    const int g = lane;
    float a0 = 0, a1 = 0, a2 = 0, a3 = 0, a4 = 0, a5 = 0, a6 = 0, a7 = 0, a8 = 0;
#pragma unroll
    for (int h4 = 0; h4 < 64; h4 += 4) {
        float4 w0 = *(const float4*)&Wl[g * 68 + h4];
        float4 w1 = *(const float4*)&Wl[(64 + g) * 68 + h4];
        float4 w2 = *(const float4*)&Wl[(128 + g) * 68 + h4];
#pragma unroll
        for (int j = 0; j < 4; j++) {
            const int h = h4 + j;
            float wa = (&w0.x)[j], wb = (&w1.x)[j], wc = (&w2.x)[j];
            a0 = fmaf(wa, rdl(i0, h), a0);
            a1 = fmaf(wb, rdl(i1, h), a1);
            a2 = fmaf(wb, rdl(i2, h), a2);
            a3 = fmaf(wb, rdl(i3, h), a3);
            a4 = fmaf(wc, rdl(i4, h), a4);
            a5 = fmaf(wc, rdl(i5, h), a5);
            a6 = fmaf(wc, rdl(i6, h), a6);
            a7 = fmaf(wc, rdl(i7, h), a7);
            a8 = fmaf(wc, rdl(i8, h), a8);
        }
    }
    if (valid) {
        unsigned* outp = Tmh + (size_t)n * 320 + g;
        outp[0 * 64] = pkbf(a0, a1);
        outp[1 * 64] = pkbf(a2, a3);
        outp[2 * 64] = pkbf(a4, a5);
        outp[3 * 64] = pkbf(a6, a7);
        outp[4 * 64] = pkbf(a8, 0.f);
    }
}

// ---------------- K2f: fused edge MLP (MFMA, transposed) + accumulate + k3 ----------------
// 14 waves/block, 896 thr; W2+W3 frags in LDS (frag-linear); q[8][5] Tmh prefetch.
// amdgpu_waves_per_eu(4,4): pin register budget to 128 VGPR (kills the 64-VGPR/spill heuristic).
// LDS: w3p [0,49152) | biases [49152,50688) | w2p [50688,67072) | 14 ef tiles (16 x 408 B).
#define LBI 49152
#define LW2 50688
#define LEF 67072
#define EFS 408
#define NW  14

__global__
__attribute__((amdgpu_flat_work_group_size(896, 896)))
__attribute__((amdgpu_waves_per_eu(4, 4)))
void k2f_fused(
    const float* __restrict__ ea, const float* __restrict__ dist,
    const int* __restrict__ perm, const int* __restrict__ col_s,
    const int* __restrict__ off, const unsigned* __restrict__ wpre,
    const unsigned* __restrict__ Tmh, float* __restrict__ out, int nrows)
{
    __shared__ __align__(16) char smem[LEF + NW * 16 * EFS];   // 158464 B
    const int tid = threadIdx.x;

    // stage w3p+biases [0,12672)dw -> LDS 0 ; w2p [13696,17792)dw -> LDS 50688 (coalesced uint4)
#pragma unroll
    for (int k = 0; k < 5; k++) {
        int idx = tid + k * 896;
        if (idx < 3168)
            ((uint4*)smem)[idx] = ((const uint4*)wpre)[idx];
        else if (idx < 4192)
            ((uint4*)(smem + LW2))[idx - 3168] = ((const uint4*)(wpre + 13696))[idx - 3168];
    }

    const int wid = tid >> 6, lane = tid & 63;
    const int r16 = lane & 15, g = lane >> 4;
    const int slot = r16 * 4 + g;
    char* efb = smem + LEF + wid * (16 * EFS);

    // W1 A-frags in registers (16 VGPR)
    bf8_t aw1[4];
#pragma unroll
    for (int m = 0; m < 4; m++)
        aw1[m] = *(const bf8_t*)(wpre + 12672 + (m * 64 + slot) * 4);
    __syncthreads();

    const int r = blockIdx.x * NW + wid;
    if (r >= nrows) return;
    const int beg = off[r];
    const int deg = off[r + 1] - beg;

    float acc[9];
#pragma unroll
    for (int i = 0; i < 9; i++) acc[i] = 0.f;

    // ---- prefetch chunk 0's edge data ----
    float4 nv0 = {0, 0, 0, 0}, nv1 = {0, 0, 0, 0};
    float nd = 1e9f;
    int nval = 0;
    if (deg > 0) {
        int cnt0 = min(16, deg);
        int e0 = perm[beg + ((r16 < cnt0) ? r16 : 0)];
        const float* ar0 = ea + (size_t)e0 * NR + 8 * g;
        nv0 = *(const float4*)(ar0);
        nv1 = *(const float4*)(ar0 + 4);
        nd = dist[e0];
        nval = (r16 < cnt0) ? 1 : 0;
    }

#pragma unroll 1
    for (int c0 = 0; c0 < deg; c0 += 16) {
        const int cnt = min(16, deg - c0);

        // cols of this chunk (lane r16 holds edge r16's col; clamped for pads)
        int colv = col_s[beg + c0 + ((r16 < cnt) ? r16 : (cnt - 1))];

        // build B-frag + cutoff from prefetched regs
        bf8_t bx;
        {
            union { bf8_t v; unsigned u[4]; } tt;
            tt.u[0] = pkbf(nv0.x, nv0.y); tt.u[1] = pkbf(nv0.z, nv0.w);
            tt.u[2] = pkbf(nv1.x, nv1.y); tt.u[3] = pkbf(nv1.z, nv1.w);
            bx = tt.v;
        }
        float cf = (nval && nd < 5.0f)
                 ? 0.5f * (__cosf(nd * 0.62831853071795864f) + 1.0f) : 0.0f;

        // ---- L1 ----
        unsigned pk1[4][2];
#pragma unroll
        for (int m = 0; m < 4; m++) {
            f4_t c = *(const f4_t*)(smem + LBI + (16 * m + 4 * g) * 4);
            c = __builtin_amdgcn_mfma_f32_16x16x32_bf16(aw1[m], bx, c, 0, 0, 0);
            pk1[m][0] = pkbf(silu_f(c[0]), silu_f(c[1]));
            pk1[m][1] = pkbf(silu_f(c[2]), silu_f(c[3]));
        }
        bf8_t B2[2];
        {
            union { bf8_t v; unsigned u[4]; } ta, tb;
            ta.u[0] = pk1[0][0]; ta.u[1] = pk1[0][1]; ta.u[2] = pk1[1][0]; ta.u[3] = pk1[1][1];
            tb.u[0] = pk1[2][0]; tb.u[1] = pk1[2][1]; tb.u[2] = pk1[3][0]; tb.u[3] = pk1[3][1];
            B2[0] = ta.v; B2[1] = tb.v;
        }

        // ---- L2 (W2 frags from LDS, frag-linear conflict-free) ----
        unsigned pk2[8][2];
#pragma unroll
        for (int m = 0; m < 8; m++) {
            f4_t c = *(const f4_t*)(smem + LBI + (64 + 16 * m + 4 * g) * 4);
#pragma unroll
            for (int kt = 0; kt < 2; kt++) {
                bf8_t aw = *(const bf8_t*)(smem + LW2 + ((m * 2 + kt) * 64 + slot) * 16);
                c = __builtin_amdgcn_mfma_f32_16x16x32_bf16(aw, B2[kt], c, 0, 0, 0);
            }
            pk2[m][0] = pkbf(silu_f(c[0]), silu_f(c[1]));
            pk2[m][1] = pkbf(silu_f(c[2]), silu_f(c[3]));
        }
        bf8_t B3[4];
#pragma unroll
        for (int kt = 0; kt < 4; kt++) {
            union { bf8_t v; unsigned u[4]; } tt;
            tt.u[0] = pk2[2 * kt][0]; tt.u[1] = pk2[2 * kt][1];
            tt.u[2] = pk2[2 * kt + 1][0]; tt.u[3] = pk2[2 * kt + 1][1];
            B3[kt] = tt.v;
        }

        // ---- Tmh gather prefetch, edges 0..7 (hidden under L3 MFMAs) ----
        unsigned q[8][5];
#pragma unroll
        for (int s = 0; s < 8; s++) {
            int sc = __builtin_amdgcn_readlane(colv, s);
            const unsigned* t = Tmh + (size_t)(unsigned)sc * 320 + lane;
            q[s][0] = t[0]; q[s][1] = t[64]; q[s][2] = t[128];
            q[s][3] = t[192]; q[s][4] = t[256];
        }

        // ---- issue next chunk's ea prefetch ----
        {
            int c1 = c0 + 16;
            if (c1 < deg) {
                int cnt1 = min(16, deg - c1);
                int e1 = perm[beg + c1 + ((r16 < cnt1) ? r16 : 0)];
                const float* ar1 = ea + (size_t)e1 * NR + 8 * g;
                nv0 = *(const float4*)(ar1);
                nv1 = *(const float4*)(ar1 + 4);
                nd = dist[e1];
                nval = (r16 < cnt1) ? 1 : 0;
            }
        }

        // ---- drain prior chunk's LDS reads before overwriting the tile ----
        asm volatile("s_waitcnt lgkmcnt(0)" ::: "memory");
        __builtin_amdgcn_sched_barrier(0);

        // ---- L3 + cutoff -> per-wave LDS ef tile ----
#pragma unroll
        for (int m = 0; m < 12; m++) {
            f4_t c = *(const f4_t*)(smem + LBI + (192 + 16 * m + 4 * g) * 4);
#pragma unroll
            for (int kt = 0; kt < 4; kt++) {
                bf8_t aw = *(const bf8_t*)(smem + ((m * 4 + kt) * 64 + slot) * 16);
                c = __builtin_amdgcn_mfma_f32_16x16x32_bf16(aw, B3[kt], c, 0, 0, 0);
            }
            union { struct { __half2 a, b; } h; uint2 u; } pu;
            pu.h.a = __float22half2_rn(make_float2(c[0] * cf, c[1] * cf));
            pu.h.b = __float22half2_rn(make_float2(c[2] * cf, c[3] * cf));
            *(uint2*)(efb + r16 * EFS + (16 * m + 4 * g) * 2) = pu.u;
        }
        asm volatile("s_waitcnt lgkmcnt(0)" ::: "memory");
        __builtin_amdgcn_sched_barrier(0);

        // ---- accumulate (branchless over 16 slots; padded slots carry f=0) ----
#define ACC_STEP(S, Q)                                                        \
        {                                                                     \
            const __half* fp = (const __half*)(efb + (S) * EFS + 6 * lane);   \
            float f0 = __half2float(fp[0]);                                   \
            float f1 = __half2float(fp[1]);                                   \
            float f2 = __half2float(fp[2]);                                   \
            acc[0] = fmaf(f0, bf_lo(Q[0]), acc[0]);                           \
            acc[1] = fmaf(f1, bf_hi(Q[0]), acc[1]);                           \
            acc[2] = fmaf(f1, bf_lo(Q[1]), acc[2]);                           \
            acc[3] = fmaf(f1, bf_hi(Q[1]), acc[3]);                           \
            acc[4] = fmaf(f2, bf_lo(Q[2]), acc[4]);                           \
            acc[5] = fmaf(f2, bf_hi(Q[2]), acc[5]);                           \
            acc[6] = fmaf(f2, bf_lo(Q[3]), acc[6]);                           \
            acc[7] = fmaf(f2, bf_hi(Q[3]), acc[7]);                           \
            acc[8] = fmaf(f2, bf_lo(Q[4]), acc[8]);                           \
        }
#define LOAD_Q(DST, S)                                                        \
        {                                                                     \
            int sc = __builtin_amdgcn_readlane(colv, (S));                    \
            const unsigned* t = Tmh + (size_t)(unsigned)sc * 320 + lane;      \
            DST[0] = t[0]; DST[1] = t[64]; DST[2] = t[128];                   \
            DST[3] = t[192]; DST[4] = t[256];                                 \
        }

        ACC_STEP(0, q[0]) ACC_STEP(1, q[1]) ACC_STEP(2, q[2]) ACC_STEP(3, q[3])
        LOAD_Q(q[0], 8)  LOAD_Q(q[1], 9)  LOAD_Q(q[2], 10) LOAD_Q(q[3], 11)
        ACC_STEP(4, q[4]) ACC_STEP(5, q[5]) ACC_STEP(6, q[6]) ACC_STEP(7, q[7])
        LOAD_Q(q[4], 12) LOAD_Q(q[5], 13) LOAD_Q(q[6], 14) LOAD_Q(q[7], 15)
        ACC_STEP(8, q[0])  ACC_STEP(9, q[1])  ACC_STEP(10, q[2]) ACC_STEP(11, q[3])
        ACC_STEP(12, q[4]) ACC_STEP(13, q[5]) ACC_STEP(14, q[6]) ACC_STEP(15, q[7])
#undef ACC_STEP
#undef LOAD_Q
    }

    // ---- fused k3: prod = M@Y + Y@M, decompose, /norm -> out (pc comp-major) ----
    float y[9];
    {
        const unsigned* tp = Tmh + (size_t)r * 320 + lane;
        unsigned q0 = tp[0], q1 = tp[64], q2 = tp[128], q3 = tp[192], q4 = tp[256];
        y[0] = bf_lo(q0); y[1] = bf_hi(q0); y[2] = bf_lo(q1); y[3] = bf_hi(q1);
        y[4] = bf_lo(q2); y[5] = bf_hi(q2); y[6] = bf_lo(q3); y[7] = bf_hi(q3);
        y[8] = bf_lo(q4);
    }
    float Y[9], Mm[9];
    Y[0] = y[0] + y[4]; Y[1] = y[1] + y[5]; Y[2] = y[2] + y[6];
    Y[3] = -y[1] + y[5]; Y[4] = y[0] + y[7]; Y[5] = y[3] + y[8];
    Y[6] = -y[2] + y[6]; Y[7] = -y[3] + y[8]; Y[8] = y[0] - y[4] - y[7];
    Mm[0] = acc[0] + acc[4]; Mm[1] = acc[1] + acc[5]; Mm[2] = acc[2] + acc[6];
    Mm[3] = -acc[1] + acc[5]; Mm[4] = acc[0] + acc[7]; Mm[5] = acc[3] + acc[8];
    Mm[6] = -acc[2] + acc[6]; Mm[7] = -acc[3] + acc[8]; Mm[8] = acc[0] - acc[4] - acc[7];
    float P[9];
#pragma unroll
    for (int a = 0; a < 3; a++)
#pragma unroll
        for (int b = 0; b < 3; b++) {
            float s = 0.f;
#pragma unroll
            for (int c = 0; c < 3; c++) {
                s = fmaf(Mm[a * 3 + c], Y[c * 3 + b], s);
                s = fmaf(Y[a * 3 + c], Mm[c * 3 + b], s);
            }
            P[a * 3 + b] = s;
        }
    float tn = 0.f;
#pragma unroll
    for (int k = 0; k < 9; k++) tn = fmaf(P[k], P[k], tn);
    float inv = 1.0f / (tn + 1.0f);
    float lam = (P[0] + P[4] + P[8]) * (1.0f / 3.0f);

    float* mp = out + (size_t)r * 576 + lane;
    mp[0 * 64] = lam * inv;
    mp[1 * 64] = (P[1] - P[3]) * 0.5f * inv;
    mp[2 * 64] = (P[2] - P[6]) * 0.5f * inv;
    mp[3 * 64] = (P[5] - P[7]) * 0.5f * inv;
    mp[4 * 64] = (P[0] - lam) * inv;
    mp[5 * 64] = (P[1] + P[3]) * 0.5f * inv;
    mp[6 * 64] = (P[2] + P[6]) * 0.5f * inv;
    mp[7 * 64] = (P[4] - lam) * inv;
    mp[8 * 64] = (P[5] + P[7]) * 0.5f * inv;
}

// ---------------- K4: mix (lin_w[3..5]) -> dX; out = Xn + dX + dX@dX (in-place over pc) ----------------
__global__ __launch_bounds__(512) void k4_final(
    const float* __restrict__ X, const float* __restrict__ lw,
    float* __restrict__ out, int nnodes)
{
    __shared__ float Wl[3 * 64 * 68];
    const int tid = threadIdx.x;
#pragma unroll
    for (int k = 0; k < 6; k++) {          // stage lw[3..5]
        int l = (tid + k * 512) * 4;
        int row = l >> 6, col = l & 63;
        *(float4*)&Wl[row * 68 + col] = *(const float4*)(lw + 3 * 4096 + l);
    }

    const int wid = tid >> 6, lane = tid & 63;
    const int n = blockIdx.x * 8 + wid;
    const bool valid = (n < nnodes);

    float i0 = 0, i1 = 0, i2 = 0, i3 = 0, i4 = 0, i5 = 0, i6 = 0, i7 = 0, i8 = 0;
    if (valid) {
        const float* pp = out + (size_t)n * 576 + lane;   // pc comp-major [n][9][64]
        i0 = pp[0 * 64]; i1 = pp[1 * 64]; i2 = pp[2 * 64];
        i3 = pp[3 * 64]; i4 = pp[4 * 64]; i5 = pp[5 * 64];
        i6 = pp[6 * 64]; i7 = pp[7 * 64]; i8 = pp[8 * 64];
    }
    __syncthreads();

    const int g = lane;
    float a0 = 0, a1 = 0, a2 = 0, a3 = 0, a4 = 0, a5 = 0, a6 = 0, a7 = 0, a8 = 0;
#pragma unroll
    for (int h4 = 0; h4 < 64; h4 += 4) {
        float4 w0 = *(const float4*)&Wl[g * 68 + h4];
        float4 w1 = *(const float4*)&Wl[(64 + g) * 68 + h4];
        float4 w2 = *(const float4*)&Wl[(128 + g) * 68 + h4];
#pragma unroll
        for (int j = 0; j < 4; j++) {
            const int h = h4 + j;
            float wa = (&w0.x)[j], wb = (&w1.x)[j], wc = (&w2.x)[j];
            a0 = fmaf(wa, rdl(i0, h), a0);
            a1 = fmaf(wb, rdl(i1, h), a1);
            a2 = fmaf(wb, rdl(i2, h), a2);
            a3 = fmaf(wb, rdl(i3, h), a3);
            a4 = fmaf(wc, rdl(i4, h), a4);
            a5 = fmaf(wc, rdl(i5, h), a5);
            a6 = fmaf(wc, rdl(i6, h), a6);
            a7 = fmaf(wc, rdl(i7, h), a7);
            a8 = fmaf(wc, rdl(i8, h), a8);
        }
    }

    if (valid) {
        float D[9];
        D[0] = a0 + a4; D[1] = a1 + a5; D[2] = a2 + a6;
        D[3] = -a1 + a5; D[4] = a0 + a7; D[5] = a3 + a8;
        D[6] = -a2 + a6; D[7] = -a3 + a8; D[8] = a0 - a4 - a7;

        const float* xp = X + ((size_t)n * 64 + g) * 9;
        float xv[9];
#pragma unroll
        for (int i = 0; i < 9; i++) xv[i] = xp[i];
        float tn = 0.f;
#pragma unroll
        for (int i = 0; i < 9; i++) tn = fmaf(xv[i], xv[i], tn);
        float inv = 1.0f / (tn + 1.0f);

        float* op = out + ((size_t)n * 64 + g) * 9;   // final [N][64][3][3]
        float res[9];
#pragma unroll
        for (int a = 0; a < 3; a++)
#pragma unroll
            for (int b = 0; b < 3; b++) {
                float dd = 0.f;
#pragma unroll
                for (int c = 0; c < 3; c++) dd = fmaf(D[a * 3 + c], D[c * 3 + b], dd);
                res[a * 3 + b] = xv[a * 3 + b] * inv + D[a * 3 + b] + dd;
            }
#pragma unroll
        for (int i = 0; i < 9; i++) op[i] = res[i];
    }
}

extern "C" void kernel_launch(void* const* d_in, const int* in_sizes, int n_in,
                              void* d_out, int out_size, void* d_ws, size_t ws_size,
                              hipStream_t stream)
{
    const float* X    = (const float*)d_in[0];
    const int*   eidx = (const int*)d_in[1];
    const float* dist = (const float*)d_in[2];
    const float* ea   = (const float*)d_in[3];
    const float* w1   = (const float*)d_in[4];
    const float* b1   = (const float*)d_in[5];
    const float* w2   = (const float*)d_in[6];
    const float* b2   = (const float*)d_in[7];
    const float* w3   = (const float*)d_in[8];
    const float* b3   = (const float*)d_in[9];
    const float* lw   = (const float*)d_in[10];
    float* outp = (float*)d_out;

    const int nnodes = in_sizes[0] / (64 * 9);   // 20000
    const int nedges = in_sizes[2];              // 320000

    unsigned* Tmh  = (unsigned*)d_ws;                       // N*320 dwords (packed bf16 pairs)
    int* cur       = (int*)(Tmh + (size_t)nnodes * 320);
    int* off       = cur + nnodes;                          // nnodes+1
    int* perm      = off + nnodes + 1;                      // nedges
    int* col_s     = perm + nedges;                         // nedges
    unsigned* wpre = (unsigned*)(col_s + nedges);           // 17792 dwords

    // CSR build (edges sorted by destination row; col pre-gathered)
    hipMemsetAsync(cur, 0, (size_t)nnodes * sizeof(int), stream);
    k_hist<<<(nedges + 255) / 256, 256, 0, stream>>>(eidx, cur, nedges);
    k_scan2<<<1, 1024, 0, stream>>>(cur, off, nnodes);
    k_scatter<<<(nedges + 255) / 256, 256, 0, stream>>>(eidx, cur, perm, col_s, nedges);
    k_prep<<<70, 256, 0, stream>>>(w1, b1, w2, b2, w3, b3, wpre);

    k1_node_mix<<<(nnodes + 7) / 8, 512, 0, stream>>>(X, lw, Tmh, nnodes);
    k2f_fused<<<(nnodes + NW - 1) / NW, 64 * NW, 0, stream>>>(ea, dist, perm, col_s, off, wpre, Tmh, outp, nnodes);
    k4_final<<<(nnodes + 7) / 8, 512, 0, stream>>>(X, lw, outp, nnodes);
}

// Round 16
// 405.083 us; speedup vs baseline: 1.4160x; 1.0964x over previous
//
#include <hip/hip_runtime.h>
#include <hip/hip_fp16.h>
#include <hip/hip_bf16.h>

#define NR 32

typedef __attribute__((ext_vector_type(8))) short bf8_t;   // 8 x bf16 (4 VGPR)
typedef __attribute__((ext_vector_type(4))) float f4_t;

__device__ __forceinline__ float silu_f(float x) {
    return x * __builtin_amdgcn_rcpf(1.0f + __expf(-x));
}

__device__ __forceinline__ unsigned pkbf(float lo, float hi) {
    __hip_bfloat162 h = __float22bfloat162_rn(make_float2(lo, hi));
    union { __hip_bfloat162 h2; unsigned u; } cv; cv.h2 = h; return cv.u;
}
__device__ __forceinline__ float bf_lo(unsigned u) { return __uint_as_float(u << 16); }
__device__ __forceinline__ float bf_hi(unsigned u) { return __uint_as_float(u & 0xffff0000u); }

__device__ __forceinline__ float rdl(float v, int l) {
    return __int_as_float(__builtin_amdgcn_readlane(__float_as_int(v), l));
}

// ---------------- CSR build ----------------
__global__ __launch_bounds__(256) void k_hist(
    const int* __restrict__ eidx, int* __restrict__ cnt, int nedges)
{
    int e = blockIdx.x * 256 + threadIdx.x;
    if (e < nedges) atomicAdd(&cnt[eidx[e]], 1);
}

__global__ __launch_bounds__(1024) void k_scan2(
    int* __restrict__ cnt, int* __restrict__ off, int n)
{
    __shared__ int wsum[16];
    __shared__ int wbase[16];
    const int tid = threadIdx.x;
    const int lane = tid & 63, wid = tid >> 6;
    const int per = (n + 1023) >> 10;
    const int base = tid * per;
    int s = 0;
    for (int i = 0; i < per; i++) {
        int idx = base + i;
        if (idx < n) s += cnt[idx];
    }
    int incl = s;
    for (int d = 1; d < 64; d <<= 1) {
        int t = __shfl_up(incl, d);
        if (lane >= d) incl += t;
    }
    if (lane == 63) wsum[wid] = incl;
    __syncthreads();
    if (wid == 0) {
        int v = (lane < 16) ? wsum[lane] : 0;
        int inc2 = v;
        for (int d = 1; d < 16; d <<= 1) {
            int t = __shfl_up(inc2, d);
            if (lane >= d) inc2 += t;
        }
        if (lane < 16) wbase[lane] = inc2 - v;
        if (lane == 15) off[n] = inc2;
    }
    __syncthreads();
    int run = wbase[wid] + incl - s;
    for (int i = 0; i < per; i++) {
        int idx = base + i;
        if (idx < n) {
            int v = cnt[idx];
            off[idx] = run;
            cnt[idx] = run;
            run += v;
        }
    }
}

__global__ __launch_bounds__(256) void k_scatter(
    const int* __restrict__ eidx, int* __restrict__ cur,
    int* __restrict__ perm, int* __restrict__ col_s, int nedges)
{
    int e = blockIdx.x * 256 + threadIdx.x;
    if (e < nedges) {
        int r = eidx[e];
        int pos = atomicAdd(&cur[r], 1);
        perm[pos] = e;
        col_s[pos] = eidx[nedges + e];
    }
}

// ---------------- K_prep: bake bf16 frag-linear remapped weight blob ----------------
// blob dwords: [0,12288) w3p | [12288,12672) biases f32 | [12672,13696) w1p | [13696,17792) w2p
// frag slot order: slot = r*4+g, dword dd; k-remap c0 = 32*kt + 16*(dd>>1) + 4*g + 2*(dd&1)
__global__ __launch_bounds__(256) void k_prep(
    const float* __restrict__ w1, const float* __restrict__ b1,
    const float* __restrict__ w2, const float* __restrict__ b2,
    const float* __restrict__ w3, const float* __restrict__ b3,
    unsigned* __restrict__ wpre)
{
    int i = blockIdx.x * 256 + threadIdx.x;
    if (i < 12288) {                       // w3p: 48 (m*4+kt) x 256 dw
        int mk = i >> 8, m = mk >> 2, kt = mk & 3;
        int rr = (i >> 4) & 15, gg = (i >> 2) & 3, dd = i & 3;
        int row = 16 * m + rr;
        int c0 = 32 * kt + 16 * (dd >> 1) + 4 * gg + 2 * (dd & 1);
        const float* s = w3 + (size_t)row * 128 + c0;
        wpre[i] = pkbf(s[0], s[1]);
    } else if (i < 12672) {                // biases: b1[64] b2[128] b3[192]
        int j = i - 12288;
        float v = (j < 64) ? b1[j] : (j < 192) ? b2[j - 64] : b3[j - 192];
        wpre[i] = __float_as_uint(v);
    } else if (i < 13696) {                // w1p: 4 m x 256 dw, natural k
        int j = i - 12672;
        int m = j >> 8, rr = (j >> 4) & 15, gg = (j >> 2) & 3, dd = j & 3;
        const float* s = w1 + (size_t)(16 * m + rr) * 32 + 8 * gg + 2 * dd;
        wpre[i] = pkbf(s[0], s[1]);
    } else if (i < 17792) {                // w2p: 16 (m*2+kt) x 256 dw, remapped
        int j = i - 13696;
        int mk = j >> 8, m = mk >> 1, kt = mk & 1;
        int rr = (j >> 4) & 15, gg = (j >> 2) & 3, dd = j & 3;
        int row = 16 * m + rr;
        int c0 = 32 * kt + 16 * (dd >> 1) + 4 * gg + 2 * (dd & 1);
        const float* s = w2 + (size_t)row * 64 + c0;
        wpre[i] = pkbf(s[0], s[1]);
    }
}

// ---------------- K1: node decompose + mix (lin_w[0..2]) -> Tmh[N][5][64] packed bf16 ----------------
__global__ __launch_bounds__(512) void k1_node_mix(
    const float* __restrict__ X, const float* __restrict__ lw,
    unsigned* __restrict__ Tmh, int nnodes)
{
    __shared__ float Wl[3 * 64 * 68];      // padded rows (68 dwords, 16B-aligned)
    const int tid = threadIdx.x;
#pragma unroll
    for (int k = 0; k < 6; k++) {          // stage lw[0..2]: 12288 floats coalesced
        int l = (tid + k * 512) * 4;
        int row = l >> 6, col = l & 63;
        *(float4*)&Wl[row * 68 + col] = *(const float4*)(lw + l);
    }

    const int wid = tid >> 6, lane = tid & 63;
    const int n = blockIdx.x * 8 + wid;
    const bool valid = (n < nnodes);

    float i0 = 0, i1 = 0, i2 = 0, i3 = 0, i4 = 0, i5 = 0, i6 = 0, i7 = 0, i8 = 0;
    if (valid) {
        const float* xp = X + ((size_t)n * 64 + lane) * 9;
        float v[9];
#pragma unroll
        for (int i = 0; i < 9; i++) v[i] = xp[i];
        float tn = 0.f;
#pragma unroll
        for (int i = 0; i < 9; i++) tn = fmaf(v[i], v[i], tn);
        float inv = 1.0f / (tn + 1.0f);
#pragma unroll
        for (int i = 0; i < 9; i++) v[i] *= inv;
        float lam = (v[0] + v[4] + v[8]) * (1.0f / 3.0f);
        i0 = lam;
        i1 = (v[1] - v[3]) * 0.5f;
        i2 = (v[2] - v[6]) * 0.5f;
        i3 = (v[5] - v[7]) * 0.5f;
        i4 = v[0] - lam;
        i5 = (v[1] + v[3]) * 0.5f;
        i6 = (v[2] + v[6]) * 0.5f;
        i7 = v[4] - lam;
        i8 = (v[5] + v[7]) * 0.5f;
    }
    __syncthreads();

    const int g = lane;
    float a0 = 0, a1 = 0, a2 = 0, a3 = 0, a4 = 0, a5 = 0, a6 = 0, a7 = 0, a8 = 0;
#pragma unroll
    for (int h4 = 0; h4 < 64; h4 += 4) {
        float4 w0 = *(const float4*)&Wl[g * 68 + h4];
        float4 w1 = *(const float4*)&Wl[(64 + g) * 68 + h4];
        float4 w2 = *(const float4*)&Wl[(128 + g) * 68 + h4];
#pragma unroll
        for (int j = 0; j < 4; j++) {
            const int h = h4 + j;
            float wa = (&w0.x)[j], wb = (&w1.x)[j], wc = (&w2.x)[j];
            a0 = fmaf(wa, rdl(i0, h), a0);
            a1 = fmaf(wb, rdl(i1, h), a1);
            a2 = fmaf(wb, rdl(i2, h), a2);
            a3 = fmaf(wb, rdl(i3, h), a3);
            a4 = fmaf(wc, rdl(i4, h), a4);
            a5 = fmaf(wc, rdl(i5, h), a5);
            a6 = fmaf(wc, rdl(i6, h), a6);
            a7 = fmaf(wc, rdl(i7, h), a7);
            a8 = fmaf(wc, rdl(i8, h), a8);
        }
    }
    if (valid) {
        unsigned* outp = Tmh + (size_t)n * 320 + g;
        outp[0 * 64] = pkbf(a0, a1);
        outp[1 * 64] = pkbf(a2, a3);
        outp[2 * 64] = pkbf(a4, a5);
        outp[3 * 64] = pkbf(a6, a7);
        outp[4 * 64] = pkbf(a8, 0.f);
    }
}

// ---------------- K2f: fused edge MLP (MFMA, transposed) + accumulate + k3 ----------------
// 14 waves/block, 896 thr; W1+W2+W3 frags ALL in LDS; q[4][5] rotated Tmh prefetch.
// Designed to fit 64 VGPR (no spill): persistent ~25 + peak transients ~35.
// LDS: blob [0,71168): w3p 0 | biases 49152 | w1p 50688 | w2p 54784 ; 14 ef tiles @71168.
#define LBI 49152
#define LW1P 50688
#define LW2P 54784
#define LEF 71168
#define EFS 408
#define NW  14

__global__
__attribute__((amdgpu_flat_work_group_size(896, 896)))
__attribute__((amdgpu_waves_per_eu(3)))
void k2f_fused(
    const float* __restrict__ ea, const float* __restrict__ dist,
    const int* __restrict__ perm, const int* __restrict__ col_s,
    const int* __restrict__ off, const unsigned* __restrict__ wpre,
    const unsigned* __restrict__ Tmh, float* __restrict__ out, int nrows)
{
    __shared__ __align__(16) char smem[LEF + NW * 16 * EFS];   // 162560 B
    const int tid = threadIdx.x;

    // stage whole weight blob (17792 dw = 4448 uint4) -> LDS linearly, coalesced
#pragma unroll
    for (int k = 0; k < 5; k++) {
        int idx = tid + k * 896;
        if (idx < 4448)
            ((uint4*)smem)[idx] = ((const uint4*)wpre)[idx];
    }

    const int wid = tid >> 6, lane = tid & 63;
    const int r16 = lane & 15, g = lane >> 4;
    const int slot = r16 * 4 + g;
    char* efb = smem + LEF + wid * (16 * EFS);
    __syncthreads();

    const int r = blockIdx.x * NW + wid;
    if (r >= nrows) return;
    const int beg = off[r];
    const int deg = off[r + 1] - beg;

    float acc[9];
#pragma unroll
    for (int i = 0; i < 9; i++) acc[i] = 0.f;

    // ---- prefetch chunk 0's edge data ----
    float4 nv0 = {0, 0, 0, 0}, nv1 = {0, 0, 0, 0};
    float nd = 1e9f;
    int nval = 0;
    if (deg > 0) {
        int cnt0 = min(16, deg);
        int e0 = perm[beg + ((r16 < cnt0) ? r16 : 0)];
        const float* ar0 = ea + (size_t)e0 * NR + 8 * g;
        nv0 = *(const float4*)(ar0);
        nv1 = *(const float4*)(ar0 + 4);
        nd = dist[e0];
        nval = (r16 < cnt0) ? 1 : 0;
    }

#pragma unroll 1
    for (int c0 = 0; c0 < deg; c0 += 16) {
        const int cnt = min(16, deg - c0);

        // cols of this chunk (lane r16 holds edge r16's col; clamped for pads)
        int colv = col_s[beg + c0 + ((r16 < cnt) ? r16 : (cnt - 1))];

        // build B-frag + cutoff from prefetched regs
        bf8_t bx;
        {
            union { bf8_t v; unsigned u[4]; } tt;
            tt.u[0] = pkbf(nv0.x, nv0.y); tt.u[1] = pkbf(nv0.z, nv0.w);
            tt.u[2] = pkbf(nv1.x, nv1.y); tt.u[3] = pkbf(nv1.z, nv1.w);
            bx = tt.v;
        }
        float cf = (nval && nd < 5.0f)
                 ? 0.5f * (__cosf(nd * 0.62831853071795864f) + 1.0f) : 0.0f;

        // ---- L1 (W1 frags from LDS) ----
        unsigned pk1[4][2];
#pragma unroll
        for (int m = 0; m < 4; m++) {
            f4_t c = *(const f4_t*)(smem + LBI + (16 * m + 4 * g) * 4);
            bf8_t aw = *(const bf8_t*)(smem + LW1P + (m * 64 + slot) * 16);
            c = __builtin_amdgcn_mfma_f32_16x16x32_bf16(aw, bx, c, 0, 0, 0);
            pk1[m][0] = pkbf(silu_f(c[0]), silu_f(c[1]));
            pk1[m][1] = pkbf(silu_f(c[2]), silu_f(c[3]));
        }
        bf8_t B2[2];
        {
            union { bf8_t v; unsigned u[4]; } ta, tb;
            ta.u[0] = pk1[0][0]; ta.u[1] = pk1[0][1]; ta.u[2] = pk1[1][0]; ta.u[3] = pk1[1][1];
            tb.u[0] = pk1[2][0]; tb.u[1] = pk1[2][1]; tb.u[2] = pk1[3][0]; tb.u[3] = pk1[3][1];
            B2[0] = ta.v; B2[1] = tb.v;
        }

        // ---- L2 (W2 frags from LDS) ----
        unsigned pk2[8][2];
#pragma unroll
        for (int m = 0; m < 8; m++) {
            f4_t c = *(const f4_t*)(smem + LBI + (64 + 16 * m + 4 * g) * 4);
#pragma unroll
            for (int kt = 0; kt < 2; kt++) {
                bf8_t aw = *(const bf8_t*)(smem + LW2P + ((m * 2 + kt) * 64 + slot) * 16);
                c = __builtin_amdgcn_mfma_f32_16x16x32_bf16(aw, B2[kt], c, 0, 0, 0);
            }
            pk2[m][0] = pkbf(silu_f(c[0]), silu_f(c[1]));
            pk2[m][1] = pkbf(silu_f(c[2]), silu_f(c[3]));
        }
        bf8_t B3[4];
#pragma unroll
        for (int kt = 0; kt < 4; kt++) {
            union { bf8_t v; unsigned u[4]; } tt;
            tt.u[0] = pk2[2 * kt][0]; tt.u[1] = pk2[2 * kt][1];
            tt.u[2] = pk2[2 * kt + 1][0]; tt.u[3] = pk2[2 * kt + 1][1];
            B3[kt] = tt.v;
        }

        // ---- Tmh gather prefetch, edges 0..3 (q[4][5] = 20 VGPR; in flight during L3) ----
        unsigned q[4][5];
#pragma unroll
        for (int s = 0; s < 4; s++) {
            int sc = __builtin_amdgcn_readlane(colv, s);
            const unsigned* t = Tmh + (size_t)(unsigned)sc * 320 + lane;
            q[s][0] = t[0]; q[s][1] = t[64]; q[s][2] = t[128];
            q[s][3] = t[192]; q[s][4] = t[256];
        }

        // ---- issue next chunk's ea prefetch ----
        {
            int c1 = c0 + 16;
            if (c1 < deg) {
                int cnt1 = min(16, deg - c1);
                int e1 = perm[beg + c1 + ((r16 < cnt1) ? r16 : 0)];
                const float* ar1 = ea + (size_t)e1 * NR + 8 * g;
                nv0 = *(const float4*)(ar1);
                nv1 = *(const float4*)(ar1 + 4);
                nd = dist[e1];
                nval = (r16 < cnt1) ? 1 : 0;
            }
        }

        // ---- drain prior chunk's LDS reads before overwriting the tile ----
        asm volatile("s_waitcnt lgkmcnt(0)" ::: "memory");
        __builtin_amdgcn_sched_barrier(0);

        // ---- L3 + cutoff -> per-wave LDS ef tile ----
#pragma unroll
        for (int m = 0; m < 12; m++) {
            f4_t c = *(const f4_t*)(smem + LBI + (192 + 16 * m + 4 * g) * 4);
#pragma unroll
            for (int kt = 0; kt < 4; kt++) {
                bf8_t aw = *(const bf8_t*)(smem + ((m * 4 + kt) * 64 + slot) * 16);
                c = __builtin_amdgcn_mfma_f32_16x16x32_bf16(aw, B3[kt], c, 0, 0, 0);
            }
            union { struct { __half2 a, b; } h; uint2 u; } pu;
            pu.h.a = __float22half2_rn(make_float2(c[0] * cf, c[1] * cf));
            pu.h.b = __float22half2_rn(make_float2(c[2] * cf, c[3] * cf));
            *(uint2*)(efb + r16 * EFS + (16 * m + 4 * g) * 2) = pu.u;
        }
        asm volatile("s_waitcnt lgkmcnt(0)" ::: "memory");
        __builtin_amdgcn_sched_barrier(0);

        // ---- accumulate: depth-4 rotation (reload each q slot right after last use) ----
#define ACC_STEP(S, Q)                                                        \
        {                                                                     \
            const __half* fp = (const __half*)(efb + (S) * EFS + 6 * lane);   \
            float f0 = __half2float(fp[0]);                                   \
            float f1 = __half2float(fp[1]);                                   \
            float f2 = __half2float(fp[2]);                                   \
            acc[0] = fmaf(f0, bf_lo(Q[0]), acc[0]);                           \
            acc[1] = fmaf(f1, bf_hi(Q[0]), acc[1]);                           \
            acc[2] = fmaf(f1, bf_lo(Q[1]), acc[2]);                           \
            acc[3] = fmaf(f1, bf_hi(Q[1]), acc[3]);                           \
            acc[4] = fmaf(f2, bf_lo(Q[2]), acc[4]);                           \
            acc[5] = fmaf(f2, bf_hi(Q[2]), acc[5]);                           \
            acc[6] = fmaf(f2, bf_lo(Q[3]), acc[6]);                           \
            acc[7] = fmaf(f2, bf_hi(Q[3]), acc[7]);                           \
            acc[8] = fmaf(f2, bf_lo(Q[4]), acc[8]);                           \
        }
#define LOAD_Q(DST, S)                                                        \
        {                                                                     \
            int sc = __builtin_amdgcn_readlane(colv, (S));                    \
            const unsigned* t = Tmh + (size_t)(unsigned)sc * 320 + lane;      \
            DST[0] = t[0]; DST[1] = t[64]; DST[2] = t[128];                   \
            DST[3] = t[192]; DST[4] = t[256];                                 \
        }

        ACC_STEP(0, q[0])  LOAD_Q(q[0], 4)
        ACC_STEP(1, q[1])  LOAD_Q(q[1], 5)
        ACC_STEP(2, q[2])  LOAD_Q(q[2], 6)
        ACC_STEP(3, q[3])  LOAD_Q(q[3], 7)
        ACC_STEP(4, q[0])  LOAD_Q(q[0], 8)
        ACC_STEP(5, q[1])  LOAD_Q(q[1], 9)
        ACC_STEP(6, q[2])  LOAD_Q(q[2], 10)
        ACC_STEP(7, q[3])  LOAD_Q(q[3], 11)
        ACC_STEP(8, q[0])  LOAD_Q(q[0], 12)
        ACC_STEP(9, q[1])  LOAD_Q(q[1], 13)
        ACC_STEP(10, q[2]) LOAD_Q(q[2], 14)
        ACC_STEP(11, q[3]) LOAD_Q(q[3], 15)
        ACC_STEP(12, q[0]) ACC_STEP(13, q[1]) ACC_STEP(14, q[2]) ACC_STEP(15, q[3])
#undef ACC_STEP
#undef LOAD_Q
    }

    // ---- fused k3: prod = M@Y + Y@M, decompose, /norm -> out (pc comp-major) ----
    float y[9];
    {
        const unsigned* tp = Tmh + (size_t)r * 320 + lane;
        unsigned q0 = tp[0], q1 = tp[64], q2 = tp[128], q3 = tp[192], q4 = tp[256];
        y[0] = bf_lo(q0); y[1] = bf_hi(q0); y[2] = bf_lo(q1); y[3] = bf_hi(q1);
        y[4] = bf_lo(q2); y[5] = bf_hi(q2); y[6] = bf_lo(q3); y[7] = bf_hi(q3);
        y[8] = bf_lo(q4);
    }
    float Y[9], Mm[9];
    Y[0] = y[0] + y[4]; Y[1] = y[1] + y[5]; Y[2] = y[2] + y[6];
    Y[3] = -y[1] + y[5]; Y[4] = y[0] + y[7]; Y[5] = y[3] + y[8];
    Y[6] = -y[2] + y[6]; Y[7] = -y[3] + y[8]; Y[8] = y[0] - y[4] - y[7];
    Mm[0] = acc[0] + acc[4]; Mm[1] = acc[1] + acc[5]; Mm[2] = acc[2] + acc[6];
    Mm[3] = -acc[1] + acc[5]; Mm[4] = acc[0] + acc[7]; Mm[5] = acc[3] + acc[8];
    Mm[6] = -acc[2] + acc[6]; Mm[7] = -acc[3] + acc[8]; Mm[8] = acc[0] - acc[4] - acc[7];
    float P[9];
#pragma unroll
    for (int a = 0; a < 3; a++)
#pragma unroll
        for (int b = 0; b < 3; b++) {
            float s = 0.f;
#pragma unroll
            for (int c = 0; c < 3; c++) {
                s = fmaf(Mm[a * 3 + c], Y[c * 3 + b], s);
                s = fmaf(Y[a * 3 + c], Mm[c * 3 + b], s);
            }
            P[a * 3 + b] = s;
        }
    float tn = 0.f;
#pragma unroll
    for (int k = 0; k < 9; k++) tn = fmaf(P[k], P[k], tn);
    float inv = 1.0f / (tn + 1.0f);
    float lam = (P[0] + P[4] + P[8]) * (1.0f / 3.0f);

    float* mp = out + (size_t)r * 576 + lane;
    mp[0 * 64] = lam * inv;
    mp[1 * 64] = (P[1] - P[3]) * 0.5f * inv;
    mp[2 * 64] = (P[2] - P[6]) * 0.5f * inv;
    mp[3 * 64] = (P[5] - P[7]) * 0.5f * inv;
    mp[4 * 64] = (P[0] - lam) * inv;
    mp[5 * 64] = (P[1] + P[3]) * 0.5f * inv;
    mp[6 * 64] = (P[2] + P[6]) * 0.5f * inv;
    mp[7 * 64] = (P[4] - lam) * inv;
    mp[8 * 64] = (P[5] + P[7]) * 0.5f * inv;
}

// ---------------- K4: mix (lin_w[3..5]) -> dX; out = Xn + dX + dX@dX (in-place over pc) ----------------
__global__ __launch_bounds__(512) void k4_final(
    const float* __restrict__ X, const float* __restrict__ lw,
    float* __restrict__ out, int nnodes)
{
    __shared__ float Wl[3 * 64 * 68];
    const int tid = threadIdx.x;
#pragma unroll
    for (int k = 0; k < 6; k++) {          // stage lw[3..5]
        int l = (tid + k * 512) * 4;
        int row = l >> 6, col = l & 63;
        *(float4*)&Wl[row * 68 + col] = *(const float4*)(lw + 3 * 4096 + l);
    }

    const int wid = tid >> 6, lane = tid & 63;
    const int n = blockIdx.x * 8 + wid;
    const bool valid = (n < nnodes);

    float i0 = 0, i1 = 0, i2 = 0, i3 = 0, i4 = 0, i5 = 0, i6 = 0, i7 = 0, i8 = 0;
    if (valid) {
        const float* pp = out + (size_t)n * 576 + lane;   // pc comp-major [n][9][64]
        i0 = pp[0 * 64]; i1 = pp[1 * 64]; i2 = pp[2 * 64];
        i3 = pp[3 * 64]; i4 = pp[4 * 64]; i5 = pp[5 * 64];
        i6 = pp[6 * 64]; i7 = pp[7 * 64]; i8 = pp[8 * 64];
    }
    __syncthreads();

    const int g = lane;
    float a0 = 0, a1 = 0, a2 = 0, a3 = 0, a4 = 0, a5 = 0, a6 = 0, a7 = 0, a8 = 0;
#pragma unroll
    for (int h4 = 0; h4 < 64; h4 += 4) {
        float4 w0 = *(const float4*)&Wl[g * 68 + h4];
        float4 w1 = *(const float4*)&Wl[(64 + g) * 68 + h4];
        float4 w2 = *(const float4*)&Wl[(128 + g) * 68 + h4];
#pragma unroll
        for (int j = 0; j < 4; j++) {
            const int h = h4 + j;
            float wa = (&w0.x)[j], wb = (&w1.x)[j], wc = (&w2.x)[j];
            a0 = fmaf(wa, rdl(i0, h), a0);
            a1 = fmaf(wb, rdl(i1, h), a1);
            a2 = fmaf(wb, rdl(i2, h), a2);
            a3 = fmaf(wb, rdl(i3, h), a3);
            a4 = fmaf(wc, rdl(i4, h), a4);
            a5 = fmaf(wc, rdl(i5, h), a5);
            a6 = fmaf(wc, rdl(i6, h), a6);
            a7 = fmaf(wc, rdl(i7, h), a7);
            a8 = fmaf(wc, rdl(i8, h), a8);
        }
    }

    if (valid) {
        float D[9];
        D[0] = a0 + a4; D[1] = a1 + a5; D[2] = a2 + a6;
        D[3] = -a1 + a5; D[4] = a0 + a7; D[5] = a3 + a8;
        D[6] = -a2 + a6; D[7] = -a3 + a8; D[8] = a0 - a4 - a7;

        const float* xp = X + ((size_t)n * 64 + g) * 9;
        float xv[9];
#pragma unroll
        for (int i = 0; i < 9; i++) xv[i] = xp[i];
        float tn = 0.f;
#pragma unroll
        for (int i = 0; i < 9; i++) tn = fmaf(xv[i], xv[i], tn);
        float inv = 1.0f / (tn + 1.0f);

        float* op = out + ((size_t)n * 64 + g) * 9;   // final [N][64][3][3]
        float res[9];
#pragma unroll
        for (int a = 0; a < 3; a++)
#pragma unroll
            for (int b = 0; b < 3; b++) {
                float dd = 0.f;
#pragma unroll
                for (int c = 0; c < 3; c++) dd = fmaf(D[a * 3 + c], D[c * 3 + b], dd);
                res[a * 3 + b] = xv[a * 3 + b] * inv + D[a * 3 + b] + dd;
            }
#pragma unroll
        for (int i = 0; i < 9; i++) op[i] = res[i];
    }
}

extern "C" void kernel_launch(void* const* d_in, const int* in_sizes, int n_in,
                              void* d_out, int out_size, void* d_ws, size_t ws_size,
                              hipStream_t stream)
{
    const float* X    = (const float*)d_in[0];
    const int*   eidx = (const int*)d_in[1];
    const float* dist = (const float*)d_in[2];
    const float* ea   = (const float*)d_in[3];
    const float* w1   = (const float*)d_in[4];
    const float* b1   = (const float*)d_in[5];
    const float* w2   = (const float*)d_in[6];
    const float* b2   = (const float*)d_in[7];
    const float* w3   = (const float*)d_in[8];
    const float* b3   = (const float*)d_in[9];
    const float* lw   = (const float*)d_in[10];
    float* outp = (float*)d_out;

    const int nnodes = in_sizes[0] / (64 * 9);   // 20000
    const int nedges = in_sizes[2];              // 320000

    unsigned* Tmh  = (unsigned*)d_ws;                       // N*320 dwords (packed bf16 pairs)
    int* cur       = (int*)(Tmh + (size_t)nnodes * 320);
    int* off       = cur + nnodes;                          // nnodes+1
    int* perm      = off + nnodes + 1;                      // nedges
    int* col_s     = perm + nedges;                         // nedges
    unsigned* wpre = (unsigned*)(col_s + nedges);           // 17792 dwords

    // CSR build (edges sorted by destination row; col pre-gathered)
    hipMemsetAsync(cur, 0, (size_t)nnodes * sizeof(int), stream);
    k_hist<<<(nedges + 255) / 256, 256, 0, stream>>>(eidx, cur, nedges);
    k_scan2<<<1, 1024, 0, stream>>>(cur, off, nnodes);
    k_scatter<<<(nedges + 255) / 256, 256, 0, stream>>>(eidx, cur, perm, col_s, nedges);
    k_prep<<<70, 256, 0, stream>>>(w1, b1, w2, b2, w3, b3, wpre);

    k1_node_mix<<<(nnodes + 7) / 8, 512, 0, stream>>>(X, lw, Tmh, nnodes);
    k2f_fused<<<(nnodes + NW - 1) / NW, 64 * NW, 0, stream>>>(ea, dist, perm, col_s, off, wpre, Tmh, outp, nnodes);
    k4_final<<<(nnodes + 7) / 8, 512, 0, stream>>>(X, lw, outp, nnodes);
}

// Round 17
// 399.416 us; speedup vs baseline: 1.4361x; 1.0142x over previous
//
#include <hip/hip_runtime.h>
#include <hip/hip_fp16.h>
#include <hip/hip_bf16.h>

#define NR 32

typedef __attribute__((ext_vector_type(8))) short bf8_t;   // 8 x bf16 (4 VGPR)
typedef __attribute__((ext_vector_type(4))) float f4_t;

__device__ __forceinline__ float silu_f(float x) {
    return x * __builtin_amdgcn_rcpf(1.0f + __expf(-x));
}

__device__ __forceinline__ unsigned pkbf(float lo, float hi) {
    __hip_bfloat162 h = __float22bfloat162_rn(make_float2(lo, hi));
    union { __hip_bfloat162 h2; unsigned u; } cv; cv.h2 = h; return cv.u;
}
__device__ __forceinline__ float bf_lo(unsigned u) { return __uint_as_float(u << 16); }
__device__ __forceinline__ float bf_hi(unsigned u) { return __uint_as_float(u & 0xffff0000u); }

__device__ __forceinline__ float rdl(float v, int l) {
    return __int_as_float(__builtin_amdgcn_readlane(__float_as_int(v), l));
}

// ---------------- CSR build ----------------
__global__ __launch_bounds__(256) void k_hist(
    const int* __restrict__ eidx, int* __restrict__ cnt, int nedges)
{
    int e = blockIdx.x * 256 + threadIdx.x;
    if (e < nedges) atomicAdd(&cnt[eidx[e]], 1);
}

__global__ __launch_bounds__(1024) void k_scan2(
    int* __restrict__ cnt, int* __restrict__ off, int n)
{
    __shared__ int wsum[16];
    __shared__ int wbase[16];
    const int tid = threadIdx.x;
    const int lane = tid & 63, wid = tid >> 6;
    const int per = (n + 1023) >> 10;
    const int base = tid * per;
    int s = 0;
    for (int i = 0; i < per; i++) {
        int idx = base + i;
        if (idx < n) s += cnt[idx];
    }
    int incl = s;
    for (int d = 1; d < 64; d <<= 1) {
        int t = __shfl_up(incl, d);
        if (lane >= d) incl += t;
    }
    if (lane == 63) wsum[wid] = incl;
    __syncthreads();
    if (wid == 0) {
        int v = (lane < 16) ? wsum[lane] : 0;
        int inc2 = v;
        for (int d = 1; d < 16; d <<= 1) {
            int t = __shfl_up(inc2, d);
            if (lane >= d) inc2 += t;
        }
        if (lane < 16) wbase[lane] = inc2 - v;
        if (lane == 15) off[n] = inc2;
    }
    __syncthreads();
    int run = wbase[wid] + incl - s;
    for (int i = 0; i < per; i++) {
        int idx = base + i;
        if (idx < n) {
            int v = cnt[idx];
            off[idx] = run;
            cnt[idx] = run;
            run += v;
        }
    }
}

__global__ __launch_bounds__(256) void k_scatter(
    const int* __restrict__ eidx, int* __restrict__ cur,
    int* __restrict__ perm, int* __restrict__ col_s, int nedges)
{
    int e = blockIdx.x * 256 + threadIdx.x;
    if (e < nedges) {
        int r = eidx[e];
        int pos = atomicAdd(&cur[r], 1);
        perm[pos] = e;
        col_s[pos] = eidx[nedges + e];
    }
}

// ---------------- K_prep: bake bf16 frag-linear remapped weight blob ----------------
// blob dwords: [0,12288) w3p | [12288,12672) biases f32 | [12672,13696) w1p | [13696,17792) w2p
// frag slot order: slot = r*4+g, dword dd; k-remap c0 = 32*kt + 16*(dd>>1) + 4*g + 2*(dd&1)
__global__ __launch_bounds__(256) void k_prep(
    const float* __restrict__ w1, const float* __restrict__ b1,
    const float* __restrict__ w2, const float* __restrict__ b2,
    const float* __restrict__ w3, const float* __restrict__ b3,
    unsigned* __restrict__ wpre)
{
    int i = blockIdx.x * 256 + threadIdx.x;
    if (i < 12288) {                       // w3p: 48 (m*4+kt) x 256 dw
        int mk = i >> 8, m = mk >> 2, kt = mk & 3;
        int rr = (i >> 4) & 15, gg = (i >> 2) & 3, dd = i & 3;
        int row = 16 * m + rr;
        int c0 = 32 * kt + 16 * (dd >> 1) + 4 * gg + 2 * (dd & 1);
        const float* s = w3 + (size_t)row * 128 + c0;
        wpre[i] = pkbf(s[0], s[1]);
    } else if (i < 12672) {                // biases: b1[64] b2[128] b3[192]
        int j = i - 12288;
        float v = (j < 64) ? b1[j] : (j < 192) ? b2[j - 64] : b3[j - 192];
        wpre[i] = __float_as_uint(v);
    } else if (i < 13696) {                // w1p: 4 m x 256 dw, natural k
        int j = i - 12672;
        int m = j >> 8, rr = (j >> 4) & 15, gg = (j >> 2) & 3, dd = j & 3;
        const float* s = w1 + (size_t)(16 * m + rr) * 32 + 8 * gg + 2 * dd;
        wpre[i] = pkbf(s[0], s[1]);
    } else if (i < 17792) {                // w2p: 16 (m*2+kt) x 256 dw, remapped
        int j = i - 13696;
        int mk = j >> 8, m = mk >> 1, kt = mk & 1;
        int rr = (j >> 4) & 15, gg = (j >> 2) & 3, dd = j & 3;
        int row = 16 * m + rr;
        int c0 = 32 * kt + 16 * (dd >> 1) + 4 * gg + 2 * (dd & 1);
        const float* s = w2 + (size_t)row * 64 + c0;
        wpre[i] = pkbf(s[0], s[1]);
    }
}

// ---------------- K1: node decompose + mix (lin_w[0..2]) -> Tmh[N][5][64] packed bf16 ----------------
__global__ __launch_bounds__(512) void k1_node_mix(
    const float* __restrict__ X, const float* __restrict__ lw,
    unsigned* __restrict__ Tmh, int nnodes)
{
    __shared__ float Wl[3 * 64 * 68];      // padded rows (68 dwords, 16B-aligned)
    const int tid = threadIdx.x;
#pragma unroll
    for (int k = 0; k < 6; k++) {          // stage lw[0..2]: 12288 floats coalesced
        int l = (tid + k * 512) * 4;
        int row = l >> 6, col = l & 63;
        *(float4*)&Wl[row * 68 + col] = *(const float4*)(lw + l);
    }

    const int wid = tid >> 6, lane = tid & 63;
    const int n = blockIdx.x * 8 + wid;
    const bool valid = (n < nnodes);

    float i0 = 0, i1 = 0, i2 = 0, i3 = 0, i4 = 0, i5 = 0, i6 = 0, i7 = 0, i8 = 0;
    if (valid) {
        const float* xp = X + ((size_t)n * 64 + lane) * 9;
        float v[9];
#pragma unroll
        for (int i = 0; i < 9; i++) v[i] = xp[i];
        float tn = 0.f;
#pragma unroll
        for (int i = 0; i < 9; i++) tn = fmaf(v[i], v[i], tn);
        float inv = 1.0f / (tn + 1.0f);
#pragma unroll
        for (int i = 0; i < 9; i++) v[i] *= inv;
        float lam = (v[0] + v[4] + v[8]) * (1.0f / 3.0f);
        i0 = lam;
        i1 = (v[1] - v[3]) * 0.5f;
        i2 = (v[2] - v[6]) * 0.5f;
        i3 = (v[5] - v[7]) * 0.5f;
        i4 = v[0] - lam;
        i5 = (v[1] + v[3]) * 0.5f;
        i6 = (v[2] + v[6]) * 0.5f;
        i7 = v[4] - lam;
        i8 = (v[5] + v[7]) * 0.5f;
    }
    __syncthreads();

    const int g = lane;
    float a0 = 0, a1 = 0, a2 = 0, a3 = 0, a4 = 0, a5 = 0, a6 = 0, a7 = 0, a8 = 0;
#pragma unroll
    for (int h4 = 0; h4 < 64; h4 += 4) {
        float4 w0 = *(const float4*)&Wl[g * 68 + h4];
        float4 w1 = *(const float4*)&Wl[(64 + g) * 68 + h4];
        float4 w2 = *(const float4*)&Wl[(128 + g) * 68 + h4];
#pragma unroll
        for (int j = 0; j < 4; j++) {
            const int h = h4 + j;
            float wa = (&w0.x)[j], wb = (&w1.x)[j], wc = (&w2.x)[j];
            a0 = fmaf(wa, rdl(i0, h), a0);
            a1 = fmaf(wb, rdl(i1, h), a1);
            a2 = fmaf(wb, rdl(i2, h), a2);
            a3 = fmaf(wb, rdl(i3, h), a3);
            a4 = fmaf(wc, rdl(i4, h), a4);
            a5 = fmaf(wc, rdl(i5, h), a5);
            a6 = fmaf(wc, rdl(i6, h), a6);
            a7 = fmaf(wc, rdl(i7, h), a7);
            a8 = fmaf(wc, rdl(i8, h), a8);
        }
    }
    if (valid) {
        unsigned* outp = Tmh + (size_t)n * 320 + g;
        outp[0 * 64] = pkbf(a0, a1);
        outp[1 * 64] = pkbf(a2, a3);
        outp[2 * 64] = pkbf(a4, a5);
        outp[3 * 64] = pkbf(a6, a7);
        outp[4 * 64] = pkbf(a8, 0.f);
    }
}

// ---------------- K2f: fused edge MLP (MFMA, transposed) + accumulate + k3 ----------------
// 14 waves/block, 896 thr; W1+W2+W3 frags ALL in LDS; q[4][5] rotated Tmh prefetch,
// issued AFTER the L3 phase so q (20 VGPR) never co-lives with B3 (16 VGPR) -> fits 64 VGPR.
// LDS: blob [0,71168): w3p 0 | biases 49152 | w1p 50688 | w2p 54784 ; 14 ef tiles @71168.
#define LBI 49152
#define LW1P 50688
#define LW2P 54784
#define LEF 71168
#define EFS 408
#define NW  14

__global__
__attribute__((amdgpu_flat_work_group_size(896, 896)))
__attribute__((amdgpu_waves_per_eu(3)))
void k2f_fused(
    const float* __restrict__ ea, const float* __restrict__ dist,
    const int* __restrict__ perm, const int* __restrict__ col_s,
    const int* __restrict__ off, const unsigned* __restrict__ wpre,
    const unsigned* __restrict__ Tmh, float* __restrict__ out, int nrows)
{
    __shared__ __align__(16) char smem[LEF + NW * 16 * EFS];   // 162560 B
    const int tid = threadIdx.x;

    // stage whole weight blob (17792 dw = 4448 uint4) -> LDS linearly, coalesced
#pragma unroll
    for (int k = 0; k < 5; k++) {
        int idx = tid + k * 896;
        if (idx < 4448)
            ((uint4*)smem)[idx] = ((const uint4*)wpre)[idx];
    }

    const int wid = tid >> 6, lane = tid & 63;
    const int r16 = lane & 15, g = lane >> 4;
    const int slot = r16 * 4 + g;
    char* efb = smem + LEF + wid * (16 * EFS);
    __syncthreads();

    const int r = blockIdx.x * NW + wid;
    if (r >= nrows) return;
    const int beg = off[r];
    const int deg = off[r + 1] - beg;

    float acc[9];
#pragma unroll
    for (int i = 0; i < 9; i++) acc[i] = 0.f;

    // ---- prefetch chunk 0's edge data ----
    float4 nv0 = {0, 0, 0, 0}, nv1 = {0, 0, 0, 0};
    float nd = 1e9f;
    int nval = 0;
    if (deg > 0) {
        int cnt0 = min(16, deg);
        int e0 = perm[beg + ((r16 < cnt0) ? r16 : 0)];
        const float* ar0 = ea + (size_t)e0 * NR + 8 * g;
        nv0 = *(const float4*)(ar0);
        nv1 = *(const float4*)(ar0 + 4);
        nd = dist[e0];
        nval = (r16 < cnt0) ? 1 : 0;
    }

#pragma unroll 1
    for (int c0 = 0; c0 < deg; c0 += 16) {
        const int cnt = min(16, deg - c0);

        // cols of this chunk (lane r16 holds edge r16's col; clamped for pads)
        int colv = col_s[beg + c0 + ((r16 < cnt) ? r16 : (cnt - 1))];

        // build B-frag + cutoff from prefetched regs
        bf8_t bx;
        {
            union { bf8_t v; unsigned u[4]; } tt;
            tt.u[0] = pkbf(nv0.x, nv0.y); tt.u[1] = pkbf(nv0.z, nv0.w);
            tt.u[2] = pkbf(nv1.x, nv1.y); tt.u[3] = pkbf(nv1.z, nv1.w);
            bx = tt.v;
        }
        float cf = (nval && nd < 5.0f)
                 ? 0.5f * (__cosf(nd * 0.62831853071795864f) + 1.0f) : 0.0f;

        // ---- L1 (W1 frags from LDS) ----
        unsigned pk1[4][2];
#pragma unroll
        for (int m = 0; m < 4; m++) {
            f4_t c = *(const f4_t*)(smem + LBI + (16 * m + 4 * g) * 4);
            bf8_t aw = *(const bf8_t*)(smem + LW1P + (m * 64 + slot) * 16);
            c = __builtin_amdgcn_mfma_f32_16x16x32_bf16(aw, bx, c, 0, 0, 0);
            pk1[m][0] = pkbf(silu_f(c[0]), silu_f(c[1]));
            pk1[m][1] = pkbf(silu_f(c[2]), silu_f(c[3]));
        }
        bf8_t B2[2];
        {
            union { bf8_t v; unsigned u[4]; } ta, tb;
            ta.u[0] = pk1[0][0]; ta.u[1] = pk1[0][1]; ta.u[2] = pk1[1][0]; ta.u[3] = pk1[1][1];
            tb.u[0] = pk1[2][0]; tb.u[1] = pk1[2][1]; tb.u[2] = pk1[3][0]; tb.u[3] = pk1[3][1];
            B2[0] = ta.v; B2[1] = tb.v;
        }

        // ---- L2 (W2 frags from LDS) ----
        unsigned pk2[8][2];
#pragma unroll
        for (int m = 0; m < 8; m++) {
            f4_t c = *(const f4_t*)(smem + LBI + (64 + 16 * m + 4 * g) * 4);
#pragma unroll
            for (int kt = 0; kt < 2; kt++) {
                bf8_t aw = *(const bf8_t*)(smem + LW2P + ((m * 2 + kt) * 64 + slot) * 16);
                c = __builtin_amdgcn_mfma_f32_16x16x32_bf16(aw, B2[kt], c, 0, 0, 0);
            }
            pk2[m][0] = pkbf(silu_f(c[0]), silu_f(c[1]));
            pk2[m][1] = pkbf(silu_f(c[2]), silu_f(c[3]));
        }
        bf8_t B3[4];
#pragma unroll
        for (int kt = 0; kt < 4; kt++) {
            union { bf8_t v; unsigned u[4]; } tt;
            tt.u[0] = pk2[2 * kt][0]; tt.u[1] = pk2[2 * kt][1];
            tt.u[2] = pk2[2 * kt + 1][0]; tt.u[3] = pk2[2 * kt + 1][1];
            B3[kt] = tt.v;
        }

        // ---- issue next chunk's ea prefetch ----
        {
            int c1 = c0 + 16;
            if (c1 < deg) {
                int cnt1 = min(16, deg - c1);
                int e1 = perm[beg + c1 + ((r16 < cnt1) ? r16 : 0)];
                const float* ar1 = ea + (size_t)e1 * NR + 8 * g;
                nv0 = *(const float4*)(ar1);
                nv1 = *(const float4*)(ar1 + 4);
                nd = dist[e1];
                nval = (r16 < cnt1) ? 1 : 0;
            }
        }

        // ---- drain prior chunk's LDS reads before overwriting the tile ----
        asm volatile("s_waitcnt lgkmcnt(0)" ::: "memory");
        __builtin_amdgcn_sched_barrier(0);

        // ---- L3 + cutoff -> per-wave LDS ef tile ----
#pragma unroll
        for (int m = 0; m < 12; m++) {
            f4_t c = *(const f4_t*)(smem + LBI + (192 + 16 * m + 4 * g) * 4);
#pragma unroll
            for (int kt = 0; kt < 4; kt++) {
                bf8_t aw = *(const bf8_t*)(smem + ((m * 4 + kt) * 64 + slot) * 16);
                c = __builtin_amdgcn_mfma_f32_16x16x32_bf16(aw, B3[kt], c, 0, 0, 0);
            }
            union { struct { __half2 a, b; } h; uint2 u; } pu;
            pu.h.a = __float22half2_rn(make_float2(c[0] * cf, c[1] * cf));
            pu.h.b = __float22half2_rn(make_float2(c[2] * cf, c[3] * cf));
            *(uint2*)(efb + r16 * EFS + (16 * m + 4 * g) * 2) = pu.u;
        }
        asm volatile("s_waitcnt lgkmcnt(0)" ::: "memory");
        __builtin_amdgcn_sched_barrier(0);

        // ---- Tmh gather, edges 0..3 (issued NOW so q never co-lives with B3) ----
        unsigned q[4][5];
#pragma unroll
        for (int s = 0; s < 4; s++) {
            int sc = __builtin_amdgcn_readlane(colv, s);
            const unsigned* t = Tmh + (size_t)(unsigned)sc * 320 + lane;
            q[s][0] = t[0]; q[s][1] = t[64]; q[s][2] = t[128];
            q[s][3] = t[192]; q[s][4] = t[256];
        }

        // ---- accumulate: depth-4 rotation (reload each q slot right after last use) ----
#define ACC_STEP(S, Q)                                                        \
        {                                                                     \
            const __half* fp = (const __half*)(efb + (S) * EFS + 6 * lane);   \
            float f0 = __half2float(fp[0]);                                   \
            float f1 = __half2float(fp[1]);                                   \
            float f2 = __half2float(fp[2]);                                   \
            acc[0] = fmaf(f0, bf_lo(Q[0]), acc[0]);                           \
            acc[1] = fmaf(f1, bf_hi(Q[0]), acc[1]);                           \
            acc[2] = fmaf(f1, bf_lo(Q[1]), acc[2]);                           \
            acc[3] = fmaf(f1, bf_hi(Q[1]), acc[3]);                           \
            acc[4] = fmaf(f2, bf_lo(Q[2]), acc[4]);                           \
            acc[5] = fmaf(f2, bf_hi(Q[2]), acc[5]);                           \
            acc[6] = fmaf(f2, bf_lo(Q[3]), acc[6]);                           \
            acc[7] = fmaf(f2, bf_hi(Q[3]), acc[7]);                           \
            acc[8] = fmaf(f2, bf_lo(Q[4]), acc[8]);                           \
        }
#define LOAD_Q(DST, S)                                                        \
        {                                                                     \
            int sc = __builtin_amdgcn_readlane(colv, (S));                    \
            const unsigned* t = Tmh + (size_t)(unsigned)sc * 320 + lane;      \
            DST[0] = t[0]; DST[1] = t[64]; DST[2] = t[128];                   \
            DST[3] = t[192]; DST[4] = t[256];                                 \
        }

        ACC_STEP(0, q[0])  LOAD_Q(q[0], 4)
        ACC_STEP(1, q[1])  LOAD_Q(q[1], 5)
        ACC_STEP(2, q[2])  LOAD_Q(q[2], 6)
        ACC_STEP(3, q[3])  LOAD_Q(q[3], 7)
        ACC_STEP(4, q[0])  LOAD_Q(q[0], 8)
        ACC_STEP(5, q[1])  LOAD_Q(q[1], 9)
        ACC_STEP(6, q[2])  LOAD_Q(q[2], 10)
        ACC_STEP(7, q[3])  LOAD_Q(q[3], 11)
        ACC_STEP(8, q[0])  LOAD_Q(q[0], 12)
        ACC_STEP(9, q[1])  LOAD_Q(q[1], 13)
        ACC_STEP(10, q[2]) LOAD_Q(q[2], 14)
        ACC_STEP(11, q[3]) LOAD_Q(q[3], 15)
        ACC_STEP(12, q[0]) ACC_STEP(13, q[1]) ACC_STEP(14, q[2]) ACC_STEP(15, q[3])
#undef ACC_STEP
#undef LOAD_Q
    }

    // ---- fused k3: prod = M@Y + Y@M, decompose, /norm -> out (pc comp-major) ----
    float y[9];
    {
        const unsigned* tp = Tmh + (size_t)r * 320 + lane;
        unsigned q0 = tp[0], q1 = tp[64], q2 = tp[128], q3 = tp[192], q4 = tp[256];
        y[0] = bf_lo(q0); y[1] = bf_hi(q0); y[2] = bf_lo(q1); y[3] = bf_hi(q1);
        y[4] = bf_lo(q2); y[5] = bf_hi(q2); y[6] = bf_lo(q3); y[7] = bf_hi(q3);
        y[8] = bf_lo(q4);
    }
    float Y[9], Mm[9];
    Y[0] = y[0] + y[4]; Y[1] = y[1] + y[5]; Y[2] = y[2] + y[6];
    Y[3] = -y[1] + y[5]; Y[4] = y[0] + y[7]; Y[5] = y[3] + y[8];
    Y[6] = -y[2] + y[6]; Y[7] = -y[3] + y[8]; Y[8] = y[0] - y[4] - y[7];
    Mm[0] = acc[0] + acc[4]; Mm[1] = acc[1] + acc[5]; Mm[2] = acc[2] + acc[6];
    Mm[3] = -acc[1] + acc[5]; Mm[4] = acc[0] + acc[7]; Mm[5] = acc[3] + acc[8];
    Mm[6] = -acc[2] + acc[6]; Mm[7] = -acc[3] + acc[8]; Mm[8] = acc[0] - acc[4] - acc[7];
    float P[9];
#pragma unroll
    for (int a = 0; a < 3; a++)
#pragma unroll
        for (int b = 0; b < 3; b++) {
            float s = 0.f;
#pragma unroll
            for (int c = 0; c < 3; c++) {
                s = fmaf(Mm[a * 3 + c], Y[c * 3 + b], s);
                s = fmaf(Y[a * 3 + c], Mm[c * 3 + b], s);
            }
            P[a * 3 + b] = s;
        }
    float tn = 0.f;
#pragma unroll
    for (int k = 0; k < 9; k++) tn = fmaf(P[k], P[k], tn);
    float inv = 1.0f / (tn + 1.0f);
    float lam = (P[0] + P[4] + P[8]) * (1.0f / 3.0f);

    float* mp = out + (size_t)r * 576 + lane;
    mp[0 * 64] = lam * inv;
    mp[1 * 64] = (P[1] - P[3]) * 0.5f * inv;
    mp[2 * 64] = (P[2] - P[6]) * 0.5f * inv;
    mp[3 * 64] = (P[5] - P[7]) * 0.5f * inv;
    mp[4 * 64] = (P[0] - lam) * inv;
    mp[5 * 64] = (P[1] + P[3]) * 0.5f * inv;
    mp[6 * 64] = (P[2] + P[6]) * 0.5f * inv;
    mp[7 * 64] = (P[4] - lam) * inv;
    mp[8 * 64] = (P[5] + P[7]) * 0.5f * inv;
}

// ---------------- K4: mix (lin_w[3..5]) -> dX; out = Xn + dX + dX@dX (in-place over pc) ----------------
__global__ __launch_bounds__(512) void k4_final(
    const float* __restrict__ X, const float* __restrict__ lw,
    float* __restrict__ out, int nnodes)
{
    __shared__ float Wl[3 * 64 * 68];
    const int tid = threadIdx.x;
#pragma unroll
    for (int k = 0; k < 6; k++) {          // stage lw[3..5]
        int l = (tid + k * 512) * 4;
        int row = l >> 6, col = l & 63;
        *(float4*)&Wl[row * 68 + col] = *(const float4*)(lw + 3 * 4096 + l);
    }

    const int wid = tid >> 6, lane = tid & 63;
    const int n = blockIdx.x * 8 + wid;
    const bool valid = (n < nnodes);

    float i0 = 0, i1 = 0, i2 = 0, i3 = 0, i4 = 0, i5 = 0, i6 = 0, i7 = 0, i8 = 0;
    if (valid) {
        const float* pp = out + (size_t)n * 576 + lane;   // pc comp-major [n][9][64]
        i0 = pp[0 * 64]; i1 = pp[1 * 64]; i2 = pp[2 * 64];
        i3 = pp[3 * 64]; i4 = pp[4 * 64]; i5 = pp[5 * 64];
        i6 = pp[6 * 64]; i7 = pp[7 * 64]; i8 = pp[8 * 64];
    }
    __syncthreads();

    const int g = lane;
    float a0 = 0, a1 = 0, a2 = 0, a3 = 0, a4 = 0, a5 = 0, a6 = 0, a7 = 0, a8 = 0;
#pragma unroll
    for (int h4 = 0; h4 < 64; h4 += 4) {
        float4 w0 = *(const float4*)&Wl[g * 68 + h4];
        float4 w1 = *(const float4*)&Wl[(64 + g) * 68 + h4];
        float4 w2 = *(const float4*)&Wl[(128 + g) * 68 + h4];
#pragma unroll
        for (int j = 0; j < 4; j++) {
            const int h = h4 + j;
            float wa = (&w0.x)[j], wb = (&w1.x)[j], wc = (&w2.x)[j];
            a0 = fmaf(wa, rdl(i0, h), a0);
            a1 = fmaf(wb, rdl(i1, h), a1);
            a2 = fmaf(wb, rdl(i2, h), a2);
            a3 = fmaf(wb, rdl(i3, h), a3);
            a4 = fmaf(wc, rdl(i4, h), a4);
            a5 = fmaf(wc, rdl(i5, h), a5);
            a6 = fmaf(wc, rdl(i6, h), a6);
            a7 = fmaf(wc, rdl(i7, h), a7);
            a8 = fmaf(wc, rdl(i8, h), a8);
        }
    }

    if (valid) {
        float D[9];
        D[0] = a0 + a4; D[1] = a1 + a5; D[2] = a2 + a6;
        D[3] = -a1 + a5; D[4] = a0 + a7; D[5] = a3 + a8;
        D[6] = -a2 + a6; D[7] = -a3 + a8; D[8] = a0 - a4 - a7;

        const float* xp = X + ((size_t)n * 64 + g) * 9;
        float xv[9];
#pragma unroll
        for (int i = 0; i < 9; i++) xv[i] = xp[i];
        float tn = 0.f;
#pragma unroll
        for (int i = 0; i < 9; i++) tn = fmaf(xv[i], xv[i], tn);
        float inv = 1.0f / (tn + 1.0f);

        float* op = out + ((size_t)n * 64 + g) * 9;   // final [N][64][3][3]
        float res[9];
#pragma unroll
        for (int a = 0; a < 3; a++)
#pragma unroll
            for (int b = 0; b < 3; b++) {
                float dd = 0.f;
#pragma unroll
                for (int c = 0; c < 3; c++) dd = fmaf(D[a * 3 + c], D[c * 3 + b], dd);
                res[a * 3 + b] = xv[a * 3 + b] * inv + D[a * 3 + b] + dd;
            }
#pragma unroll
        for (int i = 0; i < 9; i++) op[i] = res[i];
    }
}

extern "C" void kernel_launch(void* const* d_in, const int* in_sizes, int n_in,
                              void* d_out, int out_size, void* d_ws, size_t ws_size,
                              hipStream_t stream)
{
    const float* X    = (const float*)d_in[0];
    const int*   eidx = (const int*)d_in[1];
    const float* dist = (const float*)d_in[2];
    const float* ea   = (const float*)d_in[3];
    const float* w1   = (const float*)d_in[4];
    const float* b1   = (const float*)d_in[5];
    const float* w2   = (const float*)d_in[6];
    const float* b2   = (const float*)d_in[7];
    const float* w3   = (const float*)d_in[8];
    const float* b3   = (const float*)d_in[9];
    const float* lw   = (const float*)d_in[10];
    float* outp = (float*)d_out;

    const int nnodes = in_sizes[0] / (64 * 9);   // 20000
    const int nedges = in_sizes[2];              // 320000

    unsigned* Tmh  = (unsigned*)d_ws;                       // N*320 dwords (packed bf16 pairs)
    int* cur       = (int*)(Tmh + (size_t)nnodes * 320);
    int* off       = cur + nnodes;                          // nnodes+1
    int* perm      = off + nnodes + 1;                      // nedges
    int* col_s     = perm + nedges;                         // nedges
    unsigned* wpre = (unsigned*)(col_s + nedges);           // 17792 dwords

    // CSR build (edges sorted by destination row; col pre-gathered)
    hipMemsetAsync(cur, 0, (size_t)nnodes * sizeof(int), stream);
    k_hist<<<(nedges + 255) / 256, 256, 0, stream>>>(eidx, cur, nedges);
    k_scan2<<<1, 1024, 0, stream>>>(cur, off, nnodes);
    k_scatter<<<(nedges + 255) / 256, 256, 0, stream>>>(eidx, cur, perm, col_s, nedges);
    k_prep<<<70, 256, 0, stream>>>(w1, b1, w2, b2, w3, b3, wpre);

    k1_node_mix<<<(nnodes + 7) / 8, 512, 0, stream>>>(X, lw, Tmh, nnodes);
    k2f_fused<<<(nnodes + NW - 1) / NW, 64 * NW, 0, stream>>>(ea, dist, perm, col_s, off, wpre, Tmh, outp, nnodes);
    k4_final<<<(nnodes + 7) / 8, 512, 0, stream>>>(X, lw, outp, nnodes);
}

// Round 18
// 384.124 us; speedup vs baseline: 1.4933x; 1.0398x over previous
//
#include <hip/hip_runtime.h>
#include <hip/hip_fp16.h>
#include <hip/hip_bf16.h>

#define NR 32

typedef __attribute__((ext_vector_type(8))) short bf8_t;   // 8 x bf16 (4 VGPR)
typedef __attribute__((ext_vector_type(4))) float f4_t;

__device__ __forceinline__ float silu_f(float x) {
    return x * __builtin_amdgcn_rcpf(1.0f + __expf(-x));
}

__device__ __forceinline__ unsigned pkbf(float lo, float hi) {
    __hip_bfloat162 h = __float22bfloat162_rn(make_float2(lo, hi));
    union { __hip_bfloat162 h2; unsigned u; } cv; cv.h2 = h; return cv.u;
}
__device__ __forceinline__ float bf_lo(unsigned u) { return __uint_as_float(u << 16); }
__device__ __forceinline__ float bf_hi(unsigned u) { return __uint_as_float(u & 0xffff0000u); }

__device__ __forceinline__ float rdl(float v, int l) {
    return __int_as_float(__builtin_amdgcn_readlane(__float_as_int(v), l));
}

// ---------------- CSR build ----------------
__global__ __launch_bounds__(256) void k_hist(
    const int* __restrict__ eidx, int* __restrict__ cnt, int nedges)
{
    int e = blockIdx.x * 256 + threadIdx.x;
    if (e < nedges) atomicAdd(&cnt[eidx[e]], 1);
}

__global__ __launch_bounds__(1024) void k_scan2(
    int* __restrict__ cnt, int* __restrict__ off, int n)
{
    __shared__ int wsum[16];
    __shared__ int wbase[16];
    const int tid = threadIdx.x;
    const int lane = tid & 63, wid = tid >> 6;
    const int per = (n + 1023) >> 10;
    const int base = tid * per;
    int s = 0;
    for (int i = 0; i < per; i++) {
        int idx = base + i;
        if (idx < n) s += cnt[idx];
    }
    int incl = s;
    for (int d = 1; d < 64; d <<= 1) {
        int t = __shfl_up(incl, d);
        if (lane >= d) incl += t;
    }
    if (lane == 63) wsum[wid] = incl;
    __syncthreads();
    if (wid == 0) {
        int v = (lane < 16) ? wsum[lane] : 0;
        int inc2 = v;
        for (int d = 1; d < 16; d <<= 1) {
            int t = __shfl_up(inc2, d);
            if (lane >= d) inc2 += t;
        }
        if (lane < 16) wbase[lane] = inc2 - v;
        if (lane == 15) off[n] = inc2;
    }
    __syncthreads();
    int run = wbase[wid] + incl - s;
    for (int i = 0; i < per; i++) {
        int idx = base + i;
        if (idx < n) {
            int v = cnt[idx];
            off[idx] = run;
            cnt[idx] = run;
            run += v;
        }
    }
}

__global__ __launch_bounds__(256) void k_scatter(
    const int* __restrict__ eidx, int* __restrict__ cur,
    int* __restrict__ perm, int* __restrict__ col_s, int nedges)
{
    int e = blockIdx.x * 256 + threadIdx.x;
    if (e < nedges) {
        int r = eidx[e];
        int pos = atomicAdd(&cur[r], 1);
        perm[pos] = e;
        col_s[pos] = eidx[nedges + e];
    }
}

// ---------------- K_prep: bake bf16 frag-linear remapped weight blob ----------------
// blob dwords: [0,12288) w3p | [12288,12672) biases f32 | [12672,13696) w1p | [13696,17792) w2p
// frag slot order: slot = r*4+g, dword dd; k-remap c0 = 32*kt + 16*(dd>>1) + 4*g + 2*(dd&1)
__global__ __launch_bounds__(256) void k_prep(
    const float* __restrict__ w1, const float* __restrict__ b1,
    const float* __restrict__ w2, const float* __restrict__ b2,
    const float* __restrict__ w3, const float* __restrict__ b3,
    unsigned* __restrict__ wpre)
{
    int i = blockIdx.x * 256 + threadIdx.x;
    if (i < 12288) {                       // w3p: 48 (m*4+kt) x 256 dw
        int mk = i >> 8, m = mk >> 2, kt = mk & 3;
        int rr = (i >> 4) & 15, gg = (i >> 2) & 3, dd = i & 3;
        int row = 16 * m + rr;
        int c0 = 32 * kt + 16 * (dd >> 1) + 4 * gg + 2 * (dd & 1);
        const float* s = w3 + (size_t)row * 128 + c0;
        wpre[i] = pkbf(s[0], s[1]);
    } else if (i < 12672) {                // biases: b1[64] b2[128] b3[192]
        int j = i - 12288;
        float v = (j < 64) ? b1[j] : (j < 192) ? b2[j - 64] : b3[j - 192];
        wpre[i] = __float_as_uint(v);
    } else if (i < 13696) {                // w1p: 4 m x 256 dw, natural k
        int j = i - 12672;
        int m = j >> 8, rr = (j >> 4) & 15, gg = (j >> 2) & 3, dd = j & 3;
        const float* s = w1 + (size_t)(16 * m + rr) * 32 + 8 * gg + 2 * dd;
        wpre[i] = pkbf(s[0], s[1]);
    } else if (i < 17792) {                // w2p: 16 (m*2+kt) x 256 dw, remapped
        int j = i - 13696;
        int mk = j >> 8, m = mk >> 1, kt = mk & 1;
        int rr = (j >> 4) & 15, gg = (j >> 2) & 3, dd = j & 3;
        int row = 16 * m + rr;
        int c0 = 32 * kt + 16 * (dd >> 1) + 4 * gg + 2 * (dd & 1);
        const float* s = w2 + (size_t)row * 64 + c0;
        wpre[i] = pkbf(s[0], s[1]);
    }
}

// ---------------- K1: node decompose + mix (lin_w[0..2]) -> Tmh[N][5][64] packed bf16 ----------------
__global__ __launch_bounds__(512) void k1_node_mix(
    const float* __restrict__ X, const float* __restrict__ lw,
    unsigned* __restrict__ Tmh, int nnodes)
{
    __shared__ float Wl[3 * 64 * 68];      // padded rows (68 dwords, 16B-aligned)
    const int tid = threadIdx.x;
#pragma unroll
    for (int k = 0; k < 6; k++) {          // stage lw[0..2]: 12288 floats coalesced
        int l = (tid + k * 512) * 4;
        int row = l >> 6, col = l & 63;
        *(float4*)&Wl[row * 68 + col] = *(const float4*)(lw + l);
    }

    const int wid = tid >> 6, lane = tid & 63;
    const int n = blockIdx.x * 8 + wid;
    const bool valid = (n < nnodes);

    float i0 = 0, i1 = 0, i2 = 0, i3 = 0, i4 = 0, i5 = 0, i6 = 0, i7 = 0, i8 = 0;
    if (valid) {
        const float* xp = X + ((size_t)n * 64 + lane) * 9;
        float v[9];
#pragma unroll
        for (int i = 0; i < 9; i++) v[i] = xp[i];
        float tn = 0.f;
#pragma unroll
        for (int i = 0; i < 9; i++) tn = fmaf(v[i], v[i], tn);
        float inv = 1.0f / (tn + 1.0f);
#pragma unroll
        for (int i = 0; i < 9; i++) v[i] *= inv;
        float lam = (v[0] + v[4] + v[8]) * (1.0f / 3.0f);
        i0 = lam;
        i1 = (v[1] - v[3]) * 0.5f;
        i2 = (v[2] - v[6]) * 0.5f;
        i3 = (v[5] - v[7]) * 0.5f;
        i4 = v[0] - lam;
        i5 = (v[1] + v[3]) * 0.5f;
        i6 = (v[2] + v[6]) * 0.5f;
        i7 = v[4] - lam;
        i8 = (v[5] + v[7]) * 0.5f;
    }
    __syncthreads();

    const int g = lane;
    float a0 = 0, a1 = 0, a2 = 0, a3 = 0, a4 = 0, a5 = 0, a6 = 0, a7 = 0, a8 = 0;
#pragma unroll
    for (int h4 = 0; h4 < 64; h4 += 4) {
        float4 w0 = *(const float4*)&Wl[g * 68 + h4];
        float4 w1 = *(const float4*)&Wl[(64 + g) * 68 + h4];
        float4 w2 = *(const float4*)&Wl[(128 + g) * 68 + h4];
#pragma unroll
        for (int j = 0; j < 4; j++) {
            const int h = h4 + j;
            float wa = (&w0.x)[j], wb = (&w1.x)[j], wc = (&w2.x)[j];
            a0 = fmaf(wa, rdl(i0, h), a0);
            a1 = fmaf(wb, rdl(i1, h), a1);
            a2 = fmaf(wb, rdl(i2, h), a2);
            a3 = fmaf(wb, rdl(i3, h), a3);
            a4 = fmaf(wc, rdl(i4, h), a4);
            a5 = fmaf(wc, rdl(i5, h), a5);
            a6 = fmaf(wc, rdl(i6, h), a6);
            a7 = fmaf(wc, rdl(i7, h), a7);
            a8 = fmaf(wc, rdl(i8, h), a8);
        }
    }
    if (valid) {
        unsigned* outp = Tmh + (size_t)n * 320 + g;
        outp[0 * 64] = pkbf(a0, a1);
        outp[1 * 64] = pkbf(a2, a3);
        outp[2 * 64] = pkbf(a4, a5);
        outp[3 * 64] = pkbf(a6, a7);
        outp[4 * 64] = pkbf(a8, 0.f);
    }
}

// ---------------- K2f: fused edge MLP (MFMA, transposed) + accumulate + k3 ----------------
// 14 waves/block, 896 thr; W1+W2+W3 frags ALL in LDS; q[4][5] rotated Tmh prefetch after L3.
// ea/dist loaded at chunk top (no register prefetch): peak VGPR demand < 64 in every phase.
// LDS: blob [0,71168): w3p 0 | biases 49152 | w1p 50688 | w2p 54784 ; 14 ef tiles @71168.
#define LBI 49152
#define LW1P 50688
#define LW2P 54784
#define LEF 71168
#define EFS 408
#define NW  14

__global__
__attribute__((amdgpu_flat_work_group_size(896, 896)))
__attribute__((amdgpu_waves_per_eu(3)))
void k2f_fused(
    const float* __restrict__ ea, const float* __restrict__ dist,
    const int* __restrict__ perm, const int* __restrict__ col_s,
    const int* __restrict__ off, const unsigned* __restrict__ wpre,
    const unsigned* __restrict__ Tmh, float* __restrict__ out, int nrows)
{
    __shared__ __align__(16) char smem[LEF + NW * 16 * EFS];   // 162560 B
    const int tid = threadIdx.x;

    // stage whole weight blob (17792 dw = 4448 uint4) -> LDS linearly, coalesced
#pragma unroll
    for (int k = 0; k < 5; k++) {
        int idx = tid + k * 896;
        if (idx < 4448)
            ((uint4*)smem)[idx] = ((const uint4*)wpre)[idx];
    }

    const int wid = tid >> 6, lane = tid & 63;
    const int r16 = lane & 15, g = lane >> 4;
    const int slot = r16 * 4 + g;
    char* efb = smem + LEF + wid * (16 * EFS);
    __syncthreads();

    const int r = blockIdx.x * NW + wid;
    if (r >= nrows) return;
    const int beg = off[r];
    const int deg = off[r + 1] - beg;

    float acc[9];
#pragma unroll
    for (int i = 0; i < 9; i++) acc[i] = 0.f;

#pragma unroll 1
    for (int c0 = 0; c0 < deg; c0 += 16) {
        const int cnt = min(16, deg - c0);

        // cols + edge data of this chunk (lane r16 = edge slot; clamped for pads)
        int colv = col_s[beg + c0 + ((r16 < cnt) ? r16 : (cnt - 1))];
        int e = perm[beg + c0 + ((r16 < cnt) ? r16 : 0)];
        const float* ar = ea + (size_t)e * NR + 8 * g;
        float4 v0 = *(const float4*)(ar);
        float4 v1 = *(const float4*)(ar + 4);
        float d = dist[e];

        bf8_t bx;
        {
            union { bf8_t v; unsigned u[4]; } tt;
            tt.u[0] = pkbf(v0.x, v0.y); tt.u[1] = pkbf(v0.z, v0.w);
            tt.u[2] = pkbf(v1.x, v1.y); tt.u[3] = pkbf(v1.z, v1.w);
            bx = tt.v;
        }
        float cf = (r16 < cnt && d < 5.0f)
                 ? 0.5f * (__cosf(d * 0.62831853071795864f) + 1.0f) : 0.0f;

        // ---- L1 (W1 frags from LDS) ----
        unsigned pk1[4][2];
#pragma unroll
        for (int m = 0; m < 4; m++) {
            f4_t c = *(const f4_t*)(smem + LBI + (16 * m + 4 * g) * 4);
            bf8_t aw = *(const bf8_t*)(smem + LW1P + (m * 64 + slot) * 16);
            c = __builtin_amdgcn_mfma_f32_16x16x32_bf16(aw, bx, c, 0, 0, 0);
            pk1[m][0] = pkbf(silu_f(c[0]), silu_f(c[1]));
            pk1[m][1] = pkbf(silu_f(c[2]), silu_f(c[3]));
        }
        bf8_t B2[2];
        {
            union { bf8_t v; unsigned u[4]; } ta, tb;
            ta.u[0] = pk1[0][0]; ta.u[1] = pk1[0][1]; ta.u[2] = pk1[1][0]; ta.u[3] = pk1[1][1];
            tb.u[0] = pk1[2][0]; tb.u[1] = pk1[2][1]; tb.u[2] = pk1[3][0]; tb.u[3] = pk1[3][1];
            B2[0] = ta.v; B2[1] = tb.v;
        }

        // ---- L2 (W2 frags from LDS) ----
        unsigned pk2[8][2];
#pragma unroll
        for (int m = 0; m < 8; m++) {
            f4_t c = *(const f4_t*)(smem + LBI + (64 + 16 * m + 4 * g) * 4);
#pragma unroll
            for (int kt = 0; kt < 2; kt++) {
                bf8_t aw = *(const bf8_t*)(smem + LW2P + ((m * 2 + kt) * 64 + slot) * 16);
                c = __builtin_amdgcn_mfma_f32_16x16x32_bf16(aw, B2[kt], c, 0, 0, 0);
            }
            pk2[m][0] = pkbf(silu_f(c[0]), silu_f(c[1]));
            pk2[m][1] = pkbf(silu_f(c[2]), silu_f(c[3]));
        }
        bf8_t B3[4];
#pragma unroll
        for (int kt = 0; kt < 4; kt++) {
            union { bf8_t v; unsigned u[4]; } tt;
            tt.u[0] = pk2[2 * kt][0]; tt.u[1] = pk2[2 * kt][1];
            tt.u[2] = pk2[2 * kt + 1][0]; tt.u[3] = pk2[2 * kt + 1][1];
            B3[kt] = tt.v;
        }

        // ---- drain prior chunk's LDS reads before overwriting the tile ----
        asm volatile("s_waitcnt lgkmcnt(0)" ::: "memory");
        __builtin_amdgcn_sched_barrier(0);

        // ---- L3 + cutoff -> per-wave LDS ef tile ----
#pragma unroll
        for (int m = 0; m < 12; m++) {
            f4_t c = *(const f4_t*)(smem + LBI + (192 + 16 * m + 4 * g) * 4);
#pragma unroll
            for (int kt = 0; kt < 4; kt++) {
                bf8_t aw = *(const bf8_t*)(smem + ((m * 4 + kt) * 64 + slot) * 16);
                c = __builtin_amdgcn_mfma_f32_16x16x32_bf16(aw, B3[kt], c, 0, 0, 0);
            }
            union { struct { __half2 a, b; } h; uint2 u; } pu;
            pu.h.a = __float22half2_rn(make_float2(c[0] * cf, c[1] * cf));
            pu.h.b = __float22half2_rn(make_float2(c[2] * cf, c[3] * cf));
            *(uint2*)(efb + r16 * EFS + (16 * m + 4 * g) * 2) = pu.u;
        }
        asm volatile("s_waitcnt lgkmcnt(0)" ::: "memory");
        __builtin_amdgcn_sched_barrier(0);

        // ---- Tmh gather, edges 0..3 (after L3 so q never co-lives with B3) ----
        unsigned q[4][5];
#pragma unroll
        for (int s = 0; s < 4; s++) {
            int sc = __builtin_amdgcn_readlane(colv, s);
            const unsigned* t = Tmh + (size_t)(unsigned)sc * 320 + lane;
            q[s][0] = t[0]; q[s][1] = t[64]; q[s][2] = t[128];
            q[s][3] = t[192]; q[s][4] = t[256];
        }

        // ---- accumulate: depth-4 rotation (reload each q slot right after last use) ----
#define ACC_STEP(S, Q)                                                        \
        {                                                                     \
            const __half* fp = (const __half*)(efb + (S) * EFS + 6 * lane);   \
            float f0 = __half2float(fp[0]);                                   \
            float f1 = __half2float(fp[1]);                                   \
            float f2 = __half2float(fp[2]);                                   \
            acc[0] = fmaf(f0, bf_lo(Q[0]), acc[0]);                           \
            acc[1] = fmaf(f1, bf_hi(Q[0]), acc[1]);                           \
            acc[2] = fmaf(f1, bf_lo(Q[1]), acc[2]);                           \
            acc[3] = fmaf(f1, bf_hi(Q[1]), acc[3]);                           \
            acc[4] = fmaf(f2, bf_lo(Q[2]), acc[4]);                           \
            acc[5] = fmaf(f2, bf_hi(Q[2]), acc[5]);                           \
            acc[6] = fmaf(f2, bf_lo(Q[3]), acc[6]);                           \
            acc[7] = fmaf(f2, bf_hi(Q[3]), acc[7]);                           \
            acc[8] = fmaf(f2, bf_lo(Q[4]), acc[8]);                           \
        }
#define LOAD_Q(DST, S)                                                        \
        {                                                                     \
            int sc = __builtin_amdgcn_readlane(colv, (S));                    \
            const unsigned* t = Tmh + (size_t)(unsigned)sc * 320 + lane;      \
            DST[0] = t[0]; DST[1] = t[64]; DST[2] = t[128];                   \
            DST[3] = t[192]; DST[4] = t[256];                                 \
        }

        ACC_STEP(0, q[0])  LOAD_Q(q[0], 4)
        ACC_STEP(1, q[1])  LOAD_Q(q[1], 5)
        ACC_STEP(2, q[2])  LOAD_Q(q[2], 6)
        ACC_STEP(3, q[3])  LOAD_Q(q[3], 7)
        ACC_STEP(4, q[0])  LOAD_Q(q[0], 8)
        ACC_STEP(5, q[1])  LOAD_Q(q[1], 9)
        ACC_STEP(6, q[2])  LOAD_Q(q[2], 10)
        ACC_STEP(7, q[3])  LOAD_Q(q[3], 11)
        ACC_STEP(8, q[0])  LOAD_Q(q[0], 12)
        ACC_STEP(9, q[1])  LOAD_Q(q[1], 13)
        ACC_STEP(10, q[2]) LOAD_Q(q[2], 14)
        ACC_STEP(11, q[3]) LOAD_Q(q[3], 15)
        ACC_STEP(12, q[0]) ACC_STEP(13, q[1]) ACC_STEP(14, q[2]) ACC_STEP(15, q[3])
#undef ACC_STEP
#undef LOAD_Q
    }

    // ---- fused k3: prod = M@Y + Y@M, decompose, /norm -> out (pc comp-major) ----
    float y[9];
    {
        const unsigned* tp = Tmh + (size_t)r * 320 + lane;
        unsigned q0 = tp[0], q1 = tp[64], q2 = tp[128], q3 = tp[192], q4 = tp[256];
        y[0] = bf_lo(q0); y[1] = bf_hi(q0); y[2] = bf_lo(q1); y[3] = bf_hi(q1);
        y[4] = bf_lo(q2); y[5] = bf_hi(q2); y[6] = bf_lo(q3); y[7] = bf_hi(q3);
        y[8] = bf_lo(q4);
    }
    float Y[9], Mm[9];
    Y[0] = y[0] + y[4]; Y[1] = y[1] + y[5]; Y[2] = y[2] + y[6];
    Y[3] = -y[1] + y[5]; Y[4] = y[0] + y[7]; Y[5] = y[3] + y[8];
    Y[6] = -y[2] + y[6]; Y[7] = -y[3] + y[8]; Y[8] = y[0] - y[4] - y[7];
    Mm[0] = acc[0] + acc[4]; Mm[1] = acc[1] + acc[5]; Mm[2] = acc[2] + acc[6];
    Mm[3] = -acc[1] + acc[5]; Mm[4] = acc[0] + acc[7]; Mm[5] = acc[3] + acc[8];
    Mm[6] = -acc[2] + acc[6]; Mm[7] = -acc[3] + acc[8]; Mm[8] = acc[0] - acc[4] - acc[7];
    float P[9];
#pragma unroll
    for (int a = 0; a < 3; a++)
#pragma unroll
        for (int b = 0; b < 3; b++) {
            float s = 0.f;
#pragma unroll
            for (int c = 0; c < 3; c++) {
                s = fmaf(Mm[a * 3 + c], Y[c * 3 + b], s);
                s = fmaf(Y[a * 3 + c], Mm[c * 3 + b], s);
            }
            P[a * 3 + b] = s;
        }
    float tn = 0.f;
#pragma unroll
    for (int k = 0; k < 9; k++) tn = fmaf(P[k], P[k], tn);
    float inv = 1.0f / (tn + 1.0f);
    float lam = (P[0] + P[4] + P[8]) * (1.0f / 3.0f);

    float* mp = out + (size_t)r * 576 + lane;
    mp[0 * 64] = lam * inv;
    mp[1 * 64] = (P[1] - P[3]) * 0.5f * inv;
    mp[2 * 64] = (P[2] - P[6]) * 0.5f * inv;
    mp[3 * 64] = (P[5] - P[7]) * 0.5f * inv;
    mp[4 * 64] = (P[0] - lam) * inv;
    mp[5 * 64] = (P[1] + P[3]) * 0.5f * inv;
    mp[6 * 64] = (P[2] + P[6]) * 0.5f * inv;
    mp[7 * 64] = (P[4] - lam) * inv;
    mp[8 * 64] = (P[5] + P[7]) * 0.5f * inv;
}

// ---------------- K4: mix (lin_w[3..5]) -> dX; out = Xn + dX + dX@dX (in-place over pc) ----------------
__global__ __launch_bounds__(512) void k4_final(
    const float* __restrict__ X, const float* __restrict__ lw,
    float* __restrict__ out, int nnodes)
{
    __shared__ float Wl[3 * 64 * 68];
    const int tid = threadIdx.x;
#pragma unroll
    for (int k = 0; k < 6; k++) {          // stage lw[3..5]
        int l = (tid + k * 512) * 4;
        int row = l >> 6, col = l & 63;
        *(float4*)&Wl[row * 68 + col] = *(const float4*)(lw + 3 * 4096 + l);
    }

    const int wid = tid >> 6, lane = tid & 63;
    const int n = blockIdx.x * 8 + wid;
    const bool valid = (n < nnodes);

    float i0 = 0, i1 = 0, i2 = 0, i3 = 0, i4 = 0, i5 = 0, i6 = 0, i7 = 0, i8 = 0;
    if (valid) {
        const float* pp = out + (size_t)n * 576 + lane;   // pc comp-major [n][9][64]
        i0 = pp[0 * 64]; i1 = pp[1 * 64]; i2 = pp[2 * 64];
        i3 = pp[3 * 64]; i4 = pp[4 * 64]; i5 = pp[5 * 64];
        i6 = pp[6 * 64]; i7 = pp[7 * 64]; i8 = pp[8 * 64];
    }
    __syncthreads();

    const int g = lane;
    float a0 = 0, a1 = 0, a2 = 0, a3 = 0, a4 = 0, a5 = 0, a6 = 0, a7 = 0, a8 = 0;
#pragma unroll
    for (int h4 = 0; h4 < 64; h4 += 4) {
        float4 w0 = *(const float4*)&Wl[g * 68 + h4];
        float4 w1 = *(const float4*)&Wl[(64 + g) * 68 + h4];
        float4 w2 = *(const float4*)&Wl[(128 + g) * 68 + h4];
#pragma unroll
        for (int j = 0; j < 4; j++) {
            const int h = h4 + j;
            float wa = (&w0.x)[j], wb = (&w1.x)[j], wc = (&w2.x)[j];
            a0 = fmaf(wa, rdl(i0, h), a0);
            a1 = fmaf(wb, rdl(i1, h), a1);
            a2 = fmaf(wb, rdl(i2, h), a2);
            a3 = fmaf(wb, rdl(i3, h), a3);
            a4 = fmaf(wc, rdl(i4, h), a4);
            a5 = fmaf(wc, rdl(i5, h), a5);
            a6 = fmaf(wc, rdl(i6, h), a6);
            a7 = fmaf(wc, rdl(i7, h), a7);
            a8 = fmaf(wc, rdl(i8, h), a8);
        }
    }

    if (valid) {
        float D[9];
        D[0] = a0 + a4; D[1] = a1 + a5; D[2] = a2 + a6;
        D[3] = -a1 + a5; D[4] = a0 + a7; D[5] = a3 + a8;
        D[6] = -a2 + a6; D[7] = -a3 + a8; D[8] = a0 - a4 - a7;

        const float* xp = X + ((size_t)n * 64 + g) * 9;
        float xv[9];
#pragma unroll
        for (int i = 0; i < 9; i++) xv[i] = xp[i];
        float tn = 0.f;
#pragma unroll
        for (int i = 0; i < 9; i++) tn = fmaf(xv[i], xv[i], tn);
        float inv = 1.0f / (tn + 1.0f);

        float* op = out + ((size_t)n * 64 + g) * 9;   // final [N][64][3][3]
        float res[9];
#pragma unroll
        for (int a = 0; a < 3; a++)
#pragma unroll
            for (int b = 0; b < 3; b++) {
                float dd = 0.f;
#pragma unroll
                for (int c = 0; c < 3; c++) dd = fmaf(D[a * 3 + c], D[c * 3 + b], dd);
                res[a * 3 + b] = xv[a * 3 + b] * inv + D[a * 3 + b] + dd;
            }
#pragma unroll
        for (int i = 0; i < 9; i++) op[i] = res[i];
    }
}

extern "C" void kernel_launch(void* const* d_in, const int* in_sizes, int n_in,
                              void* d_out, int out_size, void* d_ws, size_t ws_size,
                              hipStream_t stream)
{
    const float* X    = (const float*)d_in[0];
    const int*   eidx = (const int*)d_in[1];
    const float* dist = (const float*)d_in[2];
    const float* ea   = (const float*)d_in[3];
    const float* w1   = (const float*)d_in[4];
    const float* b1   = (const float*)d_in[5];
    const float* w2   = (const float*)d_in[6];
    const float* b2   = (const float*)d_in[7];
    const float* w3   = (const float*)d_in[8];
    const float* b3   = (const float*)d_in[9];
    const float* lw   = (const float*)d_in[10];
    float* outp = (float*)d_out;

    const int nnodes = in_sizes[0] / (64 * 9);   // 20000
    const int nedges = in_sizes[2];              // 320000

    unsigned* Tmh  = (unsigned*)d_ws;                       // N*320 dwords (packed bf16 pairs)
    int* cur       = (int*)(Tmh + (size_t)nnodes * 320);
    int* off       = cur + nnodes;                          // nnodes+1
    int* perm      = off + nnodes + 1;                      // nedges
    int* col_s     = perm + nedges;                         // nedges
    unsigned* wpre = (unsigned*)(col_s + nedges);           // 17792 dwords

    // CSR build (edges sorted by destination row; col pre-gathered)
    hipMemsetAsync(cur, 0, (size_t)nnodes * sizeof(int), stream);
    k_hist<<<(nedges + 255) / 256, 256, 0, stream>>>(eidx, cur, nedges);
    k_scan2<<<1, 1024, 0, stream>>>(cur, off, nnodes);
    k_scatter<<<(nedges + 255) / 256, 256, 0, stream>>>(eidx, cur, perm, col_s, nedges);
    k_prep<<<70, 256, 0, stream>>>(w1, b1, w2, b2, w3, b3, wpre);

    k1_node_mix<<<(nnodes + 7) / 8, 512, 0, stream>>>(X, lw, Tmh, nnodes);
    k2f_fused<<<(nnodes + NW - 1) / NW, 64 * NW, 0, stream>>>(ea, dist, perm, col_s, off, wpre, Tmh, outp, nnodes);
    k4_final<<<(nnodes + 7) / 8, 512, 0, stream>>>(X, lw, outp, nnodes);
}

// Round 19
// 353.235 us; speedup vs baseline: 1.6238x; 1.0874x over previous
//
#include <hip/hip_runtime.h>
#include <hip/hip_fp16.h>
#include <hip/hip_bf16.h>

#define NR 32

typedef __attribute__((ext_vector_type(8))) short bf8_t;   // 8 x bf16 (4 VGPR)
typedef __attribute__((ext_vector_type(4))) float f4_t;

__device__ __forceinline__ float silu_f(float x) {
    return x * __builtin_amdgcn_rcpf(1.0f + __expf(-x));
}

__device__ __forceinline__ unsigned pkbf(float lo, float hi) {
    __hip_bfloat162 h = __float22bfloat162_rn(make_float2(lo, hi));
    union { __hip_bfloat162 h2; unsigned u; } cv; cv.h2 = h; return cv.u;
}
__device__ __forceinline__ float bf_lo(unsigned u) { return __uint_as_float(u << 16); }
__device__ __forceinline__ float bf_hi(unsigned u) { return __uint_as_float(u & 0xffff0000u); }

__device__ __forceinline__ float rdl(float v, int l) {
    return __int_as_float(__builtin_amdgcn_readlane(__float_as_int(v), l));
}

// ---------------- CSR build ----------------
__global__ __launch_bounds__(256) void k_hist(
    const int* __restrict__ eidx, int* __restrict__ cnt, int nedges)
{
    int e = blockIdx.x * 256 + threadIdx.x;
    if (e < nedges) atomicAdd(&cnt[eidx[e]], 1);
}

__global__ __launch_bounds__(256) void k_scatter(
    const int* __restrict__ eidx, int* __restrict__ cur,
    int* __restrict__ perm, int* __restrict__ col_s, int nedges)
{
    int e = blockIdx.x * 256 + threadIdx.x;
    if (e < nedges) {
        int r = eidx[e];
        int pos = atomicAdd(&cur[r], 1);
        perm[pos] = e;
        col_s[pos] = eidx[nedges + e];
    }
}

// ---------------- K_mega: block 0 = scan | blocks 1..2500 = k1 node mix | rest = weight prep ----------------
// scan: exclusive prefix over cnt[n] -> off[], cnt[] (cursors); 512 thr, 8 waves.
// k1: node decompose + mix (lin_w[0..2]) -> Tmh[N][5][64] packed bf16 (wave = node).
// prep: bake bf16 frag-linear remapped weight blob (17792 dwords).
__global__ __launch_bounds__(512) void k_mega(
    int* __restrict__ cnt, int* __restrict__ off, int nnodes,
    const float* __restrict__ w1, const float* __restrict__ b1,
    const float* __restrict__ w2, const float* __restrict__ b2,
    const float* __restrict__ w3, const float* __restrict__ b3,
    unsigned* __restrict__ wpre,
    const float* __restrict__ X, const float* __restrict__ lw,
    unsigned* __restrict__ Tmh, int nk1blocks)
{
    __shared__ float Wl[3 * 64 * 68];      // k1 weight tile; block 0 reuses as int scratch
    const int tid = threadIdx.x;
    const int bid = blockIdx.x;

    if (bid == 0) {
        // ---- scan (8 waves) ----
        int* ish = (int*)Wl;               // ish[0..7]=wsum, ish[8..15]=wbase
        const int lane = tid & 63, wid = tid >> 6;
        const int n = nnodes;
        const int per = (n + 511) >> 9;
        const int base = tid * per;
        int s = 0;
        for (int i = 0; i < per; i++) {
            int idx = base + i;
            if (idx < n) s += cnt[idx];
        }
        int incl = s;
        for (int d = 1; d < 64; d <<= 1) {
            int t = __shfl_up(incl, d);
            if (lane >= d) incl += t;
        }
        if (lane == 63) ish[wid] = incl;
        __syncthreads();
        if (wid == 0) {
            int v = (lane < 8) ? ish[lane] : 0;
            int inc2 = v;
            for (int d = 1; d < 8; d <<= 1) {
                int t = __shfl_up(inc2, d);
                if (lane >= d) inc2 += t;
            }
            if (lane < 8) ish[8 + lane] = inc2 - v;
            if (lane == 7) off[n] = inc2;
        }
        __syncthreads();
        int run = ish[8 + wid] + incl - s;
        for (int i = 0; i < per; i++) {
            int idx = base + i;
            if (idx < n) {
                int v = cnt[idx];
                off[idx] = run;
                cnt[idx] = run;
                run += v;
            }
        }
        return;
    }

    if (bid > nk1blocks) {
        // ---- weight prep ----
        int i = (bid - nk1blocks - 1) * 512 + tid;
        if (i < 12288) {                       // w3p: 48 (m*4+kt) x 256 dw
            int mk = i >> 8, m = mk >> 2, kt = mk & 3;
            int rr = (i >> 4) & 15, gg = (i >> 2) & 3, dd = i & 3;
            int row = 16 * m + rr;
            int c0 = 32 * kt + 16 * (dd >> 1) + 4 * gg + 2 * (dd & 1);
            const float* s = w3 + (size_t)row * 128 + c0;
            wpre[i] = pkbf(s[0], s[1]);
        } else if (i < 12672) {                // biases: b1[64] b2[128] b3[192]
            int j = i - 12288;
            float v = (j < 64) ? b1[j] : (j < 192) ? b2[j - 64] : b3[j - 192];
            wpre[i] = __float_as_uint(v);
        } else if (i < 13696) {                // w1p: 4 m x 256 dw, natural k
            int j = i - 12672;
            int m = j >> 8, rr = (j >> 4) & 15, gg = (j >> 2) & 3, dd = j & 3;
            const float* s = w1 + (size_t)(16 * m + rr) * 32 + 8 * gg + 2 * dd;
            wpre[i] = pkbf(s[0], s[1]);
        } else if (i < 17792) {                // w2p: 16 (m*2+kt) x 256 dw, remapped
            int j = i - 13696;
            int mk = j >> 8, m = mk >> 1, kt = mk & 1;
            int rr = (j >> 4) & 15, gg = (j >> 2) & 3, dd = j & 3;
            int row = 16 * m + rr;
            int c0 = 32 * kt + 16 * (dd >> 1) + 4 * gg + 2 * (dd & 1);
            const float* s = w2 + (size_t)row * 64 + c0;
            wpre[i] = pkbf(s[0], s[1]);
        }
        return;
    }

    // ---- k1 node mix (blocks 1..nk1blocks) ----
#pragma unroll
    for (int k = 0; k < 6; k++) {          // stage lw[0..2]: 12288 floats coalesced
        int l = (tid + k * 512) * 4;
        int row = l >> 6, col = l & 63;
        *(float4*)&Wl[row * 68 + col] = *(const float4*)(lw + l);
    }

    const int wid = tid >> 6, lane = tid & 63;
    const int n = (bid - 1) * 8 + wid;
    const bool valid = (n < nnodes);

    float i0 = 0, i1 = 0, i2 = 0, i3 = 0, i4 = 0, i5 = 0, i6 = 0, i7 = 0, i8 = 0;
    if (valid) {
        const float* xp = X + ((size_t)n * 64 + lane) * 9;
        float v[9];
#pragma unroll
        for (int i = 0; i < 9; i++) v[i] = xp[i];
        float tn = 0.f;
#pragma unroll
        for (int i = 0; i < 9; i++) tn = fmaf(v[i], v[i], tn);
        float inv = 1.0f / (tn + 1.0f);
#pragma unroll
        for (int i = 0; i < 9; i++) v[i] *= inv;
        float lam = (v[0] + v[4] + v[8]) * (1.0f / 3.0f);
        i0 = lam;
        i1 = (v[1] - v[3]) * 0.5f;
        i2 = (v[2] - v[6]) * 0.5f;
        i3 = (v[5] - v[7]) * 0.5f;
        i4 = v[0] - lam;
        i5 = (v[1] + v[3]) * 0.5f;
        i6 = (v[2] + v[6]) * 0.5f;
        i7 = v[4] - lam;
        i8 = (v[5] + v[7]) * 0.5f;
    }
    __syncthreads();

    const int g = lane;
    float a0 = 0, a1 = 0, a2 = 0, a3 = 0, a4 = 0, a5 = 0, a6 = 0, a7 = 0, a8 = 0;
#pragma unroll
    for (int h4 = 0; h4 < 64; h4 += 4) {
        float4 w0 = *(const float4*)&Wl[g * 68 + h4];
        float4 w1v = *(const float4*)&Wl[(64 + g) * 68 + h4];
        float4 w2v = *(const float4*)&Wl[(128 + g) * 68 + h4];
#pragma unroll
        for (int j = 0; j < 4; j++) {
            const int h = h4 + j;
            float wa = (&w0.x)[j], wb = (&w1v.x)[j], wc = (&w2v.x)[j];
            a0 = fmaf(wa, rdl(i0, h), a0);
            a1 = fmaf(wb, rdl(i1, h), a1);
            a2 = fmaf(wb, rdl(i2, h), a2);
            a3 = fmaf(wb, rdl(i3, h), a3);
            a4 = fmaf(wc, rdl(i4, h), a4);
            a5 = fmaf(wc, rdl(i5, h), a5);
            a6 = fmaf(wc, rdl(i6, h), a6);
            a7 = fmaf(wc, rdl(i7, h), a7);
            a8 = fmaf(wc, rdl(i8, h), a8);
        }
    }
    if (valid) {
        unsigned* outp = Tmh + (size_t)n * 320 + g;
        outp[0 * 64] = pkbf(a0, a1);
        outp[1 * 64] = pkbf(a2, a3);
        outp[2 * 64] = pkbf(a4, a5);
        outp[3 * 64] = pkbf(a6, a7);
        outp[4 * 64] = pkbf(a8, 0.f);
    }
}

// ---------------- K2f: fused edge MLP (MFMA, transposed) + accumulate + k3 ----------------
// 14 waves/block, 896 thr; W1+W2+W3 frags ALL in LDS; q[4][5] rotated Tmh prefetch after L3.
// ea/dist loaded at chunk top (no register prefetch): peak VGPR demand < 64 in every phase.
// LDS: blob [0,71168): w3p 0 | biases 49152 | w1p 50688 | w2p 54784 ; 14 ef tiles @71168.
#define LBI 49152
#define LW1P 50688
#define LW2P 54784
#define LEF 71168
#define EFS 408
#define NW  14

__global__
__attribute__((amdgpu_flat_work_group_size(896, 896)))
__attribute__((amdgpu_waves_per_eu(3)))
void k2f_fused(
    const float* __restrict__ ea, const float* __restrict__ dist,
    const int* __restrict__ perm, const int* __restrict__ col_s,
    const int* __restrict__ off, const unsigned* __restrict__ wpre,
    const unsigned* __restrict__ Tmh, float* __restrict__ out, int nrows)
{
    __shared__ __align__(16) char smem[LEF + NW * 16 * EFS];   // 162560 B
    const int tid = threadIdx.x;

    // stage whole weight blob (17792 dw = 4448 uint4) -> LDS linearly, coalesced
#pragma unroll
    for (int k = 0; k < 5; k++) {
        int idx = tid + k * 896;
        if (idx < 4448)
            ((uint4*)smem)[idx] = ((const uint4*)wpre)[idx];
    }

    const int wid = tid >> 6, lane = tid & 63;
    const int r16 = lane & 15, g = lane >> 4;
    const int slot = r16 * 4 + g;
    char* efb = smem + LEF + wid * (16 * EFS);
    __syncthreads();

    const int r = blockIdx.x * NW + wid;
    if (r >= nrows) return;
    const int beg = off[r];
    const int deg = off[r + 1] - beg;

    float acc[9];
#pragma unroll
    for (int i = 0; i < 9; i++) acc[i] = 0.f;

#pragma unroll 1
    for (int c0 = 0; c0 < deg; c0 += 16) {
        const int cnt = min(16, deg - c0);

        // cols + edge data of this chunk (lane r16 = edge slot; clamped for pads)
        int colv = col_s[beg + c0 + ((r16 < cnt) ? r16 : (cnt - 1))];
        int e = perm[beg + c0 + ((r16 < cnt) ? r16 : 0)];
        const float* ar = ea + (size_t)e * NR + 8 * g;
        float4 v0 = *(const float4*)(ar);
        float4 v1 = *(const float4*)(ar + 4);
        float d = dist[e];

        bf8_t bx;
        {
            union { bf8_t v; unsigned u[4]; } tt;
            tt.u[0] = pkbf(v0.x, v0.y); tt.u[1] = pkbf(v0.z, v0.w);
            tt.u[2] = pkbf(v1.x, v1.y); tt.u[3] = pkbf(v1.z, v1.w);
            bx = tt.v;
        }
        float cf = (r16 < cnt && d < 5.0f)
                 ? 0.5f * (__cosf(d * 0.62831853071795864f) + 1.0f) : 0.0f;

        // ---- L1 (W1 frags from LDS) ----
        unsigned pk1[4][2];
#pragma unroll
        for (int m = 0; m < 4; m++) {
            f4_t c = *(const f4_t*)(smem + LBI + (16 * m + 4 * g) * 4);
            bf8_t aw = *(const bf8_t*)(smem + LW1P + (m * 64 + slot) * 16);
            c = __builtin_amdgcn_mfma_f32_16x16x32_bf16(aw, bx, c, 0, 0, 0);
            pk1[m][0] = pkbf(silu_f(c[0]), silu_f(c[1]));
            pk1[m][1] = pkbf(silu_f(c[2]), silu_f(c[3]));
        }
        bf8_t B2[2];
        {
            union { bf8_t v; unsigned u[4]; } ta, tb;
            ta.u[0] = pk1[0][0]; ta.u[1] = pk1[0][1]; ta.u[2] = pk1[1][0]; ta.u[3] = pk1[1][1];
            tb.u[0] = pk1[2][0]; tb.u[1] = pk1[2][1]; tb.u[2] = pk1[3][0]; tb.u[3] = pk1[3][1];
            B2[0] = ta.v; B2[1] = tb.v;
        }

        // ---- L2 (W2 frags from LDS) ----
        unsigned pk2[8][2];
#pragma unroll
        for (int m = 0; m < 8; m++) {
            f4_t c = *(const f4_t*)(smem + LBI + (64 + 16 * m + 4 * g) * 4);
#pragma unroll
            for (int kt = 0; kt < 2; kt++) {
                bf8_t aw = *(const bf8_t*)(smem + LW2P + ((m * 2 + kt) * 64 + slot) * 16);
                c = __builtin_amdgcn_mfma_f32_16x16x32_bf16(aw, B2[kt], c, 0, 0, 0);
            }
            pk2[m][0] = pkbf(silu_f(c[0]), silu_f(c[1]));
            pk2[m][1] = pkbf(silu_f(c[2]), silu_f(c[3]));
        }
        bf8_t B3[4];
#pragma unroll
        for (int kt = 0; kt < 4; kt++) {
            union { bf8_t v; unsigned u[4]; } tt;
            tt.u[0] = pk2[2 * kt][0]; tt.u[1] = pk2[2 * kt][1];
            tt.u[2] = pk2[2 * kt + 1][0]; tt.u[3] = pk2[2 * kt + 1][1];
            B3[kt] = tt.v;
        }

        // ---- drain prior chunk's LDS reads before overwriting the tile ----
        asm volatile("s_waitcnt lgkmcnt(0)" ::: "memory");
        __builtin_amdgcn_sched_barrier(0);

        // ---- L3 + cutoff -> per-wave LDS ef tile ----
#pragma unroll
        for (int m = 0; m < 12; m++) {
            f4_t c = *(const f4_t*)(smem + LBI + (192 + 16 * m + 4 * g) * 4);
#pragma unroll
            for (int kt = 0; kt < 4; kt++) {
                bf8_t aw = *(const bf8_t*)(smem + ((m * 4 + kt) * 64 + slot) * 16);
                c = __builtin_amdgcn_mfma_f32_16x16x32_bf16(aw, B3[kt], c, 0, 0, 0);
            }
            union { struct { __half2 a, b; } h; uint2 u; } pu;
            pu.h.a = __float22half2_rn(make_float2(c[0] * cf, c[1] * cf));
            pu.h.b = __float22half2_rn(make_float2(c[2] * cf, c[3] * cf));
            *(uint2*)(efb + r16 * EFS + (16 * m + 4 * g) * 2) = pu.u;
        }
        asm volatile("s_waitcnt lgkmcnt(0)" ::: "memory");
        __builtin_amdgcn_sched_barrier(0);

        // ---- Tmh gather, edges 0..3 (after L3 so q never co-lives with B3) ----
        unsigned q[4][5];
#pragma unroll
        for (int s = 0; s < 4; s++) {
            int sc = __builtin_amdgcn_readlane(colv, s);
            const unsigned* t = Tmh + (size_t)(unsigned)sc * 320 + lane;
            q[s][0] = t[0]; q[s][1] = t[64]; q[s][2] = t[128];
            q[s][3] = t[192]; q[s][4] = t[256];
        }

        // ---- accumulate: depth-4 rotation (reload each q slot right after last use) ----
#define ACC_STEP(S, Q)                                                        \
        {                                                                     \
            const __half* fp = (const __half*)(efb + (S) * EFS + 6 * lane);   \
            float f0 = __half2float(fp[0]);                                   \
            float f1 = __half2float(fp[1]);                                   \
            float f2 = __half2float(fp[2]);                                   \
            acc[0] = fmaf(f0, bf_lo(Q[0]), acc[0]);                           \
            acc[1] = fmaf(f1, bf_hi(Q[0]), acc[1]);                           \
            acc[2] = fmaf(f1, bf_lo(Q[1]), acc[2]);                           \
            acc[3] = fmaf(f1, bf_hi(Q[1]), acc[3]);                           \
            acc[4] = fmaf(f2, bf_lo(Q[2]), acc[4]);                           \
            acc[5] = fmaf(f2, bf_hi(Q[2]), acc[5]);                           \
            acc[6] = fmaf(f2, bf_lo(Q[3]), acc[6]);                           \
            acc[7] = fmaf(f2, bf_hi(Q[3]), acc[7]);                           \
            acc[8] = fmaf(f2, bf_lo(Q[4]), acc[8]);                           \
        }
#define LOAD_Q(DST, S)                                                        \
        {                                                                     \
            int sc = __builtin_amdgcn_readlane(colv, (S));                    \
            const unsigned* t = Tmh + (size_t)(unsigned)sc * 320 + lane;      \
            DST[0] = t[0]; DST[1] = t[64]; DST[2] = t[128];                   \
            DST[3] = t[192]; DST[4] = t[256];                                 \
        }

        ACC_STEP(0, q[0])  LOAD_Q(q[0], 4)
        ACC_STEP(1, q[1])  LOAD_Q(q[1], 5)
        ACC_STEP(2, q[2])  LOAD_Q(q[2], 6)
        ACC_STEP(3, q[3])  LOAD_Q(q[3], 7)
        ACC_STEP(4, q[0])  LOAD_Q(q[0], 8)
        ACC_STEP(5, q[1])  LOAD_Q(q[1], 9)
        ACC_STEP(6, q[2])  LOAD_Q(q[2], 10)
        ACC_STEP(7, q[3])  LOAD_Q(q[3], 11)
        ACC_STEP(8, q[0])  LOAD_Q(q[0], 12)
        ACC_STEP(9, q[1])  LOAD_Q(q[1], 13)
        ACC_STEP(10, q[2]) LOAD_Q(q[2], 14)
        ACC_STEP(11, q[3]) LOAD_Q(q[3], 15)
        ACC_STEP(12, q[0]) ACC_STEP(13, q[1]) ACC_STEP(14, q[2]) ACC_STEP(15, q[3])
#undef ACC_STEP
#undef LOAD_Q
    }

    // ---- fused k3: prod = M@Y + Y@M, decompose, /norm -> out (pc comp-major) ----
    float y[9];
    {
        const unsigned* tp = Tmh + (size_t)r * 320 + lane;
        unsigned q0 = tp[0], q1 = tp[64], q2 = tp[128], q3 = tp[192], q4 = tp[256];
        y[0] = bf_lo(q0); y[1] = bf_hi(q0); y[2] = bf_lo(q1); y[3] = bf_hi(q1);
        y[4] = bf_lo(q2); y[5] = bf_hi(q2); y[6] = bf_lo(q3); y[7] = bf_hi(q3);
        y[8] = bf_lo(q4);
    }
    float Y[9], Mm[9];
    Y[0] = y[0] + y[4]; Y[1] = y[1] + y[5]; Y[2] = y[2] + y[6];
    Y[3] = -y[1] + y[5]; Y[4] = y[0] + y[7]; Y[5] = y[3] + y[8];
    Y[6] = -y[2] + y[6]; Y[7] = -y[3] + y[8]; Y[8] = y[0] - y[4] - y[7];
    Mm[0] = acc[0] + acc[4]; Mm[1] = acc[1] + acc[5]; Mm[2] = acc[2] + acc[6];
    Mm[3] = -acc[1] + acc[5]; Mm[4] = acc[0] + acc[7]; Mm[5] = acc[3] + acc[8];
    Mm[6] = -acc[2] + acc[6]; Mm[7] = -acc[3] + acc[8]; Mm[8] = acc[0] - acc[4] - acc[7];
    float P[9];
#pragma unroll
    for (int a = 0; a < 3; a++)
#pragma unroll
        for (int b = 0; b < 3; b++) {
            float s = 0.f;
#pragma unroll
            for (int c = 0; c < 3; c++) {
                s = fmaf(Mm[a * 3 + c], Y[c * 3 + b], s);
                s = fmaf(Y[a * 3 + c], Mm[c * 3 + b], s);
            }
            P[a * 3 + b] = s;
        }
    float tn = 0.f;
#pragma unroll
    for (int k = 0; k < 9; k++) tn = fmaf(P[k], P[k], tn);
    float inv = 1.0f / (tn + 1.0f);
    float lam = (P[0] + P[4] + P[8]) * (1.0f / 3.0f);

    float* mp = out + (size_t)r * 576 + lane;
    mp[0 * 64] = lam * inv;
    mp[1 * 64] = (P[1] - P[3]) * 0.5f * inv;
    mp[2 * 64] = (P[2] - P[6]) * 0.5f * inv;
    mp[3 * 64] = (P[5] - P[7]) * 0.5f * inv;
    mp[4 * 64] = (P[0] - lam) * inv;
    mp[5 * 64] = (P[1] + P[3]) * 0.5f * inv;
    mp[6 * 64] = (P[2] + P[6]) * 0.5f * inv;
    mp[7 * 64] = (P[4] - lam) * inv;
    mp[8 * 64] = (P[5] + P[7]) * 0.5f * inv;
}

// ---------------- K4: mix (lin_w[3..5]) -> dX; out = Xn + dX + dX@dX (in-place over pc) ----------------
__global__ __launch_bounds__(512) void k4_final(
    const float* __restrict__ X, const float* __restrict__ lw,
    float* __restrict__ out, int nnodes)
{
    __shared__ float Wl[3 * 64 * 68];
    const int tid = threadIdx.x;
#pragma unroll
    for (int k = 0; k < 6; k++) {          // stage lw[3..5]
        int l = (tid + k * 512) * 4;
        int row = l >> 6, col = l & 63;
        *(float4*)&Wl[row * 68 + col] = *(const float4*)(lw + 3 * 4096 + l);
    }

    const int wid = tid >> 6, lane = tid & 63;
    const int n = blockIdx.x * 8 + wid;
    const bool valid = (n < nnodes);

    float i0 = 0, i1 = 0, i2 = 0, i3 = 0, i4 = 0, i5 = 0, i6 = 0, i7 = 0, i8 = 0;
    if (valid) {
        const float* pp = out + (size_t)n * 576 + lane;   // pc comp-major [n][9][64]
        i0 = pp[0 * 64]; i1 = pp[1 * 64]; i2 = pp[2 * 64];
        i3 = pp[3 * 64]; i4 = pp[4 * 64]; i5 = pp[5 * 64];
        i6 = pp[6 * 64]; i7 = pp[7 * 64]; i8 = pp[8 * 64];
    }
    __syncthreads();

    const int g = lane;
    float a0 = 0, a1 = 0, a2 = 0, a3 = 0, a4 = 0, a5 = 0, a6 = 0, a7 = 0, a8 = 0;
#pragma unroll
    for (int h4 = 0; h4 < 64; h4 += 4) {
        float4 w0 = *(const float4*)&Wl[g * 68 + h4];
        float4 w1 = *(const float4*)&Wl[(64 + g) * 68 + h4];
        float4 w2 = *(const float4*)&Wl[(128 + g) * 68 + h4];
#pragma unroll
        for (int j = 0; j < 4; j++) {
            const int h = h4 + j;
            float wa = (&w0.x)[j], wb = (&w1.x)[j], wc = (&w2.x)[j];
            a0 = fmaf(wa, rdl(i0, h), a0);
            a1 = fmaf(wb, rdl(i1, h), a1);
            a2 = fmaf(wb, rdl(i2, h), a2);
            a3 = fmaf(wb, rdl(i3, h), a3);
            a4 = fmaf(wc, rdl(i4, h), a4);
            a5 = fmaf(wc, rdl(i5, h), a5);
            a6 = fmaf(wc, rdl(i6, h), a6);
            a7 = fmaf(wc, rdl(i7, h), a7);
            a8 = fmaf(wc, rdl(i8, h), a8);
        }
    }

    if (valid) {
        float D[9];
        D[0] = a0 + a4; D[1] = a1 + a5; D[2] = a2 + a6;
        D[3] = -a1 + a5; D[4] = a0 + a7; D[5] = a3 + a8;
        D[6] = -a2 + a6; D[7] = -a3 + a8; D[8] = a0 - a4 - a7;

        const float* xp = X + ((size_t)n * 64 + g) * 9;
        float xv[9];
#pragma unroll
        for (int i = 0; i < 9; i++) xv[i] = xp[i];
        float tn = 0.f;
#pragma unroll
        for (int i = 0; i < 9; i++) tn = fmaf(xv[i], xv[i], tn);
        float inv = 1.0f / (tn + 1.0f);

        float* op = out + ((size_t)n * 64 + g) * 9;   // final [N][64][3][3]
        float res[9];
#pragma unroll
        for (int a = 0; a < 3; a++)
#pragma unroll
            for (int b = 0; b < 3; b++) {
                float dd = 0.f;
#pragma unroll
                for (int c = 0; c < 3; c++) dd = fmaf(D[a * 3 + c], D[c * 3 + b], dd);
                res[a * 3 + b] = xv[a * 3 + b] * inv + D[a * 3 + b] + dd;
            }
#pragma unroll
        for (int i = 0; i < 9; i++) op[i] = res[i];
    }
}

extern "C" void kernel_launch(void* const* d_in, const int* in_sizes, int n_in,
                              void* d_out, int out_size, void* d_ws, size_t ws_size,
                              hipStream_t stream)
{
    const float* X    = (const float*)d_in[0];
    const int*   eidx = (const int*)d_in[1];
    const float* dist = (const float*)d_in[2];
    const float* ea   = (const float*)d_in[3];
    const float* w1   = (const float*)d_in[4];
    const float* b1   = (const float*)d_in[5];
    const float* w2   = (const float*)d_in[6];
    const float* b2   = (const float*)d_in[7];
    const float* w3   = (const float*)d_in[8];
    const float* b3   = (const float*)d_in[9];
    const float* lw   = (const float*)d_in[10];
    float* outp = (float*)d_out;

    const int nnodes = in_sizes[0] / (64 * 9);   // 20000
    const int nedges = in_sizes[2];              // 320000

    unsigned* Tmh  = (unsigned*)d_ws;                       // N*320 dwords (packed bf16 pairs)
    int* cur       = (int*)(Tmh + (size_t)nnodes * 320);
    int* off       = cur + nnodes;                          // nnodes+1
    int* perm      = off + nnodes + 1;                      // nedges
    int* col_s     = perm + nedges;                         // nedges
    unsigned* wpre = (unsigned*)(col_s + nedges);           // 17792 dwords

    const int nk1 = (nnodes + 7) / 8;                       // 2500
    const int nprep = (17792 + 511) / 512;                  // 35

    // CSR build + node mix + weight prep (scan fused with prep/k1 to fill its bubble)
    hipMemsetAsync(cur, 0, (size_t)nnodes * sizeof(int), stream);
    k_hist<<<(nedges + 255) / 256, 256, 0, stream>>>(eidx, cur, nedges);
    k_mega<<<1 + nk1 + nprep, 512, 0, stream>>>(cur, off, nnodes,
                                                w1, b1, w2, b2, w3, b3, wpre,
                                                X, lw, Tmh, nk1);
    k_scatter<<<(nedges + 255) / 256, 256, 0, stream>>>(eidx, cur, perm, col_s, nedges);

    k2f_fused<<<(nnodes + NW - 1) / NW, 64 * NW, 0, stream>>>(ea, dist, perm, col_s, off, wpre, Tmh, outp, nnodes);
    k4_final<<<(nnodes + 7) / 8, 512, 0, stream>>>(X, lw, outp, nnodes);
}